// Round 3
// baseline (1968.737 us; speedup 1.0000x reference)
//
#include <hip/hip_runtime.h>
#include <math.h>

#define TLEN 160000
#define NA 625      // n1 (time rows) / ka (freq elements)
#define NB 256      // n2 (time elements) / kb (freq rows)
#define TD 2500
#define KC 128      // conv half width (~5 sigma_t, sigma_t = 25.46)
#define NTAP 257
#define SROWS 337
#define TWO_PI 6.283185307179586f

struct c2 { float x, y; };

__device__ __forceinline__ c2 cmul(c2 a, c2 b){ return c2{a.x*b.x - a.y*b.y, a.x*b.y + a.y*b.x}; }
__device__ __forceinline__ c2 cadd(c2 a, c2 b){ return c2{a.x+b.x, a.y+b.y}; }
__device__ __forceinline__ c2 csub(c2 a, c2 b){ return c2{a.x-b.x, a.y-b.y}; }
__device__ __forceinline__ c2 cmac(c2 acc, c2 v, float wr, float wi){
  acc.x += v.x*wr - v.y*wi; acc.y += v.x*wi + v.y*wr; return acc;
}
__device__ __forceinline__ c2 cis(float ang){ c2 r; __sincosf(ang, &r.y, &r.x); return r; }
// LDS index swizzle to break power-of-2 bank strides
__device__ __forceinline__ int SW(int i){ return i + (i >> 4); }
// swizzle for stride-64 conv reads: bank = (65t + c) & 31 -> conflict-free
__device__ __forceinline__ int SW64(int i){ return i + (i >> 6); }

__device__ __forceinline__ float omega_of(int k){
  return (k >= TLEN/2 ? (float)(k - TLEN) : (float)k) * (1.0f/(float)TLEN);
}
__device__ __forceinline__ float psi1_val(int j1, int k){
  float xi = 0.4f * exp2f(-(float)j1 * 0.0625f);
  float sig = xi * 0.04427378243f;               // 2^(1/16)-1
  float d = omega_of(k) - xi;
  return __expf(-d*d / (2.0f*sig*sig));
}
__device__ __forceinline__ float psi2_val(int j2, int k){
  float xi = 0.4f * exp2f(-(float)j2);
  float sig = 0.35f * xi;
  float d = omega_of(k) - xi;
  return __expf(-d*d / (2.0f*sig*sig));
}

template<int S>
__device__ __forceinline__ void dft4(c2& a0, c2& a1, c2& a2, c2& a3){
  c2 t0 = cadd(a0,a2), t1 = csub(a0,a2), t2 = cadd(a1,a3), t3 = csub(a1,a3);
  float fs = (float)S;
  a0 = cadd(t0,t2); a2 = csub(t0,t2);
  a1 = c2{t1.x - fs*t3.y, t1.y + fs*t3.x};
  a3 = c2{t1.x + fs*t3.y, t1.y - fs*t3.x};
}

template<int S>
__device__ __forceinline__ void dft5(const c2 a[5], c2 b[5]){
  const float C1 = 0.30901699437494742f, C2 = -0.80901699437494745f;
  const float S1 = 0.95105651629515353f * (float)S, S2 = 0.58778525229247314f * (float)S;
  b[0] = cadd(cadd(a[0],a[1]), cadd(cadd(a[2],a[3]),a[4]));
  c2 r;
  r = a[0]; r = cmac(r,a[1],C1, S1); r = cmac(r,a[2],C2, S2); r = cmac(r,a[3],C2,-S2); r = cmac(r,a[4],C1,-S1); b[1]=r;
  r = a[0]; r = cmac(r,a[1],C2, S2); r = cmac(r,a[2],C1,-S1); r = cmac(r,a[3],C1, S1); r = cmac(r,a[4],C2,-S2); b[2]=r;
  r = a[0]; r = cmac(r,a[1],C2,-S2); r = cmac(r,a[2],C1, S1); r = cmac(r,a[3],C1,-S1); r = cmac(r,a[4],C2, S2); b[3]=r;
  r = a[0]; r = cmac(r,a[1],C1,-S1); r = cmac(r,a[2],C2,-S2); r = cmac(r,a[3],C2, S2); r = cmac(r,a[4],C1, S1); b[4]=r;
}

// ---------------- 256-point row FFT (radix-4 Stockham), one row per 64-thread block ----------------
// Only used for the tiny x-chain now (INMODE=2 gather, OUTMODE=0 twiddle-out).
template<int S, int INMODE, int OUTMODE>
__global__ __launch_bounds__(64) void k_fft256(const void* __restrict__ inp, void* __restrict__ outp){
  __shared__ c2 lds[2][272];
  int g = blockIdx.x;
  int arr = g / NA, n1 = g - arr*NA;
  int j = threadIdx.x;
  c2 v[4];
  if (INMODE == 0){
    const c2* ip = (const c2*)inp + (size_t)arr*TLEN + (size_t)n1*NB;
    #pragma unroll
    for (int q=0;q<4;q++) v[q] = ip[j + 64*q];
  } else if (INMODE == 1){
    const float* ip = (const float*)inp + (size_t)arr*TLEN + (size_t)n1*NB;
    #pragma unroll
    for (int q=0;q<4;q++) v[q] = c2{ip[j + 64*q], 0.0f};
  } else {
    const float* ip = (const float*)inp + (size_t)arr*TLEN;
    #pragma unroll
    for (int q=0;q<4;q++) v[q] = c2{ip[n1 + NA*(j + 64*q)], 0.0f};
  }
  dft4<S>(v[0],v[1],v[2],v[3]);
  #pragma unroll
  for (int r=0;r<4;r++) lds[0][SW(4*j + r)] = v[r];
  __syncthreads();
  { // L = 4
    int k = j & 3;
    c2 w = cis((float)S * TWO_PI * (float)k * (1.0f/16.0f));
    c2 w2 = cmul(w,w), w3 = cmul(w2,w);
    v[0] = lds[0][SW(j)];
    v[1] = cmul(lds[0][SW(j+64)], w);
    v[2] = cmul(lds[0][SW(j+128)], w2);
    v[3] = cmul(lds[0][SW(j+192)], w3);
    dft4<S>(v[0],v[1],v[2],v[3]);
    int base = 4*(j-k)+k;
    #pragma unroll
    for (int r=0;r<4;r++) lds[1][SW(base + 4*r)] = v[r];
  }
  __syncthreads();
  { // L = 16
    int k = j & 15;
    c2 w = cis((float)S * TWO_PI * (float)k * (1.0f/64.0f));
    c2 w2 = cmul(w,w), w3 = cmul(w2,w);
    v[0] = lds[1][SW(j)];
    v[1] = cmul(lds[1][SW(j+64)], w);
    v[2] = cmul(lds[1][SW(j+128)], w2);
    v[3] = cmul(lds[1][SW(j+192)], w3);
    dft4<S>(v[0],v[1],v[2],v[3]);
    int base = 4*(j-k)+k;
    #pragma unroll
    for (int r=0;r<4;r++) lds[0][SW(base + 16*r)] = v[r];
  }
  __syncthreads();
  { // L = 64 (k = j), outputs kb = j + 64r
    c2 w = cis((float)S * TWO_PI * (float)j * (1.0f/256.0f));
    c2 w2 = cmul(w,w), w3 = cmul(w2,w);
    v[0] = lds[0][SW(j)];
    v[1] = cmul(lds[0][SW(j+64)], w);
    v[2] = cmul(lds[0][SW(j+128)], w2);
    v[3] = cmul(lds[0][SW(j+192)], w3);
    dft4<S>(v[0],v[1],v[2],v[3]);
    if (OUTMODE == 0){
      c2* op = (c2*)outp + (size_t)arr*TLEN + (size_t)n1*NB;
      #pragma unroll
      for (int r=0;r<4;r++){
        int kb = j + 64*r;
        c2 tw = cis((float)S * TWO_PI * (float)(n1*kb) * (1.0f/160000.0f));
        op[kb] = cmul(v[r], tw);
      }
    } else {
      float* op = (float*)outp + (size_t)arr*TLEN + (size_t)n1*NB;
      #pragma unroll
      for (int r=0;r<4;r++){
        c2 z = v[r];
        op[j + 64*r] = sqrtf(z.x*z.x + z.y*z.y) * (1.0f/160000.0f);
      }
    }
  }
}

// ---------------- fused gather + inverse 256-FFT + abs (replaces transpose + k_fft256<1,0,1>) ----
// Input A in [kb][n1] layout; block = (arr, n1-chunk of 25). 256 threads = 4 wave-groups,
// each group FFTs rows n1i = gq, gq+4, ... out of a staged [256 kb][25 n1] LDS tile.
// Output: Ur[arr][n1*256 + n2] = |z| / T  (scrambled time rows, contiguous writes).
#define G_TILE  (256*25)
#define G_LDSB  ((G_TILE + 4*2*272)*8)   // 68608 B dynamic
__global__ __launch_bounds__(256) void k_fft256g(const c2* __restrict__ inp, float* __restrict__ outp){
  extern __shared__ float smemg[];
  c2* tile = (c2*)smemg;                       // [256][25]
  c2* scratch = tile + G_TILE;                 // [4][2][272]
  int g = blockIdx.x;
  int arr = g / 25, n1_0 = (g - arr*25)*25;
  const c2* ip = inp + (size_t)arr*TLEN;
  for (int e = threadIdx.x; e < G_TILE; e += 256){
    int kb = e / 25, i = e - kb*25;
    tile[e] = ip[(size_t)kb*NA + n1_0 + i];
  }
  __syncthreads();
  int gq = threadIdx.x >> 6, j = threadIdx.x & 63;
  c2* lds0 = scratch + gq*544;
  c2* lds1 = lds0 + 272;
  float* op0 = outp + (size_t)arr*TLEN;
  for (int t = 0; t < 7; t++){
    int n1i = gq + 4*t;
    bool act = (n1i < 25);
    c2 v[4];
    if (act){
      #pragma unroll
      for (int q=0;q<4;q++) v[q] = tile[(j+64*q)*25 + n1i];
      dft4<1>(v[0],v[1],v[2],v[3]);
      #pragma unroll
      for (int r=0;r<4;r++) lds0[SW(4*j + r)] = v[r];
    }
    __syncthreads();
    if (act){ // L = 4
      int k = j & 3;
      c2 w = cis(TWO_PI * (float)k * (1.0f/16.0f));
      c2 w2 = cmul(w,w), w3 = cmul(w2,w);
      v[0] = lds0[SW(j)];
      v[1] = cmul(lds0[SW(j+64)], w);
      v[2] = cmul(lds0[SW(j+128)], w2);
      v[3] = cmul(lds0[SW(j+192)], w3);
      dft4<1>(v[0],v[1],v[2],v[3]);
      int base = 4*(j-k)+k;
      #pragma unroll
      for (int r=0;r<4;r++) lds1[SW(base + 4*r)] = v[r];
    }
    __syncthreads();
    if (act){ // L = 16
      int k = j & 15;
      c2 w = cis(TWO_PI * (float)k * (1.0f/64.0f));
      c2 w2 = cmul(w,w), w3 = cmul(w2,w);
      v[0] = lds1[SW(j)];
      v[1] = cmul(lds1[SW(j+64)], w);
      v[2] = cmul(lds1[SW(j+128)], w2);
      v[3] = cmul(lds1[SW(j+192)], w3);
      dft4<1>(v[0],v[1],v[2],v[3]);
      int base = 4*(j-k)+k;
      #pragma unroll
      for (int r=0;r<4;r++) lds0[SW(base + 16*r)] = v[r];
    }
    __syncthreads();
    if (act){ // L = 64
      c2 w = cis(TWO_PI * (float)j * (1.0f/256.0f));
      c2 w2 = cmul(w,w), w3 = cmul(w2,w);
      v[0] = lds0[SW(j)];
      v[1] = cmul(lds0[SW(j+64)], w);
      v[2] = cmul(lds0[SW(j+128)], w2);
      v[3] = cmul(lds0[SW(j+192)], w3);
      dft4<1>(v[0],v[1],v[2],v[3]);
      int n1 = n1_0 + n1i;
      float* op = op0 + (size_t)n1*NB;
      #pragma unroll
      for (int r=0;r<4;r++){
        c2 z = v[r];
        op[j + 64*r] = sqrtf(z.x*z.x + z.y*z.y) * (1.0f/160000.0f);
      }
    }
    __syncthreads();
  }
}

// ---------------- fused forward 256-FFT + transposed store (replaces k_fft256<-1,1,0> + transpose) --
// Input real rows Ur[arr][n1][n2]; output B[arr][kb*625 + n1] with row twiddle e^{-2pi i n1 kb/T}.
__global__ __launch_bounds__(256) void k_fft256B(const float* __restrict__ inp, c2* __restrict__ outp){
  extern __shared__ float smemb[];
  c2* tile = (c2*)smemb;                       // [256][25]
  c2* scratch = tile + G_TILE;
  int g = blockIdx.x;
  int arr = g / 25, n1_0 = (g - arr*25)*25;
  int gq = threadIdx.x >> 6, j = threadIdx.x & 63;
  c2* lds0 = scratch + gq*544;
  c2* lds1 = lds0 + 272;
  const float* ip0 = inp + (size_t)arr*TLEN;
  for (int t = 0; t < 7; t++){
    int n1i = gq + 4*t;
    bool act = (n1i < 25);
    int n1 = n1_0 + n1i;
    c2 v[4];
    if (act){
      const float* ip = ip0 + (size_t)n1*NB;
      #pragma unroll
      for (int q=0;q<4;q++) v[q] = c2{ip[j + 64*q], 0.0f};
      dft4<-1>(v[0],v[1],v[2],v[3]);
      #pragma unroll
      for (int r=0;r<4;r++) lds0[SW(4*j + r)] = v[r];
    }
    __syncthreads();
    if (act){ // L = 4
      int k = j & 3;
      c2 w = cis(-TWO_PI * (float)k * (1.0f/16.0f));
      c2 w2 = cmul(w,w), w3 = cmul(w2,w);
      v[0] = lds0[SW(j)];
      v[1] = cmul(lds0[SW(j+64)], w);
      v[2] = cmul(lds0[SW(j+128)], w2);
      v[3] = cmul(lds0[SW(j+192)], w3);
      dft4<-1>(v[0],v[1],v[2],v[3]);
      int base = 4*(j-k)+k;
      #pragma unroll
      for (int r=0;r<4;r++) lds1[SW(base + 4*r)] = v[r];
    }
    __syncthreads();
    if (act){ // L = 16
      int k = j & 15;
      c2 w = cis(-TWO_PI * (float)k * (1.0f/64.0f));
      c2 w2 = cmul(w,w), w3 = cmul(w2,w);
      v[0] = lds1[SW(j)];
      v[1] = cmul(lds1[SW(j+64)], w);
      v[2] = cmul(lds1[SW(j+128)], w2);
      v[3] = cmul(lds1[SW(j+192)], w3);
      dft4<-1>(v[0],v[1],v[2],v[3]);
      int base = 4*(j-k)+k;
      #pragma unroll
      for (int r=0;r<4;r++) lds0[SW(base + 16*r)] = v[r];
    }
    __syncthreads();
    if (act){ // L = 64
      c2 w = cis(-TWO_PI * (float)j * (1.0f/256.0f));
      c2 w2 = cmul(w,w), w3 = cmul(w2,w);
      v[0] = lds0[SW(j)];
      v[1] = cmul(lds0[SW(j+64)], w);
      v[2] = cmul(lds0[SW(j+128)], w2);
      v[3] = cmul(lds0[SW(j+192)], w3);
      dft4<-1>(v[0],v[1],v[2],v[3]);
      #pragma unroll
      for (int r=0;r<4;r++){
        int kb = j + 64*r;
        c2 tw = cis(-TWO_PI * (float)(n1*kb) * (1.0f/160000.0f));
        tile[kb*25 + n1i] = cmul(v[r], tw);
      }
    }
    __syncthreads();
  }
  c2* op = outp + (size_t)arr*TLEN;
  for (int e = threadIdx.x; e < G_TILE; e += 256){
    int kb = e / 25, i = e - kb*25;
    op[(size_t)kb*NA + n1_0 + i] = tile[e];
  }
}

// ---------------- 625-point row FFT (radix-5 Stockham), one row per 128-thread block ----------------
// FILT: 0 none (input array = task i), 1 psi1 (input = Xf[b]), 2 psi2 (input = U1h[slot])
// TW: multiply output element n1 of row kb by e^{S*2pi*i*n1*kb/T}
template<int S, int FILT, int TW>
__global__ __launch_bounds__(128) void k_fft625(const c2* __restrict__ inp, c2* __restrict__ outp,
                                                int cblk, int BLK, int nj2, int j2base, int scBase){
  __shared__ c2 lds[2][672];
  int g = blockIdx.x;
  int i = g / NB, kb = g - i*NB;
  int j = threadIdx.x;
  c2 a[5], b[5];
  if (j < 125){
    const c2* ip;
    int j1 = 0, j2 = 0;
    if (FILT == 0){
      ip = inp + (size_t)i*TLEN;
    } else if (FILT == 1){
      int bt = i / BLK; j1 = cblk*BLK + (i - bt*BLK);
      ip = inp + (size_t)bt*TLEN;
    } else {
      int g2 = scBase + i;
      int npb = BLK*nj2;
      int bt = g2 / npb, rr = g2 - bt*npb;
      int jloc = rr / nj2; j2 = j2base + (rr - jloc*nj2);
      ip = inp + (size_t)(bt*BLK + jloc)*TLEN;
    }
    ip += (size_t)kb*NA;
    #pragma unroll
    for (int q=0;q<5;q++){
      int ka = j + 125*q;
      c2 val = ip[ka];
      if (FILT == 1){ float f = psi1_val(j1, kb + 256*ka); val.x *= f; val.y *= f; }
      if (FILT == 2){ float f = psi2_val(j2, kb + 256*ka); val.x *= f; val.y *= f; }
      a[q] = val;
    }
    dft5<S>(a, b);
    #pragma unroll
    for (int r=0;r<5;r++) lds[0][SW(5*j + r)] = b[r];
  }
  __syncthreads();
  if (j < 125){ // L = 5
    int k = j % 5;
    c2 w = cis((float)S * TWO_PI * (float)k * (1.0f/25.0f));
    c2 w2 = cmul(w,w), w3 = cmul(w2,w), w4 = cmul(w3,w);
    a[0] = lds[0][SW(j)];
    a[1] = cmul(lds[0][SW(j+125)], w);
    a[2] = cmul(lds[0][SW(j+250)], w2);
    a[3] = cmul(lds[0][SW(j+375)], w3);
    a[4] = cmul(lds[0][SW(j+500)], w4);
    dft5<S>(a, b);
    int base = 5*(j-k)+k;
    #pragma unroll
    for (int r=0;r<5;r++) lds[1][SW(base + 5*r)] = b[r];
  }
  __syncthreads();
  if (j < 125){ // L = 25
    int k = j % 25;
    c2 w = cis((float)S * TWO_PI * (float)k * (1.0f/125.0f));
    c2 w2 = cmul(w,w), w3 = cmul(w2,w), w4 = cmul(w3,w);
    a[0] = lds[1][SW(j)];
    a[1] = cmul(lds[1][SW(j+125)], w);
    a[2] = cmul(lds[1][SW(j+250)], w2);
    a[3] = cmul(lds[1][SW(j+375)], w3);
    a[4] = cmul(lds[1][SW(j+500)], w4);
    dft5<S>(a, b);
    int base = 5*(j-k)+k;
    #pragma unroll
    for (int r=0;r<5;r++) lds[0][SW(base + 25*r)] = b[r];
  }
  __syncthreads();
  if (j < 125){ // L = 125 (k = j), outputs n1 = j + 125r
    c2 w = cis((float)S * TWO_PI * (float)j * (1.0f/625.0f));
    c2 w2 = cmul(w,w), w3 = cmul(w2,w), w4 = cmul(w3,w);
    a[0] = lds[0][SW(j)];
    a[1] = cmul(lds[0][SW(j+125)], w);
    a[2] = cmul(lds[0][SW(j+250)], w2);
    a[3] = cmul(lds[0][SW(j+375)], w3);
    a[4] = cmul(lds[0][SW(j+500)], w4);
    dft5<S>(a, b);
    c2* op = outp + (size_t)i*TLEN + (size_t)kb*NA;
    #pragma unroll
    for (int r=0;r<5;r++){
      int n1 = j + 125*r;
      c2 z = b[r];
      if (TW){
        c2 tw = cis((float)S * TWO_PI * (float)(n1*kb) * (1.0f/160000.0f));
        z = cmul(z, tw);
      }
      op[n1] = z;
    }
  }
}

// ---------------- complex transpose [R][C] -> [C][R], per array (x-chain only) ----------------
__global__ __launch_bounds__(256) void k_transpose(const c2* __restrict__ in, c2* __restrict__ out,
                                                   int R, int C, int tilesR, int tilesC){
  __shared__ c2 tile[32][33];
  int bi = blockIdx.x;
  int arr = bi / (tilesR*tilesC);
  int tt = bi - arr*(tilesR*tilesC);
  int tr = tt / tilesC, tc = tt - tr*tilesC;
  const c2* ip = in + (size_t)arr*TLEN;
  c2* op = out + (size_t)arr*TLEN;
  int tx = threadIdx.x & 31, ty = threadIdx.x >> 5;
  #pragma unroll
  for (int i=0;i<4;i++){
    int r = tr*32 + ty + i*8, cc = tc*32 + tx;
    if (r < R && cc < C) tile[ty+i*8][tx] = ip[(size_t)r*C + cc];
  }
  __syncthreads();
  #pragma unroll
  for (int i=0;i<4;i++){
    int r = tc*32 + ty + i*8, cc = tr*32 + tx;
    if (r < C && cc < R) op[(size_t)r*R + cc] = tile[tx][ty+i*8];
  }
}

// ---------------- Gaussian lowpass + decimate-by-64, natural layout (S0 only) ----------------
__global__ __launch_bounds__(256) void k_conv(const float* __restrict__ inp, float* __restrict__ S){
  __shared__ float w[NTAP];
  for (int i=threadIdx.x; i<NTAP; i+=256){
    float d = (float)(i - KC);
    w[i] = 0.015666427f * __expf(-7.7106284e-4f * d * d);
  }
  __syncthreads();
  int g = blockIdx.x;
  int arr = g / 10;
  int t = (g - arr*10)*256 + threadIdx.x;
  if (t >= TD) return;
  int srow = arr * SROWS;
  const float* ip = inp + (size_t)arr*TLEN;
  float acc = 0.0f;
  int n = 64*t - KC; if (n < 0) n += TLEN;
  for (int m=0;m<NTAP;m++){
    acc += ip[n] * w[m];
    n++; if (n == TLEN) n = 0;
  }
  S[(size_t)srow*TD + t] = acc;
}

// ---------------- fused LDS stage + conv for scrambled-layout U (S1/S2 rows) ----------------
#define CONV_NCOL 27
#define CONV_NU   16875   // 27*625
#define CONV_USZ  17138   // SW64(16874)+1
#define CONV_LDSB ((CONV_USZ + NTAP + 1)*4)
template<int MODE>
__global__ __launch_bounds__(256) void k_conv2(const float* __restrict__ inp, float* __restrict__ S,
                                               int cblk, int BLK, int nj2, int j2base, int scBase){
  extern __shared__ float smem[];
  float* u = smem;
  float* w = smem + CONV_USZ;
  for (int i=threadIdx.x; i<NTAP; i+=256){
    float d = (float)(i - KC);
    w[i] = 0.015666427f * __expf(-7.7106284e-4f * d * d);
  }
  int g = blockIdx.x;
  int arr = g / 10;
  int b = g - arr*10;
  int nlo = 16000*b - KC;                       // first time sample needed
  int n2_0 = (nlo >= 0) ? (nlo/625) : -1;       // floor division (nlo >= -128)
  const float* ip = inp + (size_t)arr*TLEN;
  for (int e = threadIdx.x; e < CONV_NU; e += 256){
    int n1 = e / CONV_NCOL;
    int c  = e - n1*CONV_NCOL;
    int n2 = n2_0 + c;
    n2 &= 255;
    u[SW64(n1 + 625*c)] = ip[n1*NB + n2];
  }
  __syncthreads();
  int tl = threadIdx.x;
  if (tl >= 250) return;
  int t = 250*b + tl;
  int srow;
  if (MODE == 1){
    int a2 = arr / BLK; int j1 = cblk*BLK + (arr - a2*BLK);
    srow = a2*SROWS + 1 + j1;
  } else {
    int g2 = scBase + arr; int npb = BLK*nj2;
    int a2 = g2/npb, rr = g2 - a2*npb;
    int jloc = rr/nj2; int j2 = j2base + (rr - jloc*nj2);
    int j1 = cblk*BLK + jloc;
    int full = j1 >> 4;
    int cum = 16*(5*full - (full*(full-1))/2) + (j1 & 15)*(5 - full);
    int P = cum + j2 - full - 1;
    srow = a2*SROWS + 97 + P;
  }
  int base = 64*t - KC - 625*n2_0;
  float acc = 0.0f;
  #pragma unroll 4
  for (int m=0;m<NTAP;m++){
    acc += u[SW64(base + m)] * w[m];
  }
  S[(size_t)srow*TD + t] = acc;
}

// ---------------- global min/max + finalize ----------------
__global__ __launch_bounds__(256) void k_minmax1(const float* __restrict__ S, int n, float* pmn, float* pmx){
  __shared__ float smn[256], smx[256];
  float mn = 3.4028235e38f, mx = -3.4028235e38f;
  for (size_t i = (size_t)blockIdx.x*256 + threadIdx.x; i < (size_t)n; i += (size_t)gridDim.x*256){
    float v = S[i]; mn = fminf(mn,v); mx = fmaxf(mx,v);
  }
  smn[threadIdx.x]=mn; smx[threadIdx.x]=mx; __syncthreads();
  for (int s=128;s>0;s>>=1){
    if ((int)threadIdx.x < s){
      smn[threadIdx.x]=fminf(smn[threadIdx.x],smn[threadIdx.x+s]);
      smx[threadIdx.x]=fmaxf(smx[threadIdx.x],smx[threadIdx.x+s]);
    }
    __syncthreads();
  }
  if (threadIdx.x==0){ pmn[blockIdx.x]=smn[0]; pmx[blockIdx.x]=smx[0]; }
}
__global__ __launch_bounds__(256) void k_minmax2(const float* __restrict__ pmn, const float* __restrict__ pmx,
                                                 int nb, float* scal){
  __shared__ float smn[256], smx[256];
  float mn = 3.4028235e38f, mx = -3.4028235e38f;
  for (int i = threadIdx.x; i < nb; i += 256){ mn = fminf(mn,pmn[i]); mx = fmaxf(mx,pmx[i]); }
  smn[threadIdx.x]=mn; smx[threadIdx.x]=mx; __syncthreads();
  for (int s=128;s>0;s>>=1){
    if ((int)threadIdx.x < s){
      smn[threadIdx.x]=fminf(smn[threadIdx.x],smn[threadIdx.x+s]);
      smx[threadIdx.x]=fmaxf(smx[threadIdx.x],smx[threadIdx.x+s]);
    }
    __syncthreads();
  }
  if (threadIdx.x==0){ scal[0]=smn[0]; scal[1]=smx[0]; }
}
__global__ __launch_bounds__(256) void k_final(const float* __restrict__ S, const float* __restrict__ scal,
                                               float* __restrict__ out, int n){
  int i = blockIdx.x*256 + threadIdx.x;
  if (i >= n) return;
  float mn = scal[0];
  float r = scal[1] - mn;
  if (r == 0.0f) r = 1.0f;
  int half = SROWS*TD;
  int a = i / half; int rest = i - a*half;
  out[i] = (S[(size_t)(a & 1)*half + rest] - mn) / r;
}

extern "C" void kernel_launch(void* const* d_in, const int* in_sizes, int n_in,
                              void* d_out, int out_size, void* d_ws, size_t ws_size,
                              hipStream_t stream){
  (void)in_sizes; (void)n_in;
  const float* x = (const float*)d_in[0];

  int BLK = 16;
  while (BLK > 1){
    size_t CH = 2*(size_t)BLK;
    size_t needb = 2560000ULL + 3ULL*CH*TLEN*8ULL + CH*TLEN*4ULL + 6740000ULL + 8192ULL + 4096ULL;
    if (needb <= ws_size) break;
    BLK >>= 1;
  }
  {
    size_t CH = 2;
    size_t needmin = 2560000ULL + 3ULL*CH*TLEN*8ULL + CH*TLEN*4ULL + 6740000ULL + 8192ULL + 4096ULL;
    if (ws_size < needmin) return;
  }
  int CH = 2*BLK;

  char* p = (char*)d_ws;
  auto carve = [&](size_t bytes)->void*{ void* r = (void*)p; p += (bytes + 255) & ~(size_t)255; return r; };
  c2*    Xf  = (c2*)carve(2ULL*TLEN*sizeof(c2));
  c2*    A   = (c2*)carve((size_t)CH*TLEN*sizeof(c2));
  c2*    B   = (c2*)carve((size_t)CH*TLEN*sizeof(c2));
  c2*    U1h = (c2*)carve((size_t)CH*TLEN*sizeof(c2));
  float* Ur  = (float*)carve((size_t)CH*TLEN*sizeof(float));
  float* Sb  = (float*)carve(2ULL*SROWS*TD*sizeof(float));
  float* pmn = (float*)carve(512*4);
  float* pmx = (float*)carve(512*4);
  float* scal = (float*)carve(256);

  // ---- forward FFT of x -> Xf (scrambled-freq layout) ----
  k_fft256<-1,2,0><<<2*NA, 64, 0, stream>>>((const void*)x, (void*)A);          // natural x, rows n1, twiddle
  k_transpose<<<2*20*8, 256, 0, stream>>>(A, B, NA, NB, 20, 8);                 // [625][256] -> [256][625]
  k_fft625<-1,0,0><<<2*NB, 128, 0, stream>>>(B, Xf, 0,0,0,0,0);                 // rows kb -> Y[kb][ka]
  // ---- S0 ----
  k_conv<<<2*10, 256, 0, stream>>>(x, Sb);

  int NCB = 96 / BLK;
  for (int c = 0; c < NCB; c++){
    int cq = (c*BLK)/16;
    int nj2 = 5 - cq;
    int j2base = cq + 1;
    // ---- order 1: U1 = |ifft(Xf * psi1)| ----
    k_fft625<1,1,1><<<CH*NB, 128, 0, stream>>>(Xf, A, c, BLK, 0,0,0);           // I1 + psi1 + twiddle -> A[kb][n1]
    k_fft256g<<<CH*25, 256, G_LDSB, stream>>>(A, Ur);                           // gather + I3 + abs -> U1 scrambled
    k_conv2<1><<<CH*10, 256, CONV_LDSB, stream>>>(Ur, Sb, c, BLK, 0,0,0);       // S1 rows
    if (nj2 > 0){
      // ---- forward FFT of U1 -> U1h ----
      k_fft256B<<<CH*25, 256, G_LDSB, stream>>>(Ur, B);                         // F1 + twiddle + transposed store
      k_fft625<-1,0,0><<<CH*NB, 128, 0, stream>>>(B, U1h, 0,0,0,0,0);           // F3 -> U1h[kb][ka]
      // ---- order 2 paths ----
      for (int sc = 0; sc < nj2; sc++){
        k_fft625<1,2,1><<<CH*NB, 128, 0, stream>>>(U1h, A, c, BLK, nj2, j2base, sc*CH);
        k_fft256g<<<CH*25, 256, G_LDSB, stream>>>(A, Ur);                       // U2 scrambled
        k_conv2<2><<<CH*10, 256, CONV_LDSB, stream>>>(Ur, Sb, c, BLK, nj2, j2base, sc*CH);
      }
    }
  }

  // ---- global min-max normalize (standardize cancels) + tile(3,1,1) ----
  k_minmax1<<<512, 256, 0, stream>>>(Sb, 2*SROWS*TD, pmn, pmx);
  k_minmax2<<<1, 256, 0, stream>>>(pmn, pmx, 512, scal);
  k_final<<<(out_size+255)/256, 256, 0, stream>>>(Sb, scal, (float*)d_out, out_size);
}

// Round 4
// 1904.978 us; speedup vs baseline: 1.0335x; 1.0335x over previous
//
#include <hip/hip_runtime.h>
#include <math.h>

#define TLEN 160000
#define NA 625      // n1 (time rows) / ka (freq elements)
#define NB 256      // n2 (time elements) / kb (freq rows)
#define TD 2500
#define KC 128      // conv half width (~5 sigma_t, sigma_t = 25.46)
#define NTAP 257
#define SROWS 337
#define TWO_PI 6.283185307179586f

struct c2 { float x, y; };

__device__ __forceinline__ c2 cmul(c2 a, c2 b){ return c2{a.x*b.x - a.y*b.y, a.x*b.y + a.y*b.x}; }
__device__ __forceinline__ c2 cadd(c2 a, c2 b){ return c2{a.x+b.x, a.y+b.y}; }
__device__ __forceinline__ c2 csub(c2 a, c2 b){ return c2{a.x-b.x, a.y-b.y}; }
__device__ __forceinline__ c2 cmac(c2 acc, c2 v, float wr, float wi){
  acc.x += v.x*wr - v.y*wi; acc.y += v.x*wi + v.y*wr; return acc;
}
__device__ __forceinline__ c2 cis(float ang){ c2 r; __sincosf(ang, &r.y, &r.x); return r; }
// LDS index swizzle to break power-of-2 bank strides
__device__ __forceinline__ int SW(int i){ return i + (i >> 4); }
// swizzle for stride-64 conv reads: bank = (65t + c) & 31 -> conflict-free
__device__ __forceinline__ int SW64(int i){ return i + (i >> 6); }
// wave-local "syncthreads": scratch is wave-private, so a block barrier is overkill.
// threadfence_block lowers to s_waitcnt lgkmcnt(0); wave_barrier pins scheduling.
__device__ __forceinline__ void wsync(){
  __builtin_amdgcn_wave_barrier();
  __threadfence_block();
  __builtin_amdgcn_wave_barrier();
}

__device__ __forceinline__ float omega_of(int k){
  return (k >= TLEN/2 ? (float)(k - TLEN) : (float)k) * (1.0f/(float)TLEN);
}
__device__ __forceinline__ float psi1_val(int j1, int k){
  float xi = 0.4f * exp2f(-(float)j1 * 0.0625f);
  float sig = xi * 0.04427378243f;               // 2^(1/16)-1
  float d = omega_of(k) - xi;
  return __expf(-d*d / (2.0f*sig*sig));
}
__device__ __forceinline__ float psi2_val(int j2, int k){
  float xi = 0.4f * exp2f(-(float)j2);
  float sig = 0.35f * xi;
  float d = omega_of(k) - xi;
  return __expf(-d*d / (2.0f*sig*sig));
}

template<int S>
__device__ __forceinline__ void dft4(c2& a0, c2& a1, c2& a2, c2& a3){
  c2 t0 = cadd(a0,a2), t1 = csub(a0,a2), t2 = cadd(a1,a3), t3 = csub(a1,a3);
  float fs = (float)S;
  a0 = cadd(t0,t2); a2 = csub(t0,t2);
  a1 = c2{t1.x - fs*t3.y, t1.y + fs*t3.x};
  a3 = c2{t1.x + fs*t3.y, t1.y - fs*t3.x};
}

template<int S>
__device__ __forceinline__ void dft5(const c2 a[5], c2 b[5]){
  const float C1 = 0.30901699437494742f, C2 = -0.80901699437494745f;
  const float S1 = 0.95105651629515353f * (float)S, S2 = 0.58778525229247314f * (float)S;
  b[0] = cadd(cadd(a[0],a[1]), cadd(cadd(a[2],a[3]),a[4]));
  c2 r;
  r = a[0]; r = cmac(r,a[1],C1, S1); r = cmac(r,a[2],C2, S2); r = cmac(r,a[3],C2,-S2); r = cmac(r,a[4],C1,-S1); b[1]=r;
  r = a[0]; r = cmac(r,a[1],C2, S2); r = cmac(r,a[2],C1,-S1); r = cmac(r,a[3],C1, S1); r = cmac(r,a[4],C2,-S2); b[2]=r;
  r = a[0]; r = cmac(r,a[1],C2,-S2); r = cmac(r,a[2],C1, S1); r = cmac(r,a[3],C1,-S1); r = cmac(r,a[4],C2, S2); b[3]=r;
  r = a[0]; r = cmac(r,a[1],C1,-S1); r = cmac(r,a[2],C2,-S2); r = cmac(r,a[3],C2, S2); r = cmac(r,a[4],C1, S1); b[4]=r;
}

// ---------------- 256-point row FFT (radix-4 Stockham), one row per 64-thread block ----------------
// Only used for the tiny x-chain now (INMODE=2 gather, OUTMODE=0 twiddle-out).
template<int S, int INMODE, int OUTMODE>
__global__ __launch_bounds__(64) void k_fft256(const void* __restrict__ inp, void* __restrict__ outp){
  __shared__ c2 lds[2][272];
  int g = blockIdx.x;
  int arr = g / NA, n1 = g - arr*NA;
  int j = threadIdx.x;
  c2 v[4];
  if (INMODE == 0){
    const c2* ip = (const c2*)inp + (size_t)arr*TLEN + (size_t)n1*NB;
    #pragma unroll
    for (int q=0;q<4;q++) v[q] = ip[j + 64*q];
  } else if (INMODE == 1){
    const float* ip = (const float*)inp + (size_t)arr*TLEN + (size_t)n1*NB;
    #pragma unroll
    for (int q=0;q<4;q++) v[q] = c2{ip[j + 64*q], 0.0f};
  } else {
    const float* ip = (const float*)inp + (size_t)arr*TLEN;
    #pragma unroll
    for (int q=0;q<4;q++) v[q] = c2{ip[n1 + NA*(j + 64*q)], 0.0f};
  }
  dft4<S>(v[0],v[1],v[2],v[3]);
  #pragma unroll
  for (int r=0;r<4;r++) lds[0][SW(4*j + r)] = v[r];
  __syncthreads();
  { // L = 4
    int k = j & 3;
    c2 w = cis((float)S * TWO_PI * (float)k * (1.0f/16.0f));
    c2 w2 = cmul(w,w), w3 = cmul(w2,w);
    v[0] = lds[0][SW(j)];
    v[1] = cmul(lds[0][SW(j+64)], w);
    v[2] = cmul(lds[0][SW(j+128)], w2);
    v[3] = cmul(lds[0][SW(j+192)], w3);
    dft4<S>(v[0],v[1],v[2],v[3]);
    int base = 4*(j-k)+k;
    #pragma unroll
    for (int r=0;r<4;r++) lds[1][SW(base + 4*r)] = v[r];
  }
  __syncthreads();
  { // L = 16
    int k = j & 15;
    c2 w = cis((float)S * TWO_PI * (float)k * (1.0f/64.0f));
    c2 w2 = cmul(w,w), w3 = cmul(w2,w);
    v[0] = lds[1][SW(j)];
    v[1] = cmul(lds[1][SW(j+64)], w);
    v[2] = cmul(lds[1][SW(j+128)], w2);
    v[3] = cmul(lds[1][SW(j+192)], w3);
    dft4<S>(v[0],v[1],v[2],v[3]);
    int base = 4*(j-k)+k;
    #pragma unroll
    for (int r=0;r<4;r++) lds[0][SW(base + 16*r)] = v[r];
  }
  __syncthreads();
  { // L = 64 (k = j), outputs kb = j + 64r
    c2 w = cis((float)S * TWO_PI * (float)j * (1.0f/256.0f));
    c2 w2 = cmul(w,w), w3 = cmul(w2,w);
    v[0] = lds[0][SW(j)];
    v[1] = cmul(lds[0][SW(j+64)], w);
    v[2] = cmul(lds[0][SW(j+128)], w2);
    v[3] = cmul(lds[0][SW(j+192)], w3);
    dft4<S>(v[0],v[1],v[2],v[3]);
    if (OUTMODE == 0){
      c2* op = (c2*)outp + (size_t)arr*TLEN + (size_t)n1*NB;
      #pragma unroll
      for (int r=0;r<4;r++){
        int kb = j + 64*r;
        c2 tw = cis((float)S * TWO_PI * (float)(n1*kb) * (1.0f/160000.0f));
        op[kb] = cmul(v[r], tw);
      }
    } else {
      float* op = (float*)outp + (size_t)arr*TLEN + (size_t)n1*NB;
      #pragma unroll
      for (int r=0;r<4;r++){
        c2 z = v[r];
        op[j + 64*r] = sqrtf(z.x*z.x + z.y*z.y) * (1.0f/160000.0f);
      }
    }
  }
}

// ---------------- fused gather + inverse 256-FFT + abs (transpose-free) ----------------
// Input A in [kb][n1] layout; block = (arr, n1-chunk of 25). 256 threads = 4 wave-groups.
// Tile layout [n1 (25)][kb (stride 259)]: FFT reads are lane-consecutive (conflict-free);
// staging writes hit banks (6i+2kb)&31 = min-cycle b64 pattern. Scratch is wave-private ->
// only ONE block barrier (after stage); stages separated by wave-local fences.
#define GT_S    259
#define G_TILE  (25*GT_S)
#define G_LDSB  ((G_TILE + 4*2*272)*8)   // 69208 B dynamic
__global__ __launch_bounds__(256) void k_fft256g(const c2* __restrict__ inp, float* __restrict__ outp){
  extern __shared__ float smemg[];
  c2* tile = (c2*)smemg;                       // [25][259]
  c2* scratch = tile + G_TILE;                 // [4][2][272]
  int g = blockIdx.x;
  int arr = g / 25, n1_0 = (g - arr*25)*25;
  const c2* ip = inp + (size_t)arr*TLEN;
  for (int e = threadIdx.x; e < 256*25; e += 256){
    int kb = e / 25, i = e - kb*25;
    tile[i*GT_S + kb] = ip[(size_t)kb*NA + n1_0 + i];
  }
  __syncthreads();
  int gq = threadIdx.x >> 6, j = threadIdx.x & 63;
  c2* lds0 = scratch + gq*544;
  c2* lds1 = lds0 + 272;
  float* op0 = outp + (size_t)arr*TLEN;
  for (int t = 0; t < 7; t++){
    int n1i = gq + 4*t;
    if (n1i >= 25) break;
    c2 v[4];
    #pragma unroll
    for (int q=0;q<4;q++) v[q] = tile[n1i*GT_S + j + 64*q];
    dft4<1>(v[0],v[1],v[2],v[3]);
    #pragma unroll
    for (int r=0;r<4;r++) lds0[SW(4*j + r)] = v[r];
    wsync();
    { // L = 4
      int k = j & 3;
      c2 w = cis(TWO_PI * (float)k * (1.0f/16.0f));
      c2 w2 = cmul(w,w), w3 = cmul(w2,w);
      v[0] = lds0[SW(j)];
      v[1] = cmul(lds0[SW(j+64)], w);
      v[2] = cmul(lds0[SW(j+128)], w2);
      v[3] = cmul(lds0[SW(j+192)], w3);
      dft4<1>(v[0],v[1],v[2],v[3]);
      int base = 4*(j-k)+k;
      #pragma unroll
      for (int r=0;r<4;r++) lds1[SW(base + 4*r)] = v[r];
    }
    wsync();
    { // L = 16
      int k = j & 15;
      c2 w = cis(TWO_PI * (float)k * (1.0f/64.0f));
      c2 w2 = cmul(w,w), w3 = cmul(w2,w);
      v[0] = lds1[SW(j)];
      v[1] = cmul(lds1[SW(j+64)], w);
      v[2] = cmul(lds1[SW(j+128)], w2);
      v[3] = cmul(lds1[SW(j+192)], w3);
      dft4<1>(v[0],v[1],v[2],v[3]);
      int base = 4*(j-k)+k;
      #pragma unroll
      for (int r=0;r<4;r++) lds0[SW(base + 16*r)] = v[r];
    }
    wsync();
    { // L = 64
      c2 w = cis(TWO_PI * (float)j * (1.0f/256.0f));
      c2 w2 = cmul(w,w), w3 = cmul(w2,w);
      v[0] = lds0[SW(j)];
      v[1] = cmul(lds0[SW(j+64)], w);
      v[2] = cmul(lds0[SW(j+128)], w2);
      v[3] = cmul(lds0[SW(j+192)], w3);
      dft4<1>(v[0],v[1],v[2],v[3]);
      int n1 = n1_0 + n1i;
      float* op = op0 + (size_t)n1*NB;
      #pragma unroll
      for (int r=0;r<4;r++){
        c2 z = v[r];
        op[j + 64*r] = sqrtf(z.x*z.x + z.y*z.y) * (1.0f/160000.0f);
      }
    }
    wsync();
  }
}

// ---------------- fused forward 256-FFT + transposed store ----------------
// Input real rows Ur[arr][n1][n2]; output B[arr][kb*625 + n1] with row twiddle e^{-2pi i n1 kb/T}.
__global__ __launch_bounds__(256) void k_fft256B(const float* __restrict__ inp, c2* __restrict__ outp){
  extern __shared__ float smemb[];
  c2* tile = (c2*)smemb;                       // [25][259]
  c2* scratch = tile + G_TILE;
  int g = blockIdx.x;
  int arr = g / 25, n1_0 = (g - arr*25)*25;
  int gq = threadIdx.x >> 6, j = threadIdx.x & 63;
  c2* lds0 = scratch + gq*544;
  c2* lds1 = lds0 + 272;
  const float* ip0 = inp + (size_t)arr*TLEN;
  for (int t = 0; t < 7; t++){
    int n1i = gq + 4*t;
    if (n1i >= 25) break;
    int n1 = n1_0 + n1i;
    c2 v[4];
    {
      const float* ip = ip0 + (size_t)n1*NB;
      #pragma unroll
      for (int q=0;q<4;q++) v[q] = c2{ip[j + 64*q], 0.0f};
    }
    dft4<-1>(v[0],v[1],v[2],v[3]);
    #pragma unroll
    for (int r=0;r<4;r++) lds0[SW(4*j + r)] = v[r];
    wsync();
    { // L = 4
      int k = j & 3;
      c2 w = cis(-TWO_PI * (float)k * (1.0f/16.0f));
      c2 w2 = cmul(w,w), w3 = cmul(w2,w);
      v[0] = lds0[SW(j)];
      v[1] = cmul(lds0[SW(j+64)], w);
      v[2] = cmul(lds0[SW(j+128)], w2);
      v[3] = cmul(lds0[SW(j+192)], w3);
      dft4<-1>(v[0],v[1],v[2],v[3]);
      int base = 4*(j-k)+k;
      #pragma unroll
      for (int r=0;r<4;r++) lds1[SW(base + 4*r)] = v[r];
    }
    wsync();
    { // L = 16
      int k = j & 15;
      c2 w = cis(-TWO_PI * (float)k * (1.0f/64.0f));
      c2 w2 = cmul(w,w), w3 = cmul(w2,w);
      v[0] = lds1[SW(j)];
      v[1] = cmul(lds1[SW(j+64)], w);
      v[2] = cmul(lds1[SW(j+128)], w2);
      v[3] = cmul(lds1[SW(j+192)], w3);
      dft4<-1>(v[0],v[1],v[2],v[3]);
      int base = 4*(j-k)+k;
      #pragma unroll
      for (int r=0;r<4;r++) lds0[SW(base + 16*r)] = v[r];
    }
    wsync();
    { // L = 64
      c2 w = cis(-TWO_PI * (float)j * (1.0f/256.0f));
      c2 w2 = cmul(w,w), w3 = cmul(w2,w);
      v[0] = lds0[SW(j)];
      v[1] = cmul(lds0[SW(j+64)], w);
      v[2] = cmul(lds0[SW(j+128)], w2);
      v[3] = cmul(lds0[SW(j+192)], w3);
      dft4<-1>(v[0],v[1],v[2],v[3]);
      #pragma unroll
      for (int r=0;r<4;r++){
        int kb = j + 64*r;
        c2 tw = cis(-TWO_PI * (float)(n1*kb) * (1.0f/160000.0f));
        tile[n1i*GT_S + kb] = cmul(v[r], tw);
      }
    }
    wsync();
  }
  __syncthreads();
  c2* op = outp + (size_t)arr*TLEN;
  for (int e = threadIdx.x; e < 256*25; e += 256){
    int kb = e / 25, i = e - kb*25;
    op[(size_t)kb*NA + n1_0 + i] = tile[i*GT_S + kb];
  }
}

// ---------------- 625-point row FFT (radix-5 Stockham), one row per 128-thread block ----------------
// FILT: 0 none (input array = task i), 1 psi1 (input = Xf[b]), 2 psi2 (input = U1h[slot])
// TW: multiply output element n1 of row kb by e^{S*2pi*i*n1*kb/T}
template<int S, int FILT, int TW>
__global__ __launch_bounds__(128) void k_fft625(const c2* __restrict__ inp, c2* __restrict__ outp,
                                                int cblk, int BLK, int nj2, int j2base, int scBase){
  __shared__ c2 lds[2][672];
  int g = blockIdx.x;
  int i = g / NB, kb = g - i*NB;
  int j = threadIdx.x;
  c2 a[5], b[5];
  if (j < 125){
    const c2* ip;
    int j1 = 0, j2 = 0;
    if (FILT == 0){
      ip = inp + (size_t)i*TLEN;
    } else if (FILT == 1){
      int bt = i / BLK; j1 = cblk*BLK + (i - bt*BLK);
      ip = inp + (size_t)bt*TLEN;
    } else {
      int g2 = scBase + i;
      int npb = BLK*nj2;
      int bt = g2 / npb, rr = g2 - bt*npb;
      int jloc = rr / nj2; j2 = j2base + (rr - jloc*nj2);
      ip = inp + (size_t)(bt*BLK + jloc)*TLEN;
    }
    ip += (size_t)kb*NA;
    #pragma unroll
    for (int q=0;q<5;q++){
      int ka = j + 125*q;
      c2 val = ip[ka];
      if (FILT == 1){ float f = psi1_val(j1, kb + 256*ka); val.x *= f; val.y *= f; }
      if (FILT == 2){ float f = psi2_val(j2, kb + 256*ka); val.x *= f; val.y *= f; }
      a[q] = val;
    }
    dft5<S>(a, b);
    #pragma unroll
    for (int r=0;r<5;r++) lds[0][SW(5*j + r)] = b[r];
  }
  __syncthreads();
  if (j < 125){ // L = 5
    int k = j % 5;
    c2 w = cis((float)S * TWO_PI * (float)k * (1.0f/25.0f));
    c2 w2 = cmul(w,w), w3 = cmul(w2,w), w4 = cmul(w3,w);
    a[0] = lds[0][SW(j)];
    a[1] = cmul(lds[0][SW(j+125)], w);
    a[2] = cmul(lds[0][SW(j+250)], w2);
    a[3] = cmul(lds[0][SW(j+375)], w3);
    a[4] = cmul(lds[0][SW(j+500)], w4);
    dft5<S>(a, b);
    int base = 5*(j-k)+k;
    #pragma unroll
    for (int r=0;r<5;r++) lds[1][SW(base + 5*r)] = b[r];
  }
  __syncthreads();
  if (j < 125){ // L = 25
    int k = j % 25;
    c2 w = cis((float)S * TWO_PI * (float)k * (1.0f/125.0f));
    c2 w2 = cmul(w,w), w3 = cmul(w2,w), w4 = cmul(w3,w);
    a[0] = lds[1][SW(j)];
    a[1] = cmul(lds[1][SW(j+125)], w);
    a[2] = cmul(lds[1][SW(j+250)], w2);
    a[3] = cmul(lds[1][SW(j+375)], w3);
    a[4] = cmul(lds[1][SW(j+500)], w4);
    dft5<S>(a, b);
    int base = 5*(j-k)+k;
    #pragma unroll
    for (int r=0;r<5;r++) lds[0][SW(base + 25*r)] = b[r];
  }
  __syncthreads();
  if (j < 125){ // L = 125 (k = j), outputs n1 = j + 125r
    c2 w = cis((float)S * TWO_PI * (float)j * (1.0f/625.0f));
    c2 w2 = cmul(w,w), w3 = cmul(w2,w), w4 = cmul(w3,w);
    a[0] = lds[0][SW(j)];
    a[1] = cmul(lds[0][SW(j+125)], w);
    a[2] = cmul(lds[0][SW(j+250)], w2);
    a[3] = cmul(lds[0][SW(j+375)], w3);
    a[4] = cmul(lds[0][SW(j+500)], w4);
    dft5<S>(a, b);
    c2* op = outp + (size_t)i*TLEN + (size_t)kb*NA;
    #pragma unroll
    for (int r=0;r<5;r++){
      int n1 = j + 125*r;
      c2 z = b[r];
      if (TW){
        c2 tw = cis((float)S * TWO_PI * (float)(n1*kb) * (1.0f/160000.0f));
        z = cmul(z, tw);
      }
      op[n1] = z;
    }
  }
}

// ---------------- complex transpose [R][C] -> [C][R], per array (x-chain only) ----------------
__global__ __launch_bounds__(256) void k_transpose(const c2* __restrict__ in, c2* __restrict__ out,
                                                   int R, int C, int tilesR, int tilesC){
  __shared__ c2 tile[32][33];
  int bi = blockIdx.x;
  int arr = bi / (tilesR*tilesC);
  int tt = bi - arr*(tilesR*tilesC);
  int tr = tt / tilesC, tc = tt - tr*tilesC;
  const c2* ip = in + (size_t)arr*TLEN;
  c2* op = out + (size_t)arr*TLEN;
  int tx = threadIdx.x & 31, ty = threadIdx.x >> 5;
  #pragma unroll
  for (int i=0;i<4;i++){
    int r = tr*32 + ty + i*8, cc = tc*32 + tx;
    if (r < R && cc < C) tile[ty+i*8][tx] = ip[(size_t)r*C + cc];
  }
  __syncthreads();
  #pragma unroll
  for (int i=0;i<4;i++){
    int r = tc*32 + ty + i*8, cc = tr*32 + tx;
    if (r < C && cc < R) op[(size_t)r*R + cc] = tile[tx][ty+i*8];
  }
}

// ---------------- Gaussian lowpass + decimate-by-64, natural layout (S0 only) ----------------
__global__ __launch_bounds__(256) void k_conv(const float* __restrict__ inp, float* __restrict__ S){
  __shared__ float w[NTAP];
  for (int i=threadIdx.x; i<NTAP; i+=256){
    float d = (float)(i - KC);
    w[i] = 0.015666427f * __expf(-7.7106284e-4f * d * d);
  }
  __syncthreads();
  int g = blockIdx.x;
  int arr = g / 10;
  int t = (g - arr*10)*256 + threadIdx.x;
  if (t >= TD) return;
  int srow = arr * SROWS;
  const float* ip = inp + (size_t)arr*TLEN;
  float acc = 0.0f;
  int n = 64*t - KC; if (n < 0) n += TLEN;
  for (int m=0;m<NTAP;m++){
    acc += ip[n] * w[m];
    n++; if (n == TLEN) n = 0;
  }
  S[(size_t)srow*TD + t] = acc;
}

// ---------------- fused LDS stage + conv for scrambled-layout U (S1/S2 rows) ----------------
#define CONV_NCOL 27
#define CONV_NU   16875   // 27*625
#define CONV_USZ  17138   // SW64(16874)+1
#define CONV_LDSB ((CONV_USZ + NTAP + 1)*4)
template<int MODE>
__global__ __launch_bounds__(256) void k_conv2(const float* __restrict__ inp, float* __restrict__ S,
                                               int cblk, int BLK, int nj2, int j2base, int scBase){
  extern __shared__ float smem[];
  float* u = smem;
  float* w = smem + CONV_USZ;
  for (int i=threadIdx.x; i<NTAP; i+=256){
    float d = (float)(i - KC);
    w[i] = 0.015666427f * __expf(-7.7106284e-4f * d * d);
  }
  int g = blockIdx.x;
  int arr = g / 10;
  int b = g - arr*10;
  int nlo = 16000*b - KC;                       // first time sample needed
  int n2_0 = (nlo >= 0) ? (nlo/625) : -1;       // floor division (nlo >= -128)
  const float* ip = inp + (size_t)arr*TLEN;
  for (int e = threadIdx.x; e < CONV_NU; e += 256){
    int n1 = e / CONV_NCOL;
    int c  = e - n1*CONV_NCOL;
    int n2 = n2_0 + c;
    n2 &= 255;
    u[SW64(n1 + 625*c)] = ip[n1*NB + n2];
  }
  __syncthreads();
  int tl = threadIdx.x;
  if (tl >= 250) return;
  int t = 250*b + tl;
  int srow;
  if (MODE == 1){
    int a2 = arr / BLK; int j1 = cblk*BLK + (arr - a2*BLK);
    srow = a2*SROWS + 1 + j1;
  } else {
    int g2 = scBase + arr; int npb = BLK*nj2;
    int a2 = g2/npb, rr = g2 - a2*npb;
    int jloc = rr/nj2; int j2 = j2base + (rr - jloc*nj2);
    int j1 = cblk*BLK + jloc;
    int full = j1 >> 4;
    int cum = 16*(5*full - (full*(full-1))/2) + (j1 & 15)*(5 - full);
    int P = cum + j2 - full - 1;
    srow = a2*SROWS + 97 + P;
  }
  int base = 64*t - KC - 625*n2_0;
  float acc = 0.0f;
  #pragma unroll 4
  for (int m=0;m<NTAP;m++){
    acc += u[SW64(base + m)] * w[m];
  }
  S[(size_t)srow*TD + t] = acc;
}

// ---------------- global min/max + finalize ----------------
__global__ __launch_bounds__(256) void k_minmax1(const float* __restrict__ S, int n, float* pmn, float* pmx){
  __shared__ float smn[256], smx[256];
  float mn = 3.4028235e38f, mx = -3.4028235e38f;
  for (size_t i = (size_t)blockIdx.x*256 + threadIdx.x; i < (size_t)n; i += (size_t)gridDim.x*256){
    float v = S[i]; mn = fminf(mn,v); mx = fmaxf(mx,v);
  }
  smn[threadIdx.x]=mn; smx[threadIdx.x]=mx; __syncthreads();
  for (int s=128;s>0;s>>=1){
    if ((int)threadIdx.x < s){
      smn[threadIdx.x]=fminf(smn[threadIdx.x],smn[threadIdx.x+s]);
      smx[threadIdx.x]=fmaxf(smx[threadIdx.x],smx[threadIdx.x+s]);
    }
    __syncthreads();
  }
  if (threadIdx.x==0){ pmn[blockIdx.x]=smn[0]; pmx[blockIdx.x]=smx[0]; }
}
__global__ __launch_bounds__(256) void k_minmax2(const float* __restrict__ pmn, const float* __restrict__ pmx,
                                                 int nb, float* scal){
  __shared__ float smn[256], smx[256];
  float mn = 3.4028235e38f, mx = -3.4028235e38f;
  for (int i = threadIdx.x; i < nb; i += 256){ mn = fminf(mn,pmn[i]); mx = fmaxf(mx,pmx[i]); }
  smn[threadIdx.x]=mn; smx[threadIdx.x]=mx; __syncthreads();
  for (int s=128;s>0;s>>=1){
    if ((int)threadIdx.x < s){
      smn[threadIdx.x]=fminf(smn[threadIdx.x],smn[threadIdx.x+s]);
      smx[threadIdx.x]=fmaxf(smx[threadIdx.x],smx[threadIdx.x+s]);
    }
    __syncthreads();
  }
  if (threadIdx.x==0){ scal[0]=smn[0]; scal[1]=smx[0]; }
}
__global__ __launch_bounds__(256) void k_final(const float* __restrict__ S, const float* __restrict__ scal,
                                               float* __restrict__ out, int n){
  int i = blockIdx.x*256 + threadIdx.x;
  if (i >= n) return;
  float mn = scal[0];
  float r = scal[1] - mn;
  if (r == 0.0f) r = 1.0f;
  int half = SROWS*TD;
  int a = i / half; int rest = i - a*half;
  out[i] = (S[(size_t)(a & 1)*half + rest] - mn) / r;
}

extern "C" void kernel_launch(void* const* d_in, const int* in_sizes, int n_in,
                              void* d_out, int out_size, void* d_ws, size_t ws_size,
                              hipStream_t stream){
  (void)in_sizes; (void)n_in;
  const float* x = (const float*)d_in[0];

  int BLK = 16;
  while (BLK > 1){
    size_t CH = 2*(size_t)BLK;
    size_t needb = 2560000ULL + 3ULL*CH*TLEN*8ULL + CH*TLEN*4ULL + 6740000ULL + 8192ULL + 4096ULL;
    if (needb <= ws_size) break;
    BLK >>= 1;
  }
  {
    size_t CH = 2;
    size_t needmin = 2560000ULL + 3ULL*CH*TLEN*8ULL + CH*TLEN*4ULL + 6740000ULL + 8192ULL + 4096ULL;
    if (ws_size < needmin) return;
  }
  int CH = 2*BLK;

  char* p = (char*)d_ws;
  auto carve = [&](size_t bytes)->void*{ void* r = (void*)p; p += (bytes + 255) & ~(size_t)255; return r; };
  c2*    Xf  = (c2*)carve(2ULL*TLEN*sizeof(c2));
  c2*    A   = (c2*)carve((size_t)CH*TLEN*sizeof(c2));
  c2*    B   = (c2*)carve((size_t)CH*TLEN*sizeof(c2));
  c2*    U1h = (c2*)carve((size_t)CH*TLEN*sizeof(c2));
  float* Ur  = (float*)carve((size_t)CH*TLEN*sizeof(float));
  float* Sb  = (float*)carve(2ULL*SROWS*TD*sizeof(float));
  float* pmn = (float*)carve(512*4);
  float* pmx = (float*)carve(512*4);
  float* scal = (float*)carve(256);

  // ---- forward FFT of x -> Xf (scrambled-freq layout) ----
  k_fft256<-1,2,0><<<2*NA, 64, 0, stream>>>((const void*)x, (void*)A);          // natural x, rows n1, twiddle
  k_transpose<<<2*20*8, 256, 0, stream>>>(A, B, NA, NB, 20, 8);                 // [625][256] -> [256][625]
  k_fft625<-1,0,0><<<2*NB, 128, 0, stream>>>(B, Xf, 0,0,0,0,0);                 // rows kb -> Y[kb][ka]
  // ---- S0 ----
  k_conv<<<2*10, 256, 0, stream>>>(x, Sb);

  int NCB = 96 / BLK;
  for (int c = 0; c < NCB; c++){
    int cq = (c*BLK)/16;
    int nj2 = 5 - cq;
    int j2base = cq + 1;
    // ---- order 1: U1 = |ifft(Xf * psi1)| ----
    k_fft625<1,1,1><<<CH*NB, 128, 0, stream>>>(Xf, A, c, BLK, 0,0,0);           // I1 + psi1 + twiddle -> A[kb][n1]
    k_fft256g<<<CH*25, 256, G_LDSB, stream>>>(A, Ur);                           // gather + I3 + abs -> U1 scrambled
    k_conv2<1><<<CH*10, 256, CONV_LDSB, stream>>>(Ur, Sb, c, BLK, 0,0,0);       // S1 rows
    if (nj2 > 0){
      // ---- forward FFT of U1 -> U1h ----
      k_fft256B<<<CH*25, 256, G_LDSB, stream>>>(Ur, B);                         // F1 + twiddle + transposed store
      k_fft625<-1,0,0><<<CH*NB, 128, 0, stream>>>(B, U1h, 0,0,0,0,0);           // F3 -> U1h[kb][ka]
      // ---- order 2 paths ----
      for (int sc = 0; sc < nj2; sc++){
        k_fft625<1,2,1><<<CH*NB, 128, 0, stream>>>(U1h, A, c, BLK, nj2, j2base, sc*CH);
        k_fft256g<<<CH*25, 256, G_LDSB, stream>>>(A, Ur);                       // U2 scrambled
        k_conv2<2><<<CH*10, 256, CONV_LDSB, stream>>>(Ur, Sb, c, BLK, nj2, j2base, sc*CH);
      }
    }
  }

  // ---- global min-max normalize (standardize cancels) + tile(3,1,1) ----
  k_minmax1<<<512, 256, 0, stream>>>(Sb, 2*SROWS*TD, pmn, pmx);
  k_minmax2<<<1, 256, 0, stream>>>(pmn, pmx, 512, scal);
  k_final<<<(out_size+255)/256, 256, 0, stream>>>(Sb, scal, (float*)d_out, out_size);
}

// Round 6
// 1690.995 us; speedup vs baseline: 1.1642x; 1.1265x over previous
//
#include <hip/hip_runtime.h>
#include <math.h>

#define TLEN 160000
#define NA 625      // n1 (time rows) / ka (freq elements)
#define NB 256      // n2 (time elements) / kb (freq rows)
#define TD 2500
#define KC 128      // conv half width (~5 sigma_t, sigma_t = 25.46)
#define NTAP 257
#define SROWS 337
#define TWO_PI 6.283185307179586f

struct c2 { float x, y; };

__device__ __forceinline__ c2 cmul(c2 a, c2 b){ return c2{a.x*b.x - a.y*b.y, a.x*b.y + a.y*b.x}; }
__device__ __forceinline__ c2 cadd(c2 a, c2 b){ return c2{a.x+b.x, a.y+b.y}; }
__device__ __forceinline__ c2 csub(c2 a, c2 b){ return c2{a.x-b.x, a.y-b.y}; }
__device__ __forceinline__ c2 cmac(c2 acc, c2 v, float wr, float wi){
  acc.x += v.x*wr - v.y*wi; acc.y += v.x*wi + v.y*wr; return acc;
}
__device__ __forceinline__ c2 cis(float ang){ c2 r; __sincosf(ang, &r.y, &r.x); return r; }
// LDS index swizzle to break power-of-2 bank strides
__device__ __forceinline__ int SW(int i){ return i + (i >> 4); }
// swizzle for stride-64 conv reads: bank = (65t + c) & 31 -> conflict-free
__device__ __forceinline__ int SW64(int i){ return i + (i >> 6); }
// wave-local "syncthreads": scratch is wave-private, so a block barrier is overkill.
__device__ __forceinline__ void wsync(){
  __builtin_amdgcn_wave_barrier();
  __threadfence_block();
  __builtin_amdgcn_wave_barrier();
}

__device__ __forceinline__ float omega_of(int k){
  return (k >= TLEN/2 ? (float)(k - TLEN) : (float)k) * (1.0f/(float)TLEN);
}

template<int S>
__device__ __forceinline__ void dft4(c2& a0, c2& a1, c2& a2, c2& a3){
  c2 t0 = cadd(a0,a2), t1 = csub(a0,a2), t2 = cadd(a1,a3), t3 = csub(a1,a3);
  float fs = (float)S;
  a0 = cadd(t0,t2); a2 = csub(t0,t2);
  a1 = c2{t1.x - fs*t3.y, t1.y + fs*t3.x};
  a3 = c2{t1.x + fs*t3.y, t1.y - fs*t3.x};
}

template<int S>
__device__ __forceinline__ void dft5(const c2 a[5], c2 b[5]){
  const float C1 = 0.30901699437494742f, C2 = -0.80901699437494745f;
  const float S1 = 0.95105651629515353f * (float)S, S2 = 0.58778525229247314f * (float)S;
  b[0] = cadd(cadd(a[0],a[1]), cadd(cadd(a[2],a[3]),a[4]));
  c2 r;
  r = a[0]; r = cmac(r,a[1],C1, S1); r = cmac(r,a[2],C2, S2); r = cmac(r,a[3],C2,-S2); r = cmac(r,a[4],C1,-S1); b[1]=r;
  r = a[0]; r = cmac(r,a[1],C2, S2); r = cmac(r,a[2],C1,-S1); r = cmac(r,a[3],C1, S1); r = cmac(r,a[4],C2,-S2); b[2]=r;
  r = a[0]; r = cmac(r,a[1],C2,-S2); r = cmac(r,a[2],C1, S1); r = cmac(r,a[3],C1,-S1); r = cmac(r,a[4],C2, S2); b[3]=r;
  r = a[0]; r = cmac(r,a[1],C1,-S1); r = cmac(r,a[2],C2,-S2); r = cmac(r,a[3],C2, S2); r = cmac(r,a[4],C1, S1); b[4]=r;
}

// ---------------- 256-point row FFT (radix-4 Stockham), one row per 64-thread block ----------------
// Only used for the tiny x-chain now (INMODE=2 gather, OUTMODE=0 twiddle-out).
template<int S, int INMODE, int OUTMODE>
__global__ __launch_bounds__(64) void k_fft256(const void* __restrict__ inp, void* __restrict__ outp){
  __shared__ c2 lds[2][272];
  int g = blockIdx.x;
  int arr = g / NA, n1 = g - arr*NA;
  int j = threadIdx.x;
  c2 v[4];
  if (INMODE == 0){
    const c2* ip = (const c2*)inp + (size_t)arr*TLEN + (size_t)n1*NB;
    #pragma unroll
    for (int q=0;q<4;q++) v[q] = ip[j + 64*q];
  } else if (INMODE == 1){
    const float* ip = (const float*)inp + (size_t)arr*TLEN + (size_t)n1*NB;
    #pragma unroll
    for (int q=0;q<4;q++) v[q] = c2{ip[j + 64*q], 0.0f};
  } else {
    const float* ip = (const float*)inp + (size_t)arr*TLEN;
    #pragma unroll
    for (int q=0;q<4;q++) v[q] = c2{ip[n1 + NA*(j + 64*q)], 0.0f};
  }
  dft4<S>(v[0],v[1],v[2],v[3]);
  #pragma unroll
  for (int r=0;r<4;r++) lds[0][SW(4*j + r)] = v[r];
  __syncthreads();
  { // L = 4
    int k = j & 3;
    c2 w = cis((float)S * TWO_PI * (float)k * (1.0f/16.0f));
    c2 w2 = cmul(w,w), w3 = cmul(w2,w);
    v[0] = lds[0][SW(j)];
    v[1] = cmul(lds[0][SW(j+64)], w);
    v[2] = cmul(lds[0][SW(j+128)], w2);
    v[3] = cmul(lds[0][SW(j+192)], w3);
    dft4<S>(v[0],v[1],v[2],v[3]);
    int base = 4*(j-k)+k;
    #pragma unroll
    for (int r=0;r<4;r++) lds[1][SW(base + 4*r)] = v[r];
  }
  __syncthreads();
  { // L = 16
    int k = j & 15;
    c2 w = cis((float)S * TWO_PI * (float)k * (1.0f/64.0f));
    c2 w2 = cmul(w,w), w3 = cmul(w2,w);
    v[0] = lds[1][SW(j)];
    v[1] = cmul(lds[1][SW(j+64)], w);
    v[2] = cmul(lds[1][SW(j+128)], w2);
    v[3] = cmul(lds[1][SW(j+192)], w3);
    dft4<S>(v[0],v[1],v[2],v[3]);
    int base = 4*(j-k)+k;
    #pragma unroll
    for (int r=0;r<4;r++) lds[0][SW(base + 16*r)] = v[r];
  }
  __syncthreads();
  { // L = 64 (k = j), outputs kb = j + 64r
    c2 w = cis((float)S * TWO_PI * (float)j * (1.0f/256.0f));
    c2 w2 = cmul(w,w), w3 = cmul(w2,w);
    v[0] = lds[0][SW(j)];
    v[1] = cmul(lds[0][SW(j+64)], w);
    v[2] = cmul(lds[0][SW(j+128)], w2);
    v[3] = cmul(lds[0][SW(j+192)], w3);
    dft4<S>(v[0],v[1],v[2],v[3]);
    if (OUTMODE == 0){
      c2* op = (c2*)outp + (size_t)arr*TLEN + (size_t)n1*NB;
      #pragma unroll
      for (int r=0;r<4;r++){
        int kb = j + 64*r;
        c2 tw = cis((float)S * TWO_PI * (float)(n1*kb) * (1.0f/160000.0f));
        op[kb] = cmul(v[r], tw);
      }
    } else {
      float* op = (float*)outp + (size_t)arr*TLEN + (size_t)n1*NB;
      #pragma unroll
      for (int r=0;r<4;r++){
        c2 z = v[r];
        op[j + 64*r] = sqrtf(z.x*z.x + z.y*z.y) * (1.0f/160000.0f);
      }
    }
  }
}

// ---------------- fused gather + inverse 256-FFT + abs (transpose-free) ----------------
// Input A in [kb][n1] layout; block = (arr, n1-chunk of GCH). 256 threads = 4 wave-groups.
// Tile layout [GCH][259]: FFT reads lane-consecutive (conflict-free); 50.5 KB -> 3 blocks/CU.
#define GCH     16
#define GNCH    40                        // ceil(625/16)
#define GT_S    259
#define G_TILE  (GCH*GT_S)
#define G_LDSB  ((G_TILE + 4*2*272)*8)    // 50560 B dynamic
__global__ __launch_bounds__(256) void k_fft256g(const c2* __restrict__ inp, float* __restrict__ outp){
  extern __shared__ float smemg[];
  c2* tile = (c2*)smemg;                       // [GCH][GT_S]
  c2* scratch = tile + G_TILE;                 // [4][2][272]
  int g = blockIdx.x;
  int arr = g / GNCH, chunk = g - arr*GNCH;
  int n1_0 = chunk*GCH;
  int rows = NA - n1_0; if (rows > GCH) rows = GCH;
  const c2* ip = inp + (size_t)arr*TLEN;
  for (int e = threadIdx.x; e < 256*rows; e += 256){
    int kb = e / rows, i = e - kb*rows;
    tile[i*GT_S + kb] = ip[(size_t)kb*NA + n1_0 + i];
  }
  __syncthreads();
  int gq = threadIdx.x >> 6, j = threadIdx.x & 63;
  c2* lds0 = scratch + gq*544;
  c2* lds1 = lds0 + 272;
  float* op0 = outp + (size_t)arr*TLEN;
  for (int t = 0; t < 4; t++){
    int n1i = gq + 4*t;
    if (n1i >= rows) break;
    c2 v[4];
    #pragma unroll
    for (int q=0;q<4;q++) v[q] = tile[n1i*GT_S + j + 64*q];
    dft4<1>(v[0],v[1],v[2],v[3]);
    #pragma unroll
    for (int r=0;r<4;r++) lds0[SW(4*j + r)] = v[r];
    wsync();
    { // L = 4
      int k = j & 3;
      c2 w = cis(TWO_PI * (float)k * (1.0f/16.0f));
      c2 w2 = cmul(w,w), w3 = cmul(w2,w);
      v[0] = lds0[SW(j)];
      v[1] = cmul(lds0[SW(j+64)], w);
      v[2] = cmul(lds0[SW(j+128)], w2);
      v[3] = cmul(lds0[SW(j+192)], w3);
      dft4<1>(v[0],v[1],v[2],v[3]);
      int base = 4*(j-k)+k;
      #pragma unroll
      for (int r=0;r<4;r++) lds1[SW(base + 4*r)] = v[r];
    }
    wsync();
    { // L = 16
      int k = j & 15;
      c2 w = cis(TWO_PI * (float)k * (1.0f/64.0f));
      c2 w2 = cmul(w,w), w3 = cmul(w2,w);
      v[0] = lds1[SW(j)];
      v[1] = cmul(lds1[SW(j+64)], w);
      v[2] = cmul(lds1[SW(j+128)], w2);
      v[3] = cmul(lds1[SW(j+192)], w3);
      dft4<1>(v[0],v[1],v[2],v[3]);
      int base = 4*(j-k)+k;
      #pragma unroll
      for (int r=0;r<4;r++) lds0[SW(base + 16*r)] = v[r];
    }
    wsync();
    { // L = 64
      c2 w = cis(TWO_PI * (float)j * (1.0f/256.0f));
      c2 w2 = cmul(w,w), w3 = cmul(w2,w);
      v[0] = lds0[SW(j)];
      v[1] = cmul(lds0[SW(j+64)], w);
      v[2] = cmul(lds0[SW(j+128)], w2);
      v[3] = cmul(lds0[SW(j+192)], w3);
      dft4<1>(v[0],v[1],v[2],v[3]);
      int n1 = n1_0 + n1i;
      float* op = op0 + (size_t)n1*NB;
      #pragma unroll
      for (int r=0;r<4;r++){
        c2 z = v[r];
        op[j + 64*r] = sqrtf(z.x*z.x + z.y*z.y) * (1.0f/160000.0f);
      }
    }
    wsync();
  }
}

// ---------------- fused forward 256-FFT + transposed store ----------------
// Input real rows Ur[arr][n1][n2]; output B[arr][kb*625 + n1] with row twiddle e^{-2pi i n1 kb/T}.
__global__ __launch_bounds__(256) void k_fft256B(const float* __restrict__ inp, c2* __restrict__ outp){
  extern __shared__ float smemb[];
  c2* tile = (c2*)smemb;                       // [GCH][GT_S]
  c2* scratch = tile + G_TILE;
  int g = blockIdx.x;
  int arr = g / GNCH, chunk = g - arr*GNCH;
  int n1_0 = chunk*GCH;
  int rows = NA - n1_0; if (rows > GCH) rows = GCH;
  int gq = threadIdx.x >> 6, j = threadIdx.x & 63;
  c2* lds0 = scratch + gq*544;
  c2* lds1 = lds0 + 272;
  const float* ip0 = inp + (size_t)arr*TLEN;
  for (int t = 0; t < 4; t++){
    int n1i = gq + 4*t;
    if (n1i >= rows) break;
    int n1 = n1_0 + n1i;
    c2 v[4];
    {
      const float* ip = ip0 + (size_t)n1*NB;
      #pragma unroll
      for (int q=0;q<4;q++) v[q] = c2{ip[j + 64*q], 0.0f};
    }
    dft4<-1>(v[0],v[1],v[2],v[3]);
    #pragma unroll
    for (int r=0;r<4;r++) lds0[SW(4*j + r)] = v[r];
    wsync();
    { // L = 4
      int k = j & 3;
      c2 w = cis(-TWO_PI * (float)k * (1.0f/16.0f));
      c2 w2 = cmul(w,w), w3 = cmul(w2,w);
      v[0] = lds0[SW(j)];
      v[1] = cmul(lds0[SW(j+64)], w);
      v[2] = cmul(lds0[SW(j+128)], w2);
      v[3] = cmul(lds0[SW(j+192)], w3);
      dft4<-1>(v[0],v[1],v[2],v[3]);
      int base = 4*(j-k)+k;
      #pragma unroll
      for (int r=0;r<4;r++) lds1[SW(base + 4*r)] = v[r];
    }
    wsync();
    { // L = 16
      int k = j & 15;
      c2 w = cis(-TWO_PI * (float)k * (1.0f/64.0f));
      c2 w2 = cmul(w,w), w3 = cmul(w2,w);
      v[0] = lds1[SW(j)];
      v[1] = cmul(lds1[SW(j+64)], w);
      v[2] = cmul(lds1[SW(j+128)], w2);
      v[3] = cmul(lds1[SW(j+192)], w3);
      dft4<-1>(v[0],v[1],v[2],v[3]);
      int base = 4*(j-k)+k;
      #pragma unroll
      for (int r=0;r<4;r++) lds0[SW(base + 16*r)] = v[r];
    }
    wsync();
    { // L = 64
      c2 w = cis(-TWO_PI * (float)j * (1.0f/256.0f));
      c2 w2 = cmul(w,w), w3 = cmul(w2,w);
      v[0] = lds0[SW(j)];
      v[1] = cmul(lds0[SW(j+64)], w);
      v[2] = cmul(lds0[SW(j+128)], w2);
      v[3] = cmul(lds0[SW(j+192)], w3);
      dft4<-1>(v[0],v[1],v[2],v[3]);
      #pragma unroll
      for (int r=0;r<4;r++){
        int kb = j + 64*r;
        c2 tw = cis(-TWO_PI * (float)(n1*kb) * (1.0f/160000.0f));
        tile[n1i*GT_S + kb] = cmul(v[r], tw);
      }
    }
    wsync();
  }
  __syncthreads();
  c2* op = outp + (size_t)arr*TLEN;
  for (int e = threadIdx.x; e < 256*rows; e += 256){
    int kb = e / rows, i = e - kb*rows;
    op[(size_t)kb*NA + n1_0 + i] = tile[i*GT_S + kb];
  }
}

// ---------------- 625-point row FFT (radix-5 Stockham), one row per 128-thread block ----------------
// FILT: 0 none (input array = task i), 1 psi1 (input = Xf[b]), 2 psi2 (input = U1h[slot])
// TW: multiply output element n1 of row kb by e^{S*2pi*i*n1*kb/T}
// FILT>=1: Gaussian filters are narrow-band; skip loads+evals outside xi +/- 6 sigma
// (clamped to [0, T/2)): dropped values are <= exp(-18) * |input|.
template<int S, int FILT, int TW>
__global__ __launch_bounds__(128) void k_fft625(const c2* __restrict__ inp, c2* __restrict__ outp,
                                                int cblk, int BLK, int nj2, int j2base, int scBase){
  __shared__ c2 lds[2][672];
  int g = blockIdx.x;
  int i = g / NB, kb = g - i*NB;
  int j = threadIdx.x;
  c2 a[5], b[5];
  if (j < 125){
    const c2* ip;
    int j1 = 0, j2 = 0;
    if (FILT == 0){
      ip = inp + (size_t)i*TLEN;
    } else if (FILT == 1){
      int bt = i / BLK; j1 = cblk*BLK + (i - bt*BLK);
      ip = inp + (size_t)bt*TLEN;
    } else {
      int g2 = scBase + i;
      int npb = BLK*nj2;
      int bt = g2 / npb, rr = g2 - bt*npb;
      int jloc = rr / nj2; j2 = j2base + (rr - jloc*nj2);
      ip = inp + (size_t)(bt*BLK + jloc)*TLEN;
    }
    ip += (size_t)kb*NA;
    if (FILT == 0){
      #pragma unroll
      for (int q=0;q<5;q++) a[q] = ip[j + 125*q];
      dft5<S>(a, b);
    } else {
      float xi, sig;
      if (FILT == 1){ xi = 0.4f * exp2f(-(float)j1 * 0.0625f); sig = xi * 0.04427378243f; }
      else          { xi = 0.4f * exp2f(-(float)j2);           sig = 0.35f * xi; }
      float inv2s = 0.5f / (sig*sig);
      int klo = (int)((xi - 6.0f*sig) * (float)TLEN); if (klo < 0) klo = 0;
      int khi = (int)((xi + 6.0f*sig) * (float)TLEN) + 1; if (khi > TLEN/2 - 1) khi = TLEN/2 - 1;
      bool any = false;
      #pragma unroll
      for (int q=0;q<5;q++){
        int ka = j + 125*q;
        int k = kb + 256*ka;
        c2 val = c2{0.0f, 0.0f};
        if (k >= klo && k <= khi){
          val = ip[ka];
          float d = (float)k * (1.0f/(float)TLEN) - xi;   // k < T/2: no wrap
          float f = __expf(-d*d*inv2s);
          val.x *= f; val.y *= f;
          any = true;
        }
        a[q] = val;
      }
      if (any){
        dft5<S>(a, b);
      } else {
        #pragma unroll
        for (int r=0;r<5;r++) b[r] = c2{0.0f,0.0f};
      }
    }
    #pragma unroll
    for (int r=0;r<5;r++) lds[0][SW(5*j + r)] = b[r];
  }
  __syncthreads();
  if (j < 125){ // L = 5
    int k = j % 5;
    c2 w = cis((float)S * TWO_PI * (float)k * (1.0f/25.0f));
    c2 w2 = cmul(w,w), w3 = cmul(w2,w), w4 = cmul(w3,w);
    a[0] = lds[0][SW(j)];
    a[1] = cmul(lds[0][SW(j+125)], w);
    a[2] = cmul(lds[0][SW(j+250)], w2);
    a[3] = cmul(lds[0][SW(j+375)], w3);
    a[4] = cmul(lds[0][SW(j+500)], w4);
    dft5<S>(a, b);
    int base = 5*(j-k)+k;
    #pragma unroll
    for (int r=0;r<5;r++) lds[1][SW(base + 5*r)] = b[r];
  }
  __syncthreads();
  if (j < 125){ // L = 25
    int k = j % 25;
    c2 w = cis((float)S * TWO_PI * (float)k * (1.0f/125.0f));
    c2 w2 = cmul(w,w), w3 = cmul(w2,w), w4 = cmul(w3,w);
    a[0] = lds[1][SW(j)];
    a[1] = cmul(lds[1][SW(j+125)], w);
    a[2] = cmul(lds[1][SW(j+250)], w2);
    a[3] = cmul(lds[1][SW(j+375)], w3);
    a[4] = cmul(lds[1][SW(j+500)], w4);
    dft5<S>(a, b);
    int base = 5*(j-k)+k;
    #pragma unroll
    for (int r=0;r<5;r++) lds[0][SW(base + 25*r)] = b[r];
  }
  __syncthreads();
  if (j < 125){ // L = 125 (k = j), outputs n1 = j + 125r
    c2 w = cis((float)S * TWO_PI * (float)j * (1.0f/625.0f));
    c2 w2 = cmul(w,w), w3 = cmul(w2,w), w4 = cmul(w3,w);
    a[0] = lds[0][SW(j)];
    a[1] = cmul(lds[0][SW(j+125)], w);
    a[2] = cmul(lds[0][SW(j+250)], w2);
    a[3] = cmul(lds[0][SW(j+375)], w3);
    a[4] = cmul(lds[0][SW(j+500)], w4);
    dft5<S>(a, b);
    c2* op = outp + (size_t)i*TLEN + (size_t)kb*NA;
    #pragma unroll
    for (int r=0;r<5;r++){
      int n1 = j + 125*r;
      c2 z = b[r];
      if (TW){
        c2 tw = cis((float)S * TWO_PI * (float)(n1*kb) * (1.0f/160000.0f));
        z = cmul(z, tw);
      }
      op[n1] = z;
    }
  }
}

// ---------------- complex transpose [R][C] -> [C][R], per array (x-chain only) ----------------
__global__ __launch_bounds__(256) void k_transpose(const c2* __restrict__ in, c2* __restrict__ out,
                                                   int R, int C, int tilesR, int tilesC){
  __shared__ c2 tile[32][33];
  int bi = blockIdx.x;
  int arr = bi / (tilesR*tilesC);
  int tt = bi - arr*(tilesR*tilesC);
  int tr = tt / tilesC, tc = tt - tr*tilesC;
  const c2* ip = in + (size_t)arr*TLEN;
  c2* op = out + (size_t)arr*TLEN;
  int tx = threadIdx.x & 31, ty = threadIdx.x >> 5;
  #pragma unroll
  for (int i=0;i<4;i++){
    int r = tr*32 + ty + i*8, cc = tc*32 + tx;
    if (r < R && cc < C) tile[ty+i*8][tx] = ip[(size_t)r*C + cc];
  }
  __syncthreads();
  #pragma unroll
  for (int i=0;i<4;i++){
    int r = tc*32 + ty + i*8, cc = tr*32 + tx;
    if (r < C && cc < R) op[(size_t)r*R + cc] = tile[tx][ty+i*8];
  }
}

// ---------------- Gaussian lowpass + decimate-by-64, natural layout (S0 only) ----------------
__global__ __launch_bounds__(256) void k_conv(const float* __restrict__ inp, float* __restrict__ S){
  __shared__ float w[NTAP];
  for (int i=threadIdx.x; i<NTAP; i+=256){
    float d = (float)(i - KC);
    w[i] = 0.015666427f * __expf(-7.7106284e-4f * d * d);
  }
  __syncthreads();
  int g = blockIdx.x;
  int arr = g / 10;
  int t = (g - arr*10)*256 + threadIdx.x;
  if (t >= TD) return;
  int srow = arr * SROWS;
  const float* ip = inp + (size_t)arr*TLEN;
  float acc = 0.0f;
  int n = 64*t - KC; if (n < 0) n += TLEN;
  for (int m=0;m<NTAP;m++){
    acc += ip[n] * w[m];
    n++; if (n == TLEN) n = 0;
  }
  S[(size_t)srow*TD + t] = acc;
}

// ---------------- fused LDS stage + conv for scrambled-layout U (S1/S2 rows) ----------------
#define CONV_NCOL 27
#define CONV_NU   16875   // 27*625
#define CONV_USZ  17138   // SW64(16874)+1
#define CONV_LDSB ((CONV_USZ + NTAP + 1)*4)
template<int MODE>
__global__ __launch_bounds__(256) void k_conv2(const float* __restrict__ inp, float* __restrict__ S,
                                               int cblk, int BLK, int nj2, int j2base, int scBase){
  extern __shared__ float smem[];
  float* u = smem;
  float* w = smem + CONV_USZ;
  for (int i=threadIdx.x; i<NTAP; i+=256){
    float d = (float)(i - KC);
    w[i] = 0.015666427f * __expf(-7.7106284e-4f * d * d);
  }
  int g = blockIdx.x;
  int arr = g / 10;
  int b = g - arr*10;
  int nlo = 16000*b - KC;                       // first time sample needed
  int n2_0 = (nlo >= 0) ? (nlo/625) : -1;       // floor division (nlo >= -128)
  const float* ip = inp + (size_t)arr*TLEN;
  for (int e = threadIdx.x; e < CONV_NU; e += 256){
    int n1 = e / CONV_NCOL;
    int c  = e - n1*CONV_NCOL;
    int n2 = n2_0 + c;
    n2 &= 255;
    u[SW64(n1 + 625*c)] = ip[n1*NB + n2];
  }
  __syncthreads();
  int tl = threadIdx.x;
  if (tl >= 250) return;
  int t = 250*b + tl;
  int srow;
  if (MODE == 1){
    int a2 = arr / BLK; int j1 = cblk*BLK + (arr - a2*BLK);
    srow = a2*SROWS + 1 + j1;
  } else {
    int g2 = scBase + arr; int npb = BLK*nj2;
    int a2 = g2/npb, rr = g2 - a2*npb;
    int jloc = rr/nj2; int j2 = j2base + (rr - jloc*nj2);
    int j1 = cblk*BLK + jloc;
    int full = j1 >> 4;
    int cum = 16*(5*full - (full*(full-1))/2) + (j1 & 15)*(5 - full);
    int P = cum + j2 - full - 1;
    srow = a2*SROWS + 97 + P;
  }
  int base = 64*t - KC - 625*n2_0;
  float acc = 0.0f;
  #pragma unroll 4
  for (int m=0;m<NTAP;m++){
    acc += u[SW64(base + m)] * w[m];
  }
  S[(size_t)srow*TD + t] = acc;
}

// ---------------- global min/max + finalize ----------------
__global__ __launch_bounds__(256) void k_minmax1(const float* __restrict__ S, int n, float* pmn, float* pmx){
  __shared__ float smn[256], smx[256];
  float mn = 3.4028235e38f, mx = -3.4028235e38f;
  for (size_t i = (size_t)blockIdx.x*256 + threadIdx.x; i < (size_t)n; i += (size_t)gridDim.x*256){
    float v = S[i]; mn = fminf(mn,v); mx = fmaxf(mx,v);
  }
  smn[threadIdx.x]=mn; smx[threadIdx.x]=mx; __syncthreads();
  for (int s=128;s>0;s>>=1){
    if ((int)threadIdx.x < s){
      smn[threadIdx.x]=fminf(smn[threadIdx.x],smn[threadIdx.x+s]);
      smx[threadIdx.x]=fmaxf(smx[threadIdx.x],smx[threadIdx.x+s]);
    }
    __syncthreads();
  }
  if (threadIdx.x==0){ pmn[blockIdx.x]=smn[0]; pmx[blockIdx.x]=smx[0]; }
}
__global__ __launch_bounds__(256) void k_minmax2(const float* __restrict__ pmn, const float* __restrict__ pmx,
                                                 int nb, float* scal){
  __shared__ float smn[256], smx[256];
  float mn = 3.4028235e38f, mx = -3.4028235e38f;
  for (int i = threadIdx.x; i < nb; i += 256){ mn = fminf(mn,pmn[i]); mx = fmaxf(mx,pmx[i]); }
  smn[threadIdx.x]=mn; smx[threadIdx.x]=mx; __syncthreads();
  for (int s=128;s>0;s>>=1){
    if ((int)threadIdx.x < s){
      smn[threadIdx.x]=fminf(smn[threadIdx.x],smn[threadIdx.x+s]);
      smx[threadIdx.x]=fmaxf(smx[threadIdx.x],smx[threadIdx.x+s]);
    }
    __syncthreads();
  }
  if (threadIdx.x==0){ scal[0]=smn[0]; scal[1]=smx[0]; }
}
__global__ __launch_bounds__(256) void k_final(const float* __restrict__ S, const float* __restrict__ scal,
                                               float* __restrict__ out, int n){
  int i = blockIdx.x*256 + threadIdx.x;
  if (i >= n) return;
  float mn = scal[0];
  float r = scal[1] - mn;
  if (r == 0.0f) r = 1.0f;
  int half = SROWS*TD;
  int a = i / half; int rest = i - a*half;
  out[i] = (S[(size_t)(a & 1)*half + rest] - mn) / r;
}

extern "C" void kernel_launch(void* const* d_in, const int* in_sizes, int n_in,
                              void* d_out, int out_size, void* d_ws, size_t ws_size,
                              hipStream_t stream){
  (void)in_sizes; (void)n_in;
  const float* x = (const float*)d_in[0];

  int BLK = 16;
  while (BLK > 1){
    size_t CH = 2*(size_t)BLK;
    size_t needb = 2560000ULL + 3ULL*CH*TLEN*8ULL + CH*TLEN*4ULL + 6740000ULL + 8192ULL + 4096ULL;
    if (needb <= ws_size) break;
    BLK >>= 1;
  }
  {
    size_t CH = 2;
    size_t needmin = 2560000ULL + 3ULL*CH*TLEN*8ULL + CH*TLEN*4ULL + 6740000ULL + 8192ULL + 4096ULL;
    if (ws_size < needmin) return;
  }
  int CH = 2*BLK;

  char* p = (char*)d_ws;
  auto carve = [&](size_t bytes)->void*{ void* r = (void*)p; p += (bytes + 255) & ~(size_t)255; return r; };
  c2*    Xf  = (c2*)carve(2ULL*TLEN*sizeof(c2));
  c2*    A   = (c2*)carve((size_t)CH*TLEN*sizeof(c2));
  c2*    B   = (c2*)carve((size_t)CH*TLEN*sizeof(c2));
  c2*    U1h = (c2*)carve((size_t)CH*TLEN*sizeof(c2));
  float* Ur  = (float*)carve((size_t)CH*TLEN*sizeof(float));
  float* Sb  = (float*)carve(2ULL*SROWS*TD*sizeof(float));
  float* pmn = (float*)carve(512*4);
  float* pmx = (float*)carve(512*4);
  float* scal = (float*)carve(256);

  // ---- forward FFT of x -> Xf (scrambled-freq layout) ----
  k_fft256<-1,2,0><<<2*NA, 64, 0, stream>>>((const void*)x, (void*)A);          // natural x, rows n1, twiddle
  k_transpose<<<2*20*8, 256, 0, stream>>>(A, B, NA, NB, 20, 8);                 // [625][256] -> [256][625]
  k_fft625<-1,0,0><<<2*NB, 128, 0, stream>>>(B, Xf, 0,0,0,0,0);                 // rows kb -> Y[kb][ka]
  // ---- S0 ----
  k_conv<<<2*10, 256, 0, stream>>>(x, Sb);

  int NCB = 96 / BLK;
  for (int c = 0; c < NCB; c++){
    int cq = (c*BLK)/16;
    int nj2 = 5 - cq;
    int j2base = cq + 1;
    // ---- order 1: U1 = |ifft(Xf * psi1)| ----
    k_fft625<1,1,1><<<CH*NB, 128, 0, stream>>>(Xf, A, c, BLK, 0,0,0);           // I1 + psi1 + twiddle -> A[kb][n1]
    k_fft256g<<<CH*GNCH, 256, G_LDSB, stream>>>(A, Ur);                         // gather + I3 + abs -> U1 scrambled
    k_conv2<1><<<CH*10, 256, CONV_LDSB, stream>>>(Ur, Sb, c, BLK, 0,0,0);       // S1 rows
    if (nj2 > 0){
      // ---- forward FFT of U1 -> U1h ----
      k_fft256B<<<CH*GNCH, 256, G_LDSB, stream>>>(Ur, B);                       // F1 + twiddle + transposed store
      k_fft625<-1,0,0><<<CH*NB, 128, 0, stream>>>(B, U1h, 0,0,0,0,0);           // F3 -> U1h[kb][ka]
      // ---- order 2 paths ----
      for (int sc = 0; sc < nj2; sc++){
        k_fft625<1,2,1><<<CH*NB, 128, 0, stream>>>(U1h, A, c, BLK, nj2, j2base, sc*CH);
        k_fft256g<<<CH*GNCH, 256, G_LDSB, stream>>>(A, Ur);                     // U2 scrambled
        k_conv2<2><<<CH*10, 256, CONV_LDSB, stream>>>(Ur, Sb, c, BLK, nj2, j2base, sc*CH);
      }
    }
  }

  // ---- global min-max normalize (standardize cancels) + tile(3,1,1) ----
  k_minmax1<<<512, 256, 0, stream>>>(Sb, 2*SROWS*TD, pmn, pmx);
  k_minmax2<<<1, 256, 0, stream>>>(pmn, pmx, 512, scal);
  k_final<<<(out_size+255)/256, 256, 0, stream>>>(Sb, scal, (float*)d_out, out_size);
}

// Round 7
// 1591.756 us; speedup vs baseline: 1.2368x; 1.0623x over previous
//
#include <hip/hip_runtime.h>
#include <math.h>

#define TLEN 160000
#define NA 625      // n1 (time rows) / ka (freq elements)
#define NB 256      // n2 (time elements) / kb (freq rows)
#define TD 2500
#define KC 128      // conv half width (~5 sigma_t, sigma_t = 25.46)
#define NTAP 257
#define SROWS 337
#define TWO_PI 6.283185307179586f

struct c2 { float x, y; };

__device__ __forceinline__ c2 cmul(c2 a, c2 b){ return c2{a.x*b.x - a.y*b.y, a.x*b.y + a.y*b.x}; }
__device__ __forceinline__ c2 cadd(c2 a, c2 b){ return c2{a.x+b.x, a.y+b.y}; }
__device__ __forceinline__ c2 csub(c2 a, c2 b){ return c2{a.x-b.x, a.y-b.y}; }
__device__ __forceinline__ c2 cmac(c2 acc, c2 v, float wr, float wi){
  acc.x += v.x*wr - v.y*wi; acc.y += v.x*wi + v.y*wr; return acc;
}
__device__ __forceinline__ c2 cis(float ang){ c2 r; __sincosf(ang, &r.y, &r.x); return r; }
__device__ __forceinline__ int SW(int i){ return i + (i >> 4); }
__device__ __forceinline__ int SW64(int i){ return i + (i >> 6); }
// wave-local "syncthreads": scratch is wave-private, so a block barrier is overkill.
__device__ __forceinline__ void wsync(){
  __builtin_amdgcn_wave_barrier();
  __threadfence_block();
  __builtin_amdgcn_wave_barrier();
}

template<int S>
__device__ __forceinline__ void dft4(c2& a0, c2& a1, c2& a2, c2& a3){
  c2 t0 = cadd(a0,a2), t1 = csub(a0,a2), t2 = cadd(a1,a3), t3 = csub(a1,a3);
  float fs = (float)S;
  a0 = cadd(t0,t2); a2 = csub(t0,t2);
  a1 = c2{t1.x - fs*t3.y, t1.y + fs*t3.x};
  a3 = c2{t1.x + fs*t3.y, t1.y - fs*t3.x};
}

template<int S>
__device__ __forceinline__ void dft5(const c2 a[5], c2 b[5]){
  const float C1 = 0.30901699437494742f, C2 = -0.80901699437494745f;
  const float S1 = 0.95105651629515353f * (float)S, S2 = 0.58778525229247314f * (float)S;
  b[0] = cadd(cadd(a[0],a[1]), cadd(cadd(a[2],a[3]),a[4]));
  c2 r;
  r = a[0]; r = cmac(r,a[1],C1, S1); r = cmac(r,a[2],C2, S2); r = cmac(r,a[3],C2,-S2); r = cmac(r,a[4],C1,-S1); b[1]=r;
  r = a[0]; r = cmac(r,a[1],C2, S2); r = cmac(r,a[2],C1,-S1); r = cmac(r,a[3],C1, S1); r = cmac(r,a[4],C2,-S2); b[2]=r;
  r = a[0]; r = cmac(r,a[1],C2,-S2); r = cmac(r,a[2],C1, S1); r = cmac(r,a[3],C1,-S1); r = cmac(r,a[4],C2, S2); b[3]=r;
  r = a[0]; r = cmac(r,a[1],C1,-S1); r = cmac(r,a[2],C2,-S2); r = cmac(r,a[3],C2, S2); r = cmac(r,a[4],C1, S1); b[4]=r;
}

// ---------------- 256-point row FFT (x-chain only) ----------------
template<int S, int INMODE, int OUTMODE>
__global__ __launch_bounds__(64) void k_fft256(const void* __restrict__ inp, void* __restrict__ outp){
  __shared__ c2 lds[2][272];
  int g = blockIdx.x;
  int arr = g / NA, n1 = g - arr*NA;
  int j = threadIdx.x;
  c2 v[4];
  if (INMODE == 0){
    const c2* ip = (const c2*)inp + (size_t)arr*TLEN + (size_t)n1*NB;
    #pragma unroll
    for (int q=0;q<4;q++) v[q] = ip[j + 64*q];
  } else if (INMODE == 1){
    const float* ip = (const float*)inp + (size_t)arr*TLEN + (size_t)n1*NB;
    #pragma unroll
    for (int q=0;q<4;q++) v[q] = c2{ip[j + 64*q], 0.0f};
  } else {
    const float* ip = (const float*)inp + (size_t)arr*TLEN;
    #pragma unroll
    for (int q=0;q<4;q++) v[q] = c2{ip[n1 + NA*(j + 64*q)], 0.0f};
  }
  dft4<S>(v[0],v[1],v[2],v[3]);
  #pragma unroll
  for (int r=0;r<4;r++) lds[0][SW(4*j + r)] = v[r];
  __syncthreads();
  { // L = 4
    int k = j & 3;
    c2 w = cis((float)S * TWO_PI * (float)k * (1.0f/16.0f));
    c2 w2 = cmul(w,w), w3 = cmul(w2,w);
    v[0] = lds[0][SW(j)];
    v[1] = cmul(lds[0][SW(j+64)], w);
    v[2] = cmul(lds[0][SW(j+128)], w2);
    v[3] = cmul(lds[0][SW(j+192)], w3);
    dft4<S>(v[0],v[1],v[2],v[3]);
    int base = 4*(j-k)+k;
    #pragma unroll
    for (int r=0;r<4;r++) lds[1][SW(base + 4*r)] = v[r];
  }
  __syncthreads();
  { // L = 16
    int k = j & 15;
    c2 w = cis((float)S * TWO_PI * (float)k * (1.0f/64.0f));
    c2 w2 = cmul(w,w), w3 = cmul(w2,w);
    v[0] = lds[1][SW(j)];
    v[1] = cmul(lds[1][SW(j+64)], w);
    v[2] = cmul(lds[1][SW(j+128)], w2);
    v[3] = cmul(lds[1][SW(j+192)], w3);
    dft4<S>(v[0],v[1],v[2],v[3]);
    int base = 4*(j-k)+k;
    #pragma unroll
    for (int r=0;r<4;r++) lds[0][SW(base + 16*r)] = v[r];
  }
  __syncthreads();
  { // L = 64
    c2 w = cis((float)S * TWO_PI * (float)j * (1.0f/256.0f));
    c2 w2 = cmul(w,w), w3 = cmul(w2,w);
    v[0] = lds[0][SW(j)];
    v[1] = cmul(lds[0][SW(j+64)], w);
    v[2] = cmul(lds[0][SW(j+128)], w2);
    v[3] = cmul(lds[0][SW(j+192)], w3);
    dft4<S>(v[0],v[1],v[2],v[3]);
    if (OUTMODE == 0){
      c2* op = (c2*)outp + (size_t)arr*TLEN + (size_t)n1*NB;
      #pragma unroll
      for (int r=0;r<4;r++){
        int kb = j + 64*r;
        c2 tw = cis((float)S * TWO_PI * (float)(n1*kb) * (1.0f/160000.0f));
        op[kb] = cmul(v[r], tw);
      }
    } else {
      float* op = (float*)outp + (size_t)arr*TLEN + (size_t)n1*NB;
      #pragma unroll
      for (int r=0;r<4;r++){
        c2 z = v[r];
        op[j + 64*r] = sqrtf(z.x*z.x + z.y*z.y) * (1.0f/160000.0f);
      }
    }
  }
}

// ---------------- fused gather + inverse 256-FFT + abs (+ optional forward 256-FFT -> B) --------
// Input A in [kb][n1]; block = (arr, n1-chunk of GCH). 256 threads = 4 wave-groups.
// Tile [GCH][259]: FFT reads lane-consecutive. After the inverse row is consumed, the forward
// FFT's transposed output overwrites the same (dead) tile row; one block barrier before scatter.
#define GCH     16
#define GNCH    40                        // ceil(625/16)
#define GT_S    259
#define G_TILE  (GCH*GT_S)
#define G_LDSB  ((G_TILE + 4*2*272)*8)    // 50560 B dynamic
template<int WRITEB>
__global__ __launch_bounds__(256) void k_fft256g(const c2* __restrict__ inp, float* __restrict__ outp,
                                                 c2* __restrict__ outB){
  extern __shared__ float smemg[];
  c2* tile = (c2*)smemg;                       // [GCH][GT_S]
  c2* scratch = tile + G_TILE;                 // [4][2][272]
  int g = blockIdx.x;
  int arr = g / GNCH, chunk = g - arr*GNCH;
  int n1_0 = chunk*GCH;
  int rows = NA - n1_0; if (rows > GCH) rows = GCH;
  const c2* ip = inp + (size_t)arr*TLEN;
  for (int e = threadIdx.x; e < 256*rows; e += 256){
    int kb = e / rows, i = e - kb*rows;
    tile[i*GT_S + kb] = ip[(size_t)kb*NA + n1_0 + i];
  }
  __syncthreads();
  int gq = threadIdx.x >> 6, j = threadIdx.x & 63;
  c2* lds0 = scratch + gq*544;
  c2* lds1 = lds0 + 272;
  float* op0 = outp + (size_t)arr*TLEN;
  for (int t = 0; t < 4; t++){
    int n1i = gq + 4*t;
    if (n1i >= rows) break;
    int n1 = n1_0 + n1i;
    c2 v[4];
    #pragma unroll
    for (int q=0;q<4;q++) v[q] = tile[n1i*GT_S + j + 64*q];
    dft4<1>(v[0],v[1],v[2],v[3]);
    #pragma unroll
    for (int r=0;r<4;r++) lds0[SW(4*j + r)] = v[r];
    wsync();
    { // L=4
      int k = j & 3;
      c2 w = cis(TWO_PI * (float)k * (1.0f/16.0f));
      c2 w2 = cmul(w,w), w3 = cmul(w2,w);
      v[0] = lds0[SW(j)];
      v[1] = cmul(lds0[SW(j+64)], w);
      v[2] = cmul(lds0[SW(j+128)], w2);
      v[3] = cmul(lds0[SW(j+192)], w3);
      dft4<1>(v[0],v[1],v[2],v[3]);
      int base = 4*(j-k)+k;
      #pragma unroll
      for (int r=0;r<4;r++) lds1[SW(base + 4*r)] = v[r];
    }
    wsync();
    { // L=16
      int k = j & 15;
      c2 w = cis(TWO_PI * (float)k * (1.0f/64.0f));
      c2 w2 = cmul(w,w), w3 = cmul(w2,w);
      v[0] = lds1[SW(j)];
      v[1] = cmul(lds1[SW(j+64)], w);
      v[2] = cmul(lds1[SW(j+128)], w2);
      v[3] = cmul(lds1[SW(j+192)], w3);
      dft4<1>(v[0],v[1],v[2],v[3]);
      int base = 4*(j-k)+k;
      #pragma unroll
      for (int r=0;r<4;r++) lds0[SW(base + 16*r)] = v[r];
    }
    wsync();
    float av[4];
    { // L=64 + abs
      c2 w = cis(TWO_PI * (float)j * (1.0f/256.0f));
      c2 w2 = cmul(w,w), w3 = cmul(w2,w);
      v[0] = lds0[SW(j)];
      v[1] = cmul(lds0[SW(j+64)], w);
      v[2] = cmul(lds0[SW(j+128)], w2);
      v[3] = cmul(lds0[SW(j+192)], w3);
      dft4<1>(v[0],v[1],v[2],v[3]);
      float* op = op0 + (size_t)n1*NB;
      #pragma unroll
      for (int r=0;r<4;r++){
        c2 z = v[r];
        av[r] = sqrtf(z.x*z.x + z.y*z.y) * (1.0f/160000.0f);
        op[j + 64*r] = av[r];
      }
    }
    if (WRITEB){
      wsync();
      // forward 256-FFT of the real row just produced (same positions j+64q)
      #pragma unroll
      for (int q=0;q<4;q++) v[q] = c2{av[q], 0.0f};
      dft4<-1>(v[0],v[1],v[2],v[3]);
      #pragma unroll
      for (int r=0;r<4;r++) lds0[SW(4*j + r)] = v[r];
      wsync();
      { // L=4
        int k = j & 3;
        c2 w = cis(-TWO_PI * (float)k * (1.0f/16.0f));
        c2 w2 = cmul(w,w), w3 = cmul(w2,w);
        v[0] = lds0[SW(j)];
        v[1] = cmul(lds0[SW(j+64)], w);
        v[2] = cmul(lds0[SW(j+128)], w2);
        v[3] = cmul(lds0[SW(j+192)], w3);
        dft4<-1>(v[0],v[1],v[2],v[3]);
        int base = 4*(j-k)+k;
        #pragma unroll
        for (int r=0;r<4;r++) lds1[SW(base + 4*r)] = v[r];
      }
      wsync();
      { // L=16
        int k = j & 15;
        c2 w = cis(-TWO_PI * (float)k * (1.0f/64.0f));
        c2 w2 = cmul(w,w), w3 = cmul(w2,w);
        v[0] = lds1[SW(j)];
        v[1] = cmul(lds1[SW(j+64)], w);
        v[2] = cmul(lds1[SW(j+128)], w2);
        v[3] = cmul(lds1[SW(j+192)], w3);
        dft4<-1>(v[0],v[1],v[2],v[3]);
        int base = 4*(j-k)+k;
        #pragma unroll
        for (int r=0;r<4;r++) lds0[SW(base + 16*r)] = v[r];
      }
      wsync();
      { // L=64 + row twiddle -> overwrite dead tile row (transposed store)
        c2 w = cis(-TWO_PI * (float)j * (1.0f/256.0f));
        c2 w2 = cmul(w,w), w3 = cmul(w2,w);
        v[0] = lds0[SW(j)];
        v[1] = cmul(lds0[SW(j+64)], w);
        v[2] = cmul(lds0[SW(j+128)], w2);
        v[3] = cmul(lds0[SW(j+192)], w3);
        dft4<-1>(v[0],v[1],v[2],v[3]);
        #pragma unroll
        for (int r=0;r<4;r++){
          int kb = j + 64*r;
          c2 tw = cis(-TWO_PI * (float)(n1*kb) * (1.0f/160000.0f));
          tile[n1i*GT_S + kb] = cmul(v[r], tw);
        }
      }
    }
    wsync();
  }
  if (WRITEB){
    __syncthreads();
    c2* op = outB + (size_t)arr*TLEN;
    for (int e = threadIdx.x; e < 256*rows; e += 256){
      int kb = e / rows, i = e - kb*rows;
      op[(size_t)kb*NA + n1_0 + i] = tile[i*GT_S + kb];
    }
  }
}

// ---------------- 625-point row FFT (radix-5 Stockham) ----------------
// FILT: 0 none, 1 psi1 (input Xf), 2 psi2 (input U1h). TW: output twiddle.
// kamax: when TW==0, only outputs n1 <= kamax are written (partial-spectrum store).
template<int S, int FILT, int TW>
__global__ __launch_bounds__(128) void k_fft625(const c2* __restrict__ inp, c2* __restrict__ outp,
                                                int cblk, int BLK, int nj2, int j2base, int scBase,
                                                int kamax){
  __shared__ c2 lds[2][672];
  int g = blockIdx.x;
  int i = g / NB, kb = g - i*NB;
  int j = threadIdx.x;
  c2 a[5], b[5];
  if (j < 125){
    const c2* ip;
    int j1 = 0, j2 = 0;
    if (FILT == 0){
      ip = inp + (size_t)i*TLEN;
    } else if (FILT == 1){
      int bt = i / BLK; j1 = cblk*BLK + (i - bt*BLK);
      ip = inp + (size_t)bt*TLEN;
    } else {
      int g2 = scBase + i;
      int npb = BLK*nj2;
      int bt = g2 / npb, rr = g2 - bt*npb;
      int jloc = rr / nj2; j2 = j2base + (rr - jloc*nj2);
      ip = inp + (size_t)(bt*BLK + jloc)*TLEN;
    }
    ip += (size_t)kb*NA;
    if (FILT == 0){
      #pragma unroll
      for (int q=0;q<5;q++) a[q] = ip[j + 125*q];
      dft5<S>(a, b);
    } else {
      float xi, sig;
      if (FILT == 1){ xi = 0.4f * exp2f(-(float)j1 * 0.0625f); sig = xi * 0.04427378243f; }
      else          { xi = 0.4f * exp2f(-(float)j2);           sig = 0.35f * xi; }
      float inv2s = 0.5f / (sig*sig);
      int klo = (int)((xi - 6.0f*sig) * (float)TLEN); if (klo < 0) klo = 0;
      int khi = (int)((xi + 6.0f*sig) * (float)TLEN) + 1; if (khi > TLEN/2 - 1) khi = TLEN/2 - 1;
      bool any = false;
      #pragma unroll
      for (int q=0;q<5;q++){
        int ka = j + 125*q;
        int k = kb + 256*ka;
        c2 val = c2{0.0f, 0.0f};
        if (k >= klo && k <= khi){
          val = ip[ka];
          float d = (float)k * (1.0f/(float)TLEN) - xi;
          float f = __expf(-d*d*inv2s);
          val.x *= f; val.y *= f;
          any = true;
        }
        a[q] = val;
      }
      if (any){
        dft5<S>(a, b);
      } else {
        #pragma unroll
        for (int r=0;r<5;r++) b[r] = c2{0.0f,0.0f};
      }
    }
    #pragma unroll
    for (int r=0;r<5;r++) lds[0][SW(5*j + r)] = b[r];
  }
  __syncthreads();
  if (j < 125){ // L = 5
    int k = j % 5;
    c2 w = cis((float)S * TWO_PI * (float)k * (1.0f/25.0f));
    c2 w2 = cmul(w,w), w3 = cmul(w2,w), w4 = cmul(w3,w);
    a[0] = lds[0][SW(j)];
    a[1] = cmul(lds[0][SW(j+125)], w);
    a[2] = cmul(lds[0][SW(j+250)], w2);
    a[3] = cmul(lds[0][SW(j+375)], w3);
    a[4] = cmul(lds[0][SW(j+500)], w4);
    dft5<S>(a, b);
    int base = 5*(j-k)+k;
    #pragma unroll
    for (int r=0;r<5;r++) lds[1][SW(base + 5*r)] = b[r];
  }
  __syncthreads();
  if (j < 125){ // L = 25
    int k = j % 25;
    c2 w = cis((float)S * TWO_PI * (float)k * (1.0f/125.0f));
    c2 w2 = cmul(w,w), w3 = cmul(w2,w), w4 = cmul(w3,w);
    a[0] = lds[1][SW(j)];
    a[1] = cmul(lds[1][SW(j+125)], w);
    a[2] = cmul(lds[1][SW(j+250)], w2);
    a[3] = cmul(lds[1][SW(j+375)], w3);
    a[4] = cmul(lds[1][SW(j+500)], w4);
    dft5<S>(a, b);
    int base = 5*(j-k)+k;
    #pragma unroll
    for (int r=0;r<5;r++) lds[0][SW(base + 25*r)] = b[r];
  }
  __syncthreads();
  if (j < 125){ // L = 125
    c2 w = cis((float)S * TWO_PI * (float)j * (1.0f/625.0f));
    c2 w2 = cmul(w,w), w3 = cmul(w2,w), w4 = cmul(w3,w);
    a[0] = lds[0][SW(j)];
    a[1] = cmul(lds[0][SW(j+125)], w);
    a[2] = cmul(lds[0][SW(j+250)], w2);
    a[3] = cmul(lds[0][SW(j+375)], w3);
    a[4] = cmul(lds[0][SW(j+500)], w4);
    dft5<S>(a, b);
    c2* op = outp + (size_t)i*TLEN + (size_t)kb*NA;
    #pragma unroll
    for (int r=0;r<5;r++){
      int n1 = j + 125*r;
      c2 z = b[r];
      if (TW){
        c2 tw = cis((float)S * TWO_PI * (float)(n1*kb) * (1.0f/160000.0f));
        z = cmul(z, tw);
        op[n1] = z;
      } else {
        if (n1 <= kamax) op[n1] = z;
      }
    }
  }
}

// ---------------- complex transpose (x-chain only) ----------------
__global__ __launch_bounds__(256) void k_transpose(const c2* __restrict__ in, c2* __restrict__ out,
                                                   int R, int C, int tilesR, int tilesC){
  __shared__ c2 tile[32][33];
  int bi = blockIdx.x;
  int arr = bi / (tilesR*tilesC);
  int tt = bi - arr*(tilesR*tilesC);
  int tr = tt / tilesC, tc = tt - tr*tilesC;
  const c2* ip = in + (size_t)arr*TLEN;
  c2* op = out + (size_t)arr*TLEN;
  int tx = threadIdx.x & 31, ty = threadIdx.x >> 5;
  #pragma unroll
  for (int i=0;i<4;i++){
    int r = tr*32 + ty + i*8, cc = tc*32 + tx;
    if (r < R && cc < C) tile[ty+i*8][tx] = ip[(size_t)r*C + cc];
  }
  __syncthreads();
  #pragma unroll
  for (int i=0;i<4;i++){
    int r = tc*32 + ty + i*8, cc = tr*32 + tx;
    if (r < C && cc < R) op[(size_t)r*R + cc] = tile[tx][ty+i*8];
  }
}

// ---------------- Gaussian lowpass + decimate-by-64, natural layout (S0 only) ----------------
__global__ __launch_bounds__(256) void k_conv(const float* __restrict__ inp, float* __restrict__ S){
  __shared__ float w[NTAP];
  for (int i=threadIdx.x; i<NTAP; i+=256){
    float d = (float)(i - KC);
    w[i] = 0.015666427f * __expf(-7.7106284e-4f * d * d);
  }
  __syncthreads();
  int g = blockIdx.x;
  int arr = g / 10;
  int t = (g - arr*10)*256 + threadIdx.x;
  if (t >= TD) return;
  int srow = arr * SROWS;
  const float* ip = inp + (size_t)arr*TLEN;
  float acc = 0.0f;
  int n = 64*t - KC; if (n < 0) n += TLEN;
  for (int m=0;m<NTAP;m++){
    acc += ip[n] * w[m];
    n++; if (n == TLEN) n = 0;
  }
  S[(size_t)srow*TD + t] = acc;
}

// ---------------- fused LDS stage + conv for scrambled-layout U (S1/S2 rows) ----------------
#define CONV_NCOL 27
#define CONV_NU   16875
#define CONV_USZ  17138
#define CONV_LDSB ((CONV_USZ + NTAP + 1)*4)
template<int MODE>
__global__ __launch_bounds__(256) void k_conv2(const float* __restrict__ inp, float* __restrict__ S,
                                               int cblk, int BLK, int nj2, int j2base, int scBase){
  extern __shared__ float smem[];
  float* u = smem;
  float* w = smem + CONV_USZ;
  for (int i=threadIdx.x; i<NTAP; i+=256){
    float d = (float)(i - KC);
    w[i] = 0.015666427f * __expf(-7.7106284e-4f * d * d);
  }
  int g = blockIdx.x;
  int arr = g / 10;
  int b = g - arr*10;
  int nlo = 16000*b - KC;
  int n2_0 = (nlo >= 0) ? (nlo/625) : -1;
  const float* ip = inp + (size_t)arr*TLEN;
  for (int e = threadIdx.x; e < CONV_NU; e += 256){
    int n1 = e / CONV_NCOL;
    int c  = e - n1*CONV_NCOL;
    int n2 = n2_0 + c;
    n2 &= 255;
    u[SW64(n1 + 625*c)] = ip[n1*NB + n2];
  }
  __syncthreads();
  int tl = threadIdx.x;
  if (tl >= 250) return;
  int t = 250*b + tl;
  int srow;
  if (MODE == 1){
    int a2 = arr / BLK; int j1 = cblk*BLK + (arr - a2*BLK);
    srow = a2*SROWS + 1 + j1;
  } else {
    int g2 = scBase + arr; int npb = BLK*nj2;
    int a2 = g2/npb, rr = g2 - a2*npb;
    int jloc = rr/nj2; int j2 = j2base + (rr - jloc*nj2);
    int j1 = cblk*BLK + jloc;
    int full = j1 >> 4;
    int cum = 16*(5*full - (full*(full-1))/2) + (j1 & 15)*(5 - full);
    int P = cum + j2 - full - 1;
    srow = a2*SROWS + 97 + P;
  }
  int base = 64*t - KC - 625*n2_0;
  float acc = 0.0f;
  #pragma unroll 4
  for (int m=0;m<NTAP;m++){
    acc += u[SW64(base + m)] * w[m];
  }
  S[(size_t)srow*TD + t] = acc;
}

// ---------------- global min/max + finalize ----------------
__global__ __launch_bounds__(256) void k_minmax1(const float* __restrict__ S, int n, float* pmn, float* pmx){
  __shared__ float smn[256], smx[256];
  float mn = 3.4028235e38f, mx = -3.4028235e38f;
  for (size_t i = (size_t)blockIdx.x*256 + threadIdx.x; i < (size_t)n; i += (size_t)gridDim.x*256){
    float v = S[i]; mn = fminf(mn,v); mx = fmaxf(mx,v);
  }
  smn[threadIdx.x]=mn; smx[threadIdx.x]=mx; __syncthreads();
  for (int s=128;s>0;s>>=1){
    if ((int)threadIdx.x < s){
      smn[threadIdx.x]=fminf(smn[threadIdx.x],smn[threadIdx.x+s]);
      smx[threadIdx.x]=fmaxf(smx[threadIdx.x],smx[threadIdx.x+s]);
    }
    __syncthreads();
  }
  if (threadIdx.x==0){ pmn[blockIdx.x]=smn[0]; pmx[blockIdx.x]=smx[0]; }
}
__global__ __launch_bounds__(256) void k_minmax2(const float* __restrict__ pmn, const float* __restrict__ pmx,
                                                 int nb, float* scal){
  __shared__ float smn[256], smx[256];
  float mn = 3.4028235e38f, mx = -3.4028235e38f;
  for (int i = threadIdx.x; i < nb; i += 256){ mn = fminf(mn,pmn[i]); mx = fmaxf(mx,pmx[i]); }
  smn[threadIdx.x]=mn; smx[threadIdx.x]=mx; __syncthreads();
  for (int s=128;s>0;s>>=1){
    if ((int)threadIdx.x < s){
      smn[threadIdx.x]=fminf(smn[threadIdx.x],smn[threadIdx.x+s]);
      smx[threadIdx.x]=fmaxf(smx[threadIdx.x],smx[threadIdx.x+s]);
    }
    __syncthreads();
  }
  if (threadIdx.x==0){ scal[0]=smn[0]; scal[1]=smx[0]; }
}
__global__ __launch_bounds__(256) void k_final(const float* __restrict__ S, const float* __restrict__ scal,
                                               float* __restrict__ out, int n){
  int i = blockIdx.x*256 + threadIdx.x;
  if (i >= n) return;
  float mn = scal[0];
  float r = scal[1] - mn;
  if (r == 0.0f) r = 1.0f;
  int half = SROWS*TD;
  int a = i / half; int rest = i - a*half;
  out[i] = (S[(size_t)(a & 1)*half + rest] - mn) / r;
}

extern "C" void kernel_launch(void* const* d_in, const int* in_sizes, int n_in,
                              void* d_out, int out_size, void* d_ws, size_t ws_size,
                              hipStream_t stream){
  (void)in_sizes; (void)n_in;
  const float* x = (const float*)d_in[0];

  int BLK = 16;
  while (BLK > 1){
    size_t CH = 2*(size_t)BLK;
    // Xf + A(2CH) + B(CH) + U1h(CH) + Ur(2CH) + Sb + reductions
    size_t needb = 2560000ULL + 2ULL*CH*TLEN*8ULL + CH*TLEN*8ULL + CH*TLEN*8ULL
                 + 2ULL*CH*TLEN*4ULL + 6740000ULL + 8192ULL + 4096ULL;
    if (needb <= ws_size) break;
    BLK >>= 1;
  }
  {
    size_t CH = 2;
    size_t needmin = 2560000ULL + 2ULL*CH*TLEN*8ULL + CH*TLEN*8ULL + CH*TLEN*8ULL
                   + 2ULL*CH*TLEN*4ULL + 6740000ULL + 8192ULL + 4096ULL;
    if (ws_size < needmin) return;
  }
  int CH = 2*BLK;

  char* p = (char*)d_ws;
  auto carve = [&](size_t bytes)->void*{ void* r = (void*)p; p += (bytes + 255) & ~(size_t)255; return r; };
  c2*    Xf  = (c2*)carve(2ULL*TLEN*sizeof(c2));
  c2*    A   = (c2*)carve(2ULL*CH*TLEN*sizeof(c2));      // 2x slots for sc-pair batching
  c2*    B   = (c2*)carve((size_t)CH*TLEN*sizeof(c2));
  c2*    U1h = (c2*)carve((size_t)CH*TLEN*sizeof(c2));
  float* Ur  = (float*)carve(2ULL*CH*TLEN*sizeof(float)); // 2x slots
  float* Sb  = (float*)carve(2ULL*SROWS*TD*sizeof(float));
  float* pmn = (float*)carve(512*4);
  float* pmx = (float*)carve(512*4);
  float* scal = (float*)carve(256);

  // ---- forward FFT of x -> Xf ----
  k_fft256<-1,2,0><<<2*NA, 64, 0, stream>>>((const void*)x, (void*)A);
  k_transpose<<<2*20*8, 256, 0, stream>>>(A, B, NA, NB, 20, 8);
  k_fft625<-1,0,0><<<2*NB, 128, 0, stream>>>(B, Xf, 0,0,0,0,0, 314);  // only ka<=314 read by psi1
  // ---- S0 ----
  k_conv<<<2*10, 256, 0, stream>>>(x, Sb);

  int NCB = 96 / BLK;
  for (int c = 0; c < NCB; c++){
    int cq = (c*BLK)/16;
    int nj2 = 5 - cq;
    int j2base = cq + 1;
    // F3 partial-spectrum bound from the widest psi2 in this block (j2 = j2base)
    float xi2 = 0.4f * exp2f(-(float)j2base);
    int khi2 = (int)(3.1f * xi2 * 160000.0f) + 1; if (khi2 > TLEN/2 - 1) khi2 = TLEN/2 - 1;
    int kamax = (khi2 >> 8) + 1; if (kamax > 624) kamax = 624;
    // ---- order 1 ----
    k_fft625<1,1,1><<<CH*NB, 128, 0, stream>>>(Xf, A, c, BLK, 0,0,0, 624);
    if (nj2 > 0){
      k_fft256g<1><<<CH*GNCH, 256, G_LDSB, stream>>>(A, Ur, B);       // |ifft| -> Ur, fft -> B
      k_conv2<1><<<CH*10, 256, CONV_LDSB, stream>>>(Ur, Sb, c, BLK, 0,0,0);
      k_fft625<-1,0,0><<<CH*NB, 128, 0, stream>>>(B, U1h, 0,0,0,0,0, kamax);
      // ---- order 2, sc batched in pairs ----
      for (int scStart = 0; scStart < nj2; scStart += 2){
        int nsc = nj2 - scStart; if (nsc > 2) nsc = 2;
        k_fft625<1,2,1><<<nsc*CH*NB, 128, 0, stream>>>(U1h, A, c, BLK, nj2, j2base, scStart*CH, 624);
        k_fft256g<0><<<nsc*CH*GNCH, 256, G_LDSB, stream>>>(A, Ur, (c2*)nullptr);
        k_conv2<2><<<nsc*CH*10, 256, CONV_LDSB, stream>>>(Ur, Sb, c, BLK, nj2, j2base, scStart*CH);
      }
    } else {
      k_fft256g<0><<<CH*GNCH, 256, G_LDSB, stream>>>(A, Ur, (c2*)nullptr);
      k_conv2<1><<<CH*10, 256, CONV_LDSB, stream>>>(Ur, Sb, c, BLK, 0,0,0);
    }
  }

  // ---- global min-max normalize (standardize cancels) + tile(3,1,1) ----
  k_minmax1<<<512, 256, 0, stream>>>(Sb, 2*SROWS*TD, pmn, pmx);
  k_minmax2<<<1, 256, 0, stream>>>(pmn, pmx, 512, scal);
  k_final<<<(out_size+255)/256, 256, 0, stream>>>(Sb, scal, (float*)d_out, out_size);
}

// Round 8
// 1591.608 us; speedup vs baseline: 1.2369x; 1.0001x over previous
//
#include <hip/hip_runtime.h>
#include <math.h>

#define TLEN 160000
#define NA 625      // n1 (time rows) / ka (freq elements)
#define NB 256      // n2 (time elements) / kb (freq rows)
#define TD 2500
#define KC 128      // conv half width (~5 sigma_t, sigma_t = 25.46)
#define NTAP 257
#define SROWS 337
#define TWO_PI 6.283185307179586f

struct c2 { float x, y; };

__device__ __forceinline__ c2 cmul(c2 a, c2 b){ return c2{a.x*b.x - a.y*b.y, a.x*b.y + a.y*b.x}; }
__device__ __forceinline__ c2 cmulc(c2 a, c2 b){ return c2{a.x*b.x + a.y*b.y, a.y*b.x - a.x*b.y}; } // a*conj(b)
__device__ __forceinline__ c2 cadd(c2 a, c2 b){ return c2{a.x+b.x, a.y+b.y}; }
__device__ __forceinline__ c2 csub(c2 a, c2 b){ return c2{a.x-b.x, a.y-b.y}; }
__device__ __forceinline__ c2 cmac(c2 acc, c2 v, float wr, float wi){
  acc.x += v.x*wr - v.y*wi; acc.y += v.x*wi + v.y*wr; return acc;
}
__device__ __forceinline__ c2 cis(float ang){ c2 r; __sincosf(ang, &r.y, &r.x); return r; }
__device__ __forceinline__ int SW(int i){ return i + (i >> 4); }
__device__ __forceinline__ int SW64(int i){ return i + (i >> 6); }
// wave-local "syncthreads": scratch is wave-private, so a block barrier is overkill.
__device__ __forceinline__ void wsync(){
  __builtin_amdgcn_wave_barrier();
  __threadfence_block();
  __builtin_amdgcn_wave_barrier();
}

template<int S>
__device__ __forceinline__ void dft4(c2& a0, c2& a1, c2& a2, c2& a3){
  c2 t0 = cadd(a0,a2), t1 = csub(a0,a2), t2 = cadd(a1,a3), t3 = csub(a1,a3);
  float fs = (float)S;
  a0 = cadd(t0,t2); a2 = csub(t0,t2);
  a1 = c2{t1.x - fs*t3.y, t1.y + fs*t3.x};
  a3 = c2{t1.x + fs*t3.y, t1.y - fs*t3.x};
}

template<int S>
__device__ __forceinline__ void dft5(const c2 a[5], c2 b[5]){
  const float C1 = 0.30901699437494742f, C2 = -0.80901699437494745f;
  const float S1 = 0.95105651629515353f * (float)S, S2 = 0.58778525229247314f * (float)S;
  b[0] = cadd(cadd(a[0],a[1]), cadd(cadd(a[2],a[3]),a[4]));
  c2 r;
  r = a[0]; r = cmac(r,a[1],C1, S1); r = cmac(r,a[2],C2, S2); r = cmac(r,a[3],C2,-S2); r = cmac(r,a[4],C1,-S1); b[1]=r;
  r = a[0]; r = cmac(r,a[1],C2, S2); r = cmac(r,a[2],C1,-S1); r = cmac(r,a[3],C1, S1); r = cmac(r,a[4],C2,-S2); b[2]=r;
  r = a[0]; r = cmac(r,a[1],C2,-S2); r = cmac(r,a[2],C1, S1); r = cmac(r,a[3],C1,-S1); r = cmac(r,a[4],C2, S2); b[3]=r;
  r = a[0]; r = cmac(r,a[1],C1,-S1); r = cmac(r,a[2],C2,-S2); r = cmac(r,a[3],C2, S2); r = cmac(r,a[4],C1, S1); b[4]=r;
}

// ---------------- 256-point row FFT (x-chain only) ----------------
template<int S, int INMODE, int OUTMODE>
__global__ __launch_bounds__(64) void k_fft256(const void* __restrict__ inp, void* __restrict__ outp){
  __shared__ c2 lds[2][272];
  int g = blockIdx.x;
  int arr = g / NA, n1 = g - arr*NA;
  int j = threadIdx.x;
  c2 v[4];
  if (INMODE == 0){
    const c2* ip = (const c2*)inp + (size_t)arr*TLEN + (size_t)n1*NB;
    #pragma unroll
    for (int q=0;q<4;q++) v[q] = ip[j + 64*q];
  } else if (INMODE == 1){
    const float* ip = (const float*)inp + (size_t)arr*TLEN + (size_t)n1*NB;
    #pragma unroll
    for (int q=0;q<4;q++) v[q] = c2{ip[j + 64*q], 0.0f};
  } else {
    const float* ip = (const float*)inp + (size_t)arr*TLEN;
    #pragma unroll
    for (int q=0;q<4;q++) v[q] = c2{ip[n1 + NA*(j + 64*q)], 0.0f};
  }
  dft4<S>(v[0],v[1],v[2],v[3]);
  #pragma unroll
  for (int r=0;r<4;r++) lds[0][SW(4*j + r)] = v[r];
  __syncthreads();
  { // L = 4
    int k = j & 3;
    c2 w = cis((float)S * TWO_PI * (float)k * (1.0f/16.0f));
    c2 w2 = cmul(w,w), w3 = cmul(w2,w);
    v[0] = lds[0][SW(j)];
    v[1] = cmul(lds[0][SW(j+64)], w);
    v[2] = cmul(lds[0][SW(j+128)], w2);
    v[3] = cmul(lds[0][SW(j+192)], w3);
    dft4<S>(v[0],v[1],v[2],v[3]);
    int base = 4*(j-k)+k;
    #pragma unroll
    for (int r=0;r<4;r++) lds[1][SW(base + 4*r)] = v[r];
  }
  __syncthreads();
  { // L = 16
    int k = j & 15;
    c2 w = cis((float)S * TWO_PI * (float)k * (1.0f/64.0f));
    c2 w2 = cmul(w,w), w3 = cmul(w2,w);
    v[0] = lds[1][SW(j)];
    v[1] = cmul(lds[1][SW(j+64)], w);
    v[2] = cmul(lds[1][SW(j+128)], w2);
    v[3] = cmul(lds[1][SW(j+192)], w3);
    dft4<S>(v[0],v[1],v[2],v[3]);
    int base = 4*(j-k)+k;
    #pragma unroll
    for (int r=0;r<4;r++) lds[0][SW(base + 16*r)] = v[r];
  }
  __syncthreads();
  { // L = 64
    c2 w = cis((float)S * TWO_PI * (float)j * (1.0f/256.0f));
    c2 w2 = cmul(w,w), w3 = cmul(w2,w);
    v[0] = lds[0][SW(j)];
    v[1] = cmul(lds[0][SW(j+64)], w);
    v[2] = cmul(lds[0][SW(j+128)], w2);
    v[3] = cmul(lds[0][SW(j+192)], w3);
    dft4<S>(v[0],v[1],v[2],v[3]);
    if (OUTMODE == 0){
      c2* op = (c2*)outp + (size_t)arr*TLEN + (size_t)n1*NB;
      #pragma unroll
      for (int r=0;r<4;r++){
        int kb = j + 64*r;
        c2 tw = cis((float)S * TWO_PI * (float)(n1*kb) * (1.0f/160000.0f));
        op[kb] = cmul(v[r], tw);
      }
    } else {
      float* op = (float*)outp + (size_t)arr*TLEN + (size_t)n1*NB;
      #pragma unroll
      for (int r=0;r<4;r++){
        c2 z = v[r];
        op[j + 64*r] = sqrtf(z.x*z.x + z.y*z.y) * (1.0f/160000.0f);
      }
    }
  }
}

// ---------------- fused gather + inverse 256-FFT + abs (+ optional forward 256-FFT -> B) --------
// Tile is split into re/im float planes with stride 273 (== 17 mod 32): all tile accesses
// are b32 at ~2 lanes/bank (free), vs the old c2 tile's structural 4-way conflicts.
// Stage twiddles depend only on lane j -> hoisted out of the row loop; forward pass uses conj.
#define GCH     16
#define GNCH    40                        // ceil(625/16)
#define GTF     273                       // float-plane stride; 273 % 32 = 17
#define G_LDSB  ((2*GCH*GTF + 4*2*272*2)*4)   // 52352 B dynamic
template<int WRITEB>
__global__ __launch_bounds__(256) void k_fft256g(const c2* __restrict__ inp, float* __restrict__ outp,
                                                 c2* __restrict__ outB){
  extern __shared__ float smemg[];
  float* tr = smemg;                           // [GCH][GTF]
  float* ti = smemg + GCH*GTF;                 // [GCH][GTF]
  c2* scratch = (c2*)(smemg + 2*GCH*GTF);      // [4][2][272]
  int g = blockIdx.x;
  int arr = g / GNCH, chunk = g - arr*GNCH;
  int n1_0 = chunk*GCH;
  int rows = NA - n1_0; if (rows > GCH) rows = GCH;
  const c2* ip = inp + (size_t)arr*TLEN;
  for (int e = threadIdx.x; e < 256*rows; e += 256){
    int kb = e / rows, i = e - kb*rows;
    c2 z = ip[(size_t)kb*NA + n1_0 + i];
    tr[i*GTF + kb] = z.x;
    ti[i*GTF + kb] = z.y;
  }
  __syncthreads();
  int gq = threadIdx.x >> 6, j = threadIdx.x & 63;
  c2* lds0 = scratch + gq*544;
  c2* lds1 = lds0 + 272;
  // hoisted stage twiddles (inverse; forward = conjugate)
  c2 w4  = cis(TWO_PI * (float)(j & 3)  * (1.0f/16.0f));
  c2 w4b = cmul(w4,w4),  w4c = cmul(w4b,w4);
  c2 w16 = cis(TWO_PI * (float)(j & 15) * (1.0f/64.0f));
  c2 w16b= cmul(w16,w16), w16c= cmul(w16b,w16);
  c2 w64 = cis(TWO_PI * (float)j * (1.0f/256.0f));
  c2 w64b= cmul(w64,w64), w64c= cmul(w64b,w64);
  int b4 = 4*(j-(j&3))+(j&3);
  int b16= 4*(j-(j&15))+(j&15);
  float* op0 = outp + (size_t)arr*TLEN;
  for (int t = 0; t < 4; t++){
    int n1i = gq + 4*t;
    if (n1i >= rows) break;
    int n1 = n1_0 + n1i;
    c2 v[4];
    #pragma unroll
    for (int q=0;q<4;q++) v[q] = c2{tr[n1i*GTF + j + 64*q], ti[n1i*GTF + j + 64*q]};
    dft4<1>(v[0],v[1],v[2],v[3]);
    #pragma unroll
    for (int r=0;r<4;r++) lds0[SW(4*j + r)] = v[r];
    wsync();
    { // L=4
      v[0] = lds0[SW(j)];
      v[1] = cmul(lds0[SW(j+64)], w4);
      v[2] = cmul(lds0[SW(j+128)], w4b);
      v[3] = cmul(lds0[SW(j+192)], w4c);
      dft4<1>(v[0],v[1],v[2],v[3]);
      #pragma unroll
      for (int r=0;r<4;r++) lds1[SW(b4 + 4*r)] = v[r];
    }
    wsync();
    { // L=16
      v[0] = lds1[SW(j)];
      v[1] = cmul(lds1[SW(j+64)], w16);
      v[2] = cmul(lds1[SW(j+128)], w16b);
      v[3] = cmul(lds1[SW(j+192)], w16c);
      dft4<1>(v[0],v[1],v[2],v[3]);
      #pragma unroll
      for (int r=0;r<4;r++) lds0[SW(b16 + 16*r)] = v[r];
    }
    wsync();
    float av[4];
    { // L=64 + abs
      v[0] = lds0[SW(j)];
      v[1] = cmul(lds0[SW(j+64)], w64);
      v[2] = cmul(lds0[SW(j+128)], w64b);
      v[3] = cmul(lds0[SW(j+192)], w64c);
      dft4<1>(v[0],v[1],v[2],v[3]);
      float* op = op0 + (size_t)n1*NB;
      #pragma unroll
      for (int r=0;r<4;r++){
        c2 z = v[r];
        av[r] = sqrtf(z.x*z.x + z.y*z.y) * (1.0f/160000.0f);
        op[j + 64*r] = av[r];
      }
    }
    if (WRITEB){
      wsync();
      // forward 256-FFT of the real row just produced (conjugate twiddles)
      #pragma unroll
      for (int q=0;q<4;q++) v[q] = c2{av[q], 0.0f};
      dft4<-1>(v[0],v[1],v[2],v[3]);
      #pragma unroll
      for (int r=0;r<4;r++) lds0[SW(4*j + r)] = v[r];
      wsync();
      { // L=4
        v[0] = lds0[SW(j)];
        v[1] = cmulc(lds0[SW(j+64)], w4);
        v[2] = cmulc(lds0[SW(j+128)], w4b);
        v[3] = cmulc(lds0[SW(j+192)], w4c);
        dft4<-1>(v[0],v[1],v[2],v[3]);
        #pragma unroll
        for (int r=0;r<4;r++) lds1[SW(b4 + 4*r)] = v[r];
      }
      wsync();
      { // L=16
        v[0] = lds1[SW(j)];
        v[1] = cmulc(lds1[SW(j+64)], w16);
        v[2] = cmulc(lds1[SW(j+128)], w16b);
        v[3] = cmulc(lds1[SW(j+192)], w16c);
        dft4<-1>(v[0],v[1],v[2],v[3]);
        #pragma unroll
        for (int r=0;r<4;r++) lds0[SW(b16 + 16*r)] = v[r];
      }
      wsync();
      { // L=64 + row twiddle -> overwrite dead tile row (transposed store)
        v[0] = lds0[SW(j)];
        v[1] = cmulc(lds0[SW(j+64)], w64);
        v[2] = cmulc(lds0[SW(j+128)], w64b);
        v[3] = cmulc(lds0[SW(j+192)], w64c);
        dft4<-1>(v[0],v[1],v[2],v[3]);
        #pragma unroll
        for (int r=0;r<4;r++){
          int kb = j + 64*r;
          c2 tw = cis(-TWO_PI * (float)(n1*kb) * (1.0f/160000.0f));
          c2 z = cmul(v[r], tw);
          tr[n1i*GTF + kb] = z.x;
          ti[n1i*GTF + kb] = z.y;
        }
      }
    }
    wsync();
  }
  if (WRITEB){
    __syncthreads();
    c2* op = outB + (size_t)arr*TLEN;
    for (int e = threadIdx.x; e < 256*rows; e += 256){
      int kb = e / rows, i = e - kb*rows;
      op[(size_t)kb*NA + n1_0 + i] = c2{tr[i*GTF + kb], ti[i*GTF + kb]};
    }
  }
}

// ---------------- 625-point row FFT (radix-5 Stockham) ----------------
// FILT: 0 none, 1 psi1 (input Xf), 2 psi2 (input U1h). TW: output twiddle.
// kamax: when TW==0, only outputs n1 <= kamax are written (partial-spectrum store).
// FILT>=1: block-uniform early exit (zero write) when row kb has no in-band bin.
template<int S, int FILT, int TW>
__global__ __launch_bounds__(128) void k_fft625(const c2* __restrict__ inp, c2* __restrict__ outp,
                                                int cblk, int BLK, int nj2, int j2base, int scBase,
                                                int kamax){
  __shared__ c2 lds[2][672];
  int g = blockIdx.x;
  int i = g / NB, kb = g - i*NB;
  int j = threadIdx.x;
  const c2* ip;
  int j1 = 0, j2 = 0;
  if (FILT == 0){
    ip = inp + (size_t)i*TLEN;
  } else if (FILT == 1){
    int bt = i / BLK; j1 = cblk*BLK + (i - bt*BLK);
    ip = inp + (size_t)bt*TLEN;
  } else {
    int g2 = scBase + i;
    int npb = BLK*nj2;
    int bt = g2 / npb, rr = g2 - bt*npb;
    int jloc = rr / nj2; j2 = j2base + (rr - jloc*nj2);
    ip = inp + (size_t)(bt*BLK + jloc)*TLEN;
  }
  ip += (size_t)kb*NA;
  float xi = 0.0f, sig = 0.0f, inv2s = 0.0f;
  int klo = 0, khi = 0;
  if (FILT != 0){
    if (FILT == 1){ xi = 0.4f * exp2f(-(float)j1 * 0.0625f); sig = xi * 0.04427378243f; }
    else          { xi = 0.4f * exp2f(-(float)j2);           sig = 0.35f * xi; }
    inv2s = 0.5f / (sig*sig);
    klo = (int)((xi - 6.0f*sig) * (float)TLEN); if (klo < 0) klo = 0;
    khi = (int)((xi + 6.0f*sig) * (float)TLEN) + 1; if (khi > TLEN/2 - 1) khi = TLEN/2 - 1;
    int kaHi = (khi - kb) >= 0 ? ((khi - kb) >> 8) : -1;
    int kaLo = (klo - kb + 255) >> 8;
    if (kaHi < kaLo || kaHi < 0 || kaLo > 624){
      // whole row out of band -> exact-zero output row (block-uniform, before any barrier)
      c2* op = outp + (size_t)i*TLEN + (size_t)kb*NA;
      for (int e = j; e < NA; e += 128) op[e] = c2{0.0f, 0.0f};
      return;
    }
  }
  c2 a[5], b[5];
  if (j < 125){
    if (FILT == 0){
      #pragma unroll
      for (int q=0;q<5;q++) a[q] = ip[j + 125*q];
      dft5<S>(a, b);
    } else {
      bool any = false;
      #pragma unroll
      for (int q=0;q<5;q++){
        int ka = j + 125*q;
        int k = kb + 256*ka;
        c2 val = c2{0.0f, 0.0f};
        if (k >= klo && k <= khi){
          val = ip[ka];
          float d = (float)k * (1.0f/(float)TLEN) - xi;
          float f = __expf(-d*d*inv2s);
          val.x *= f; val.y *= f;
          any = true;
        }
        a[q] = val;
      }
      if (any){
        dft5<S>(a, b);
      } else {
        #pragma unroll
        for (int r=0;r<5;r++) b[r] = c2{0.0f,0.0f};
      }
    }
    #pragma unroll
    for (int r=0;r<5;r++) lds[0][SW(5*j + r)] = b[r];
  }
  __syncthreads();
  if (j < 125){ // L = 5
    int k = j % 5;
    c2 w = cis((float)S * TWO_PI * (float)k * (1.0f/25.0f));
    c2 w2 = cmul(w,w), w3 = cmul(w2,w), w4 = cmul(w3,w);
    a[0] = lds[0][SW(j)];
    a[1] = cmul(lds[0][SW(j+125)], w);
    a[2] = cmul(lds[0][SW(j+250)], w2);
    a[3] = cmul(lds[0][SW(j+375)], w3);
    a[4] = cmul(lds[0][SW(j+500)], w4);
    dft5<S>(a, b);
    int base = 5*(j-k)+k;
    #pragma unroll
    for (int r=0;r<5;r++) lds[1][SW(base + 5*r)] = b[r];
  }
  __syncthreads();
  if (j < 125){ // L = 25
    int k = j % 25;
    c2 w = cis((float)S * TWO_PI * (float)k * (1.0f/125.0f));
    c2 w2 = cmul(w,w), w3 = cmul(w2,w), w4 = cmul(w3,w);
    a[0] = lds[1][SW(j)];
    a[1] = cmul(lds[1][SW(j+125)], w);
    a[2] = cmul(lds[1][SW(j+250)], w2);
    a[3] = cmul(lds[1][SW(j+375)], w3);
    a[4] = cmul(lds[1][SW(j+500)], w4);
    dft5<S>(a, b);
    int base = 5*(j-k)+k;
    #pragma unroll
    for (int r=0;r<5;r++) lds[0][SW(base + 25*r)] = b[r];
  }
  __syncthreads();
  if (j < 125){ // L = 125
    c2 w = cis((float)S * TWO_PI * (float)j * (1.0f/625.0f));
    c2 w2 = cmul(w,w), w3 = cmul(w2,w), w4 = cmul(w3,w);
    a[0] = lds[0][SW(j)];
    a[1] = cmul(lds[0][SW(j+125)], w);
    a[2] = cmul(lds[0][SW(j+250)], w2);
    a[3] = cmul(lds[0][SW(j+375)], w3);
    a[4] = cmul(lds[0][SW(j+500)], w4);
    dft5<S>(a, b);
    c2* op = outp + (size_t)i*TLEN + (size_t)kb*NA;
    #pragma unroll
    for (int r=0;r<5;r++){
      int n1 = j + 125*r;
      c2 z = b[r];
      if (TW){
        c2 tw = cis((float)S * TWO_PI * (float)(n1*kb) * (1.0f/160000.0f));
        z = cmul(z, tw);
        op[n1] = z;
      } else {
        if (n1 <= kamax) op[n1] = z;
      }
    }
  }
}

// ---------------- complex transpose (x-chain only) ----------------
__global__ __launch_bounds__(256) void k_transpose(const c2* __restrict__ in, c2* __restrict__ out,
                                                   int R, int C, int tilesR, int tilesC){
  __shared__ c2 tile[32][33];
  int bi = blockIdx.x;
  int arr = bi / (tilesR*tilesC);
  int tt = bi - arr*(tilesR*tilesC);
  int tr = tt / tilesC, tc = tt - tr*tilesC;
  const c2* ip = in + (size_t)arr*TLEN;
  c2* op = out + (size_t)arr*TLEN;
  int tx = threadIdx.x & 31, ty = threadIdx.x >> 5;
  #pragma unroll
  for (int i=0;i<4;i++){
    int r = tr*32 + ty + i*8, cc = tc*32 + tx;
    if (r < R && cc < C) tile[ty+i*8][tx] = ip[(size_t)r*C + cc];
  }
  __syncthreads();
  #pragma unroll
  for (int i=0;i<4;i++){
    int r = tc*32 + ty + i*8, cc = tr*32 + tx;
    if (r < C && cc < R) op[(size_t)r*R + cc] = tile[tx][ty+i*8];
  }
}

// ---------------- Gaussian lowpass + decimate-by-64, natural layout (S0 only) ----------------
__global__ __launch_bounds__(256) void k_conv(const float* __restrict__ inp, float* __restrict__ S){
  __shared__ float w[NTAP];
  for (int i=threadIdx.x; i<NTAP; i+=256){
    float d = (float)(i - KC);
    w[i] = 0.015666427f * __expf(-7.7106284e-4f * d * d);
  }
  __syncthreads();
  int g = blockIdx.x;
  int arr = g / 10;
  int t = (g - arr*10)*256 + threadIdx.x;
  if (t >= TD) return;
  int srow = arr * SROWS;
  const float* ip = inp + (size_t)arr*TLEN;
  float acc = 0.0f;
  int n = 64*t - KC; if (n < 0) n += TLEN;
  for (int m=0;m<NTAP;m++){
    acc += ip[n] * w[m];
    n++; if (n == TLEN) n = 0;
  }
  S[(size_t)srow*TD + t] = acc;
}

// ---------------- fused LDS stage + conv for scrambled-layout U (S1/S2 rows) ----------------
#define CONV_NCOL 27
#define CONV_NU   16875
#define CONV_USZ  17138
#define CONV_LDSB ((CONV_USZ + NTAP + 1)*4)
template<int MODE>
__global__ __launch_bounds__(256) void k_conv2(const float* __restrict__ inp, float* __restrict__ S,
                                               int cblk, int BLK, int nj2, int j2base, int scBase){
  extern __shared__ float smem[];
  float* u = smem;
  float* w = smem + CONV_USZ;
  for (int i=threadIdx.x; i<NTAP; i+=256){
    float d = (float)(i - KC);
    w[i] = 0.015666427f * __expf(-7.7106284e-4f * d * d);
  }
  int g = blockIdx.x;
  int arr = g / 10;
  int b = g - arr*10;
  int nlo = 16000*b - KC;
  int n2_0 = (nlo >= 0) ? (nlo/625) : -1;
  const float* ip = inp + (size_t)arr*TLEN;
  for (int e = threadIdx.x; e < CONV_NU; e += 256){
    int n1 = e / CONV_NCOL;
    int c  = e - n1*CONV_NCOL;
    int n2 = n2_0 + c;
    n2 &= 255;
    u[SW64(n1 + 625*c)] = ip[n1*NB + n2];
  }
  __syncthreads();
  int tl = threadIdx.x;
  if (tl >= 250) return;
  int t = 250*b + tl;
  int srow;
  if (MODE == 1){
    int a2 = arr / BLK; int j1 = cblk*BLK + (arr - a2*BLK);
    srow = a2*SROWS + 1 + j1;
  } else {
    int g2 = scBase + arr; int npb = BLK*nj2;
    int a2 = g2/npb, rr = g2 - a2*npb;
    int jloc = rr/nj2; int j2 = j2base + (rr - jloc*nj2);
    int j1 = cblk*BLK + jloc;
    int full = j1 >> 4;
    int cum = 16*(5*full - (full*(full-1))/2) + (j1 & 15)*(5 - full);
    int P = cum + j2 - full - 1;
    srow = a2*SROWS + 97 + P;
  }
  int base = 64*t - KC - 625*n2_0;
  float acc = 0.0f;
  #pragma unroll 4
  for (int m=0;m<NTAP;m++){
    acc += u[SW64(base + m)] * w[m];
  }
  S[(size_t)srow*TD + t] = acc;
}

// ---------------- global min/max + finalize ----------------
__global__ __launch_bounds__(256) void k_minmax1(const float* __restrict__ S, int n, float* pmn, float* pmx){
  __shared__ float smn[256], smx[256];
  float mn = 3.4028235e38f, mx = -3.4028235e38f;
  for (size_t i = (size_t)blockIdx.x*256 + threadIdx.x; i < (size_t)n; i += (size_t)gridDim.x*256){
    float v = S[i]; mn = fminf(mn,v); mx = fmaxf(mx,v);
  }
  smn[threadIdx.x]=mn; smx[threadIdx.x]=mx; __syncthreads();
  for (int s=128;s>0;s>>=1){
    if ((int)threadIdx.x < s){
      smn[threadIdx.x]=fminf(smn[threadIdx.x],smn[threadIdx.x+s]);
      smx[threadIdx.x]=fmaxf(smx[threadIdx.x],smx[threadIdx.x+s]);
    }
    __syncthreads();
  }
  if (threadIdx.x==0){ pmn[blockIdx.x]=smn[0]; pmx[blockIdx.x]=smx[0]; }
}
__global__ __launch_bounds__(256) void k_minmax2(const float* __restrict__ pmn, const float* __restrict__ pmx,
                                                 int nb, float* scal){
  __shared__ float smn[256], smx[256];
  float mn = 3.4028235e38f, mx = -3.4028235e38f;
  for (int i = threadIdx.x; i < nb; i += 256){ mn = fminf(mn,pmn[i]); mx = fmaxf(mx,pmx[i]); }
  smn[threadIdx.x]=mn; smx[threadIdx.x]=mx; __syncthreads();
  for (int s=128;s>0;s>>=1){
    if ((int)threadIdx.x < s){
      smn[threadIdx.x]=fminf(smn[threadIdx.x],smn[threadIdx.x+s]);
      smx[threadIdx.x]=fmaxf(smx[threadIdx.x],smx[threadIdx.x+s]);
    }
    __syncthreads();
  }
  if (threadIdx.x==0){ scal[0]=smn[0]; scal[1]=smx[0]; }
}
__global__ __launch_bounds__(256) void k_final(const float* __restrict__ S, const float* __restrict__ scal,
                                               float* __restrict__ out, int n){
  int i = blockIdx.x*256 + threadIdx.x;
  if (i >= n) return;
  float mn = scal[0];
  float r = scal[1] - mn;
  if (r == 0.0f) r = 1.0f;
  int half = SROWS*TD;
  int a = i / half; int rest = i - a*half;
  out[i] = (S[(size_t)(a & 1)*half + rest] - mn) / r;
}

extern "C" void kernel_launch(void* const* d_in, const int* in_sizes, int n_in,
                              void* d_out, int out_size, void* d_ws, size_t ws_size,
                              hipStream_t stream){
  (void)in_sizes; (void)n_in;
  const float* x = (const float*)d_in[0];

  int BLK = 16;
  while (BLK > 1){
    size_t CH = 2*(size_t)BLK;
    size_t needb = 2560000ULL + 2ULL*CH*TLEN*8ULL + CH*TLEN*8ULL + CH*TLEN*8ULL
                 + 2ULL*CH*TLEN*4ULL + 6740000ULL + 8192ULL + 4096ULL;
    if (needb <= ws_size) break;
    BLK >>= 1;
  }
  {
    size_t CH = 2;
    size_t needmin = 2560000ULL + 2ULL*CH*TLEN*8ULL + CH*TLEN*8ULL + CH*TLEN*8ULL
                   + 2ULL*CH*TLEN*4ULL + 6740000ULL + 8192ULL + 4096ULL;
    if (ws_size < needmin) return;
  }
  int CH = 2*BLK;

  char* p = (char*)d_ws;
  auto carve = [&](size_t bytes)->void*{ void* r = (void*)p; p += (bytes + 255) & ~(size_t)255; return r; };
  c2*    Xf  = (c2*)carve(2ULL*TLEN*sizeof(c2));
  c2*    A   = (c2*)carve(2ULL*CH*TLEN*sizeof(c2));      // 2x slots for sc-pair batching
  c2*    B   = (c2*)carve((size_t)CH*TLEN*sizeof(c2));
  c2*    U1h = (c2*)carve((size_t)CH*TLEN*sizeof(c2));
  float* Ur  = (float*)carve(2ULL*CH*TLEN*sizeof(float)); // 2x slots
  float* Sb  = (float*)carve(2ULL*SROWS*TD*sizeof(float));
  float* pmn = (float*)carve(512*4);
  float* pmx = (float*)carve(512*4);
  float* scal = (float*)carve(256);

  // ---- forward FFT of x -> Xf ----
  k_fft256<-1,2,0><<<2*NA, 64, 0, stream>>>((const void*)x, (void*)A);
  k_transpose<<<2*20*8, 256, 0, stream>>>(A, B, NA, NB, 20, 8);
  k_fft625<-1,0,0><<<2*NB, 128, 0, stream>>>(B, Xf, 0,0,0,0,0, 314);  // only ka<=314 read by psi1
  // ---- S0 ----
  k_conv<<<2*10, 256, 0, stream>>>(x, Sb);

  int NCB = 96 / BLK;
  for (int c = 0; c < NCB; c++){
    int cq = (c*BLK)/16;
    int nj2 = 5 - cq;
    int j2base = cq + 1;
    // F3 partial-spectrum bound from the widest psi2 in this block (j2 = j2base)
    float xi2 = 0.4f * exp2f(-(float)j2base);
    int khi2 = (int)(3.1f * xi2 * 160000.0f) + 1; if (khi2 > TLEN/2 - 1) khi2 = TLEN/2 - 1;
    int kamax = (khi2 >> 8) + 1; if (kamax > 624) kamax = 624;
    // ---- order 1 ----
    k_fft625<1,1,1><<<CH*NB, 128, 0, stream>>>(Xf, A, c, BLK, 0,0,0, 624);
    if (nj2 > 0){
      k_fft256g<1><<<CH*GNCH, 256, G_LDSB, stream>>>(A, Ur, B);       // |ifft| -> Ur, fft -> B
      k_conv2<1><<<CH*10, 256, CONV_LDSB, stream>>>(Ur, Sb, c, BLK, 0,0,0);
      k_fft625<-1,0,0><<<CH*NB, 128, 0, stream>>>(B, U1h, 0,0,0,0,0, kamax);
      // ---- order 2, sc batched in pairs ----
      for (int scStart = 0; scStart < nj2; scStart += 2){
        int nsc = nj2 - scStart; if (nsc > 2) nsc = 2;
        k_fft625<1,2,1><<<nsc*CH*NB, 128, 0, stream>>>(U1h, A, c, BLK, nj2, j2base, scStart*CH, 624);
        k_fft256g<0><<<nsc*CH*GNCH, 256, G_LDSB, stream>>>(A, Ur, (c2*)nullptr);
        k_conv2<2><<<nsc*CH*10, 256, CONV_LDSB, stream>>>(Ur, Sb, c, BLK, nj2, j2base, scStart*CH);
      }
    } else {
      k_fft256g<0><<<CH*GNCH, 256, G_LDSB, stream>>>(A, Ur, (c2*)nullptr);
      k_conv2<1><<<CH*10, 256, CONV_LDSB, stream>>>(Ur, Sb, c, BLK, 0,0,0);
    }
  }

  // ---- global min-max normalize (standardize cancels) + tile(3,1,1) ----
  k_minmax1<<<512, 256, 0, stream>>>(Sb, 2*SROWS*TD, pmn, pmx);
  k_minmax2<<<1, 256, 0, stream>>>(pmn, pmx, 512, scal);
  k_final<<<(out_size+255)/256, 256, 0, stream>>>(Sb, scal, (float*)d_out, out_size);
}

// Round 9
// 1546.044 us; speedup vs baseline: 1.2734x; 1.0295x over previous
//
#include <hip/hip_runtime.h>
#include <math.h>

#define TLEN 160000
#define NA 625      // n1 (time rows) / ka (freq elements)
#define NB 256      // n2 (time elements) / kb (freq rows)
#define TD 2500
#define KC 128      // conv half width (~5 sigma_t, sigma_t = 25.46)
#define NTAP 257
#define SROWS 337
#define TWO_PI 6.283185307179586f

struct c2 { float x, y; };

__device__ __forceinline__ c2 cmul(c2 a, c2 b){ return c2{a.x*b.x - a.y*b.y, a.x*b.y + a.y*b.x}; }
__device__ __forceinline__ c2 cmulc(c2 a, c2 b){ return c2{a.x*b.x + a.y*b.y, a.y*b.x - a.x*b.y}; } // a*conj(b)
__device__ __forceinline__ c2 cadd(c2 a, c2 b){ return c2{a.x+b.x, a.y+b.y}; }
__device__ __forceinline__ c2 csub(c2 a, c2 b){ return c2{a.x-b.x, a.y-b.y}; }
__device__ __forceinline__ c2 cmac(c2 acc, c2 v, float wr, float wi){
  acc.x += v.x*wr - v.y*wi; acc.y += v.x*wi + v.y*wr; return acc;
}
__device__ __forceinline__ c2 cis(float ang){ c2 r; __sincosf(ang, &r.y, &r.x); return r; }
__device__ __forceinline__ int SW(int i){ return i + (i >> 4); }
__device__ __forceinline__ int SW2(int i){ return i + (i >> 2); }   // scratch swizzle: 5j+r mod 32, gcd(5,32)=1
__device__ __forceinline__ int SW64(int i){ return i + (i >> 6); }
// wave-local "syncthreads": scratch is wave-private, so a block barrier is overkill.
__device__ __forceinline__ void wsync(){
  __builtin_amdgcn_wave_barrier();
  __threadfence_block();
  __builtin_amdgcn_wave_barrier();
}

template<int S>
__device__ __forceinline__ void dft4(c2& a0, c2& a1, c2& a2, c2& a3){
  c2 t0 = cadd(a0,a2), t1 = csub(a0,a2), t2 = cadd(a1,a3), t3 = csub(a1,a3);
  float fs = (float)S;
  a0 = cadd(t0,t2); a2 = csub(t0,t2);
  a1 = c2{t1.x - fs*t3.y, t1.y + fs*t3.x};
  a3 = c2{t1.x + fs*t3.y, t1.y - fs*t3.x};
}

template<int S>
__device__ __forceinline__ void dft5(const c2 a[5], c2 b[5]){
  const float C1 = 0.30901699437494742f, C2 = -0.80901699437494745f;
  const float S1 = 0.95105651629515353f * (float)S, S2 = 0.58778525229247314f * (float)S;
  b[0] = cadd(cadd(a[0],a[1]), cadd(cadd(a[2],a[3]),a[4]));
  c2 r;
  r = a[0]; r = cmac(r,a[1],C1, S1); r = cmac(r,a[2],C2, S2); r = cmac(r,a[3],C2,-S2); r = cmac(r,a[4],C1,-S1); b[1]=r;
  r = a[0]; r = cmac(r,a[1],C2, S2); r = cmac(r,a[2],C1,-S1); r = cmac(r,a[3],C1, S1); r = cmac(r,a[4],C2,-S2); b[2]=r;
  r = a[0]; r = cmac(r,a[1],C2,-S2); r = cmac(r,a[2],C1, S1); r = cmac(r,a[3],C1,-S1); r = cmac(r,a[4],C2, S2); b[3]=r;
  r = a[0]; r = cmac(r,a[1],C1,-S1); r = cmac(r,a[2],C2,-S2); r = cmac(r,a[3],C2, S2); r = cmac(r,a[4],C1, S1); b[4]=r;
}

// ---------------- 256-point row FFT (x-chain only) ----------------
template<int S, int INMODE, int OUTMODE>
__global__ __launch_bounds__(64) void k_fft256(const void* __restrict__ inp, void* __restrict__ outp){
  __shared__ c2 lds[2][272];
  int g = blockIdx.x;
  int arr = g / NA, n1 = g - arr*NA;
  int j = threadIdx.x;
  c2 v[4];
  if (INMODE == 0){
    const c2* ip = (const c2*)inp + (size_t)arr*TLEN + (size_t)n1*NB;
    #pragma unroll
    for (int q=0;q<4;q++) v[q] = ip[j + 64*q];
  } else if (INMODE == 1){
    const float* ip = (const float*)inp + (size_t)arr*TLEN + (size_t)n1*NB;
    #pragma unroll
    for (int q=0;q<4;q++) v[q] = c2{ip[j + 64*q], 0.0f};
  } else {
    const float* ip = (const float*)inp + (size_t)arr*TLEN;
    #pragma unroll
    for (int q=0;q<4;q++) v[q] = c2{ip[n1 + NA*(j + 64*q)], 0.0f};
  }
  dft4<S>(v[0],v[1],v[2],v[3]);
  #pragma unroll
  for (int r=0;r<4;r++) lds[0][SW(4*j + r)] = v[r];
  __syncthreads();
  { // L = 4
    int k = j & 3;
    c2 w = cis((float)S * TWO_PI * (float)k * (1.0f/16.0f));
    c2 w2 = cmul(w,w), w3 = cmul(w2,w);
    v[0] = lds[0][SW(j)];
    v[1] = cmul(lds[0][SW(j+64)], w);
    v[2] = cmul(lds[0][SW(j+128)], w2);
    v[3] = cmul(lds[0][SW(j+192)], w3);
    dft4<S>(v[0],v[1],v[2],v[3]);
    int base = 4*(j-k)+k;
    #pragma unroll
    for (int r=0;r<4;r++) lds[1][SW(base + 4*r)] = v[r];
  }
  __syncthreads();
  { // L = 16
    int k = j & 15;
    c2 w = cis((float)S * TWO_PI * (float)k * (1.0f/64.0f));
    c2 w2 = cmul(w,w), w3 = cmul(w2,w);
    v[0] = lds[1][SW(j)];
    v[1] = cmul(lds[1][SW(j+64)], w);
    v[2] = cmul(lds[1][SW(j+128)], w2);
    v[3] = cmul(lds[1][SW(j+192)], w3);
    dft4<S>(v[0],v[1],v[2],v[3]);
    int base = 4*(j-k)+k;
    #pragma unroll
    for (int r=0;r<4;r++) lds[0][SW(base + 16*r)] = v[r];
  }
  __syncthreads();
  { // L = 64
    c2 w = cis((float)S * TWO_PI * (float)j * (1.0f/256.0f));
    c2 w2 = cmul(w,w), w3 = cmul(w2,w);
    v[0] = lds[0][SW(j)];
    v[1] = cmul(lds[0][SW(j+64)], w);
    v[2] = cmul(lds[0][SW(j+128)], w2);
    v[3] = cmul(lds[0][SW(j+192)], w3);
    dft4<S>(v[0],v[1],v[2],v[3]);
    if (OUTMODE == 0){
      c2* op = (c2*)outp + (size_t)arr*TLEN + (size_t)n1*NB;
      #pragma unroll
      for (int r=0;r<4;r++){
        int kb = j + 64*r;
        c2 tw = cis((float)S * TWO_PI * (float)(n1*kb) * (1.0f/160000.0f));
        op[kb] = cmul(v[r], tw);
      }
    } else {
      float* op = (float*)outp + (size_t)arr*TLEN + (size_t)n1*NB;
      #pragma unroll
      for (int r=0;r<4;r++){
        c2 z = v[r];
        op[j + 64*r] = sqrtf(z.x*z.x + z.y*z.y) * (1.0f/160000.0f);
      }
    }
  }
}

// ---------------- fused gather + inverse 256-FFT + abs (+ optional forward 256-FFT -> B) --------
// Tile AND scratch are float planes. Scratch swizzle SW2 makes every stage write pattern hit
// >=32 distinct banks per 2 lanes (stage0: bank=(5j+r)&31, gcd(5,32)=1). Scratch is wave-private
// single-buffer in-place (per-wave LDS ops execute in order). 36.4 KB LDS -> 4 blocks/CU.
#define GCH     12
#define GNCH    53                        // ceil(625/12)
#define GTF     273                       // tile float-plane stride; 273 % 32 = 17
#define SCR     320                       // per-plane scratch floats; SW2(255)+1 = 319
#define G_LDSB  ((2*GCH*GTF + 4*2*SCR)*4) // 36448 B dynamic
template<int WRITEB>
__global__ __launch_bounds__(256) void k_fft256g(const c2* __restrict__ inp, float* __restrict__ outp,
                                                 c2* __restrict__ outB){
  extern __shared__ float smemg[];
  float* tr = smemg;                           // [GCH][GTF]
  float* ti = smemg + GCH*GTF;                 // [GCH][GTF]
  int g = blockIdx.x;
  int arr = g / GNCH, chunk = g - arr*GNCH;
  int n1_0 = chunk*GCH;
  int rows = NA - n1_0; if (rows > GCH) rows = GCH;
  const c2* ip = inp + (size_t)arr*TLEN;
  if (rows == GCH){
    for (int e = threadIdx.x; e < 256*GCH; e += 256){
      int kb = e / GCH, i = e - kb*GCH;        // const divisor
      c2 z = ip[(size_t)kb*NA + n1_0 + i];
      tr[i*GTF + kb] = z.x; ti[i*GTF + kb] = z.y;
    }
  } else {
    for (int e = threadIdx.x; e < 256*rows; e += 256){
      int kb = e / rows, i = e - kb*rows;
      c2 z = ip[(size_t)kb*NA + n1_0 + i];
      tr[i*GTF + kb] = z.x; ti[i*GTF + kb] = z.y;
    }
  }
  __syncthreads();
  int gq = threadIdx.x >> 6, j = threadIdx.x & 63;
  float* sr = smemg + 2*GCH*GTF + gq*(2*SCR);
  float* si = sr + SCR;
  // hoisted stage twiddles (inverse; forward = conjugate via cmulc)
  c2 w4  = cis(TWO_PI * (float)(j & 3)  * (1.0f/16.0f));
  c2 w4b = cmul(w4,w4),  w4c = cmul(w4b,w4);
  c2 w16 = cis(TWO_PI * (float)(j & 15) * (1.0f/64.0f));
  c2 w16b= cmul(w16,w16), w16c= cmul(w16b,w16);
  c2 w64 = cis(TWO_PI * (float)j * (1.0f/256.0f));
  c2 w64b= cmul(w64,w64), w64c= cmul(w64b,w64);
  int b4 = 4*(j-(j&3))+(j&3);
  int b16= 4*(j-(j&15))+(j&15);
  float* op0 = outp + (size_t)arr*TLEN;
  for (int t = 0; t < 3; t++){
    int n1i = gq + 4*t;
    if (n1i >= rows) break;
    int n1 = n1_0 + n1i;
    c2 v[4];
    #pragma unroll
    for (int q=0;q<4;q++) v[q] = c2{tr[n1i*GTF + j + 64*q], ti[n1i*GTF + j + 64*q]};
    dft4<1>(v[0],v[1],v[2],v[3]);
    #pragma unroll
    for (int r=0;r<4;r++){ sr[SW2(4*j + r)] = v[r].x; si[SW2(4*j + r)] = v[r].y; }
    wsync();
    { // L=4
      v[0] = c2{sr[SW2(j)],     si[SW2(j)]};
      v[1] = cmul(c2{sr[SW2(j+64)],  si[SW2(j+64)]},  w4);
      v[2] = cmul(c2{sr[SW2(j+128)], si[SW2(j+128)]}, w4b);
      v[3] = cmul(c2{sr[SW2(j+192)], si[SW2(j+192)]}, w4c);
      dft4<1>(v[0],v[1],v[2],v[3]);
      wsync();
      #pragma unroll
      for (int r=0;r<4;r++){ sr[SW2(b4 + 4*r)] = v[r].x; si[SW2(b4 + 4*r)] = v[r].y; }
    }
    wsync();
    { // L=16
      v[0] = c2{sr[SW2(j)],     si[SW2(j)]};
      v[1] = cmul(c2{sr[SW2(j+64)],  si[SW2(j+64)]},  w16);
      v[2] = cmul(c2{sr[SW2(j+128)], si[SW2(j+128)]}, w16b);
      v[3] = cmul(c2{sr[SW2(j+192)], si[SW2(j+192)]}, w16c);
      dft4<1>(v[0],v[1],v[2],v[3]);
      wsync();
      #pragma unroll
      for (int r=0;r<4;r++){ sr[SW2(b16 + 16*r)] = v[r].x; si[SW2(b16 + 16*r)] = v[r].y; }
    }
    wsync();
    float av[4];
    { // L=64 + abs
      v[0] = c2{sr[SW2(j)],     si[SW2(j)]};
      v[1] = cmul(c2{sr[SW2(j+64)],  si[SW2(j+64)]},  w64);
      v[2] = cmul(c2{sr[SW2(j+128)], si[SW2(j+128)]}, w64b);
      v[3] = cmul(c2{sr[SW2(j+192)], si[SW2(j+192)]}, w64c);
      dft4<1>(v[0],v[1],v[2],v[3]);
      float* op = op0 + (size_t)n1*NB;
      #pragma unroll
      for (int r=0;r<4;r++){
        c2 z = v[r];
        av[r] = sqrtf(z.x*z.x + z.y*z.y) * (1.0f/160000.0f);
        op[j + 64*r] = av[r];
      }
    }
    if (WRITEB){
      wsync();
      // forward 256-FFT of the real row just produced (conjugate twiddles)
      #pragma unroll
      for (int q=0;q<4;q++) v[q] = c2{av[q], 0.0f};
      dft4<-1>(v[0],v[1],v[2],v[3]);
      #pragma unroll
      for (int r=0;r<4;r++){ sr[SW2(4*j + r)] = v[r].x; si[SW2(4*j + r)] = v[r].y; }
      wsync();
      { // L=4
        v[0] = c2{sr[SW2(j)],     si[SW2(j)]};
        v[1] = cmulc(c2{sr[SW2(j+64)],  si[SW2(j+64)]},  w4);
        v[2] = cmulc(c2{sr[SW2(j+128)], si[SW2(j+128)]}, w4b);
        v[3] = cmulc(c2{sr[SW2(j+192)], si[SW2(j+192)]}, w4c);
        dft4<-1>(v[0],v[1],v[2],v[3]);
        wsync();
        #pragma unroll
        for (int r=0;r<4;r++){ sr[SW2(b4 + 4*r)] = v[r].x; si[SW2(b4 + 4*r)] = v[r].y; }
      }
      wsync();
      { // L=16
        v[0] = c2{sr[SW2(j)],     si[SW2(j)]};
        v[1] = cmulc(c2{sr[SW2(j+64)],  si[SW2(j+64)]},  w16);
        v[2] = cmulc(c2{sr[SW2(j+128)], si[SW2(j+128)]}, w16b);
        v[3] = cmulc(c2{sr[SW2(j+192)], si[SW2(j+192)]}, w16c);
        dft4<-1>(v[0],v[1],v[2],v[3]);
        wsync();
        #pragma unroll
        for (int r=0;r<4;r++){ sr[SW2(b16 + 16*r)] = v[r].x; si[SW2(b16 + 16*r)] = v[r].y; }
      }
      wsync();
      { // L=64 + row twiddle -> overwrite dead tile row (transposed store)
        v[0] = c2{sr[SW2(j)],     si[SW2(j)]};
        v[1] = cmulc(c2{sr[SW2(j+64)],  si[SW2(j+64)]},  w64);
        v[2] = cmulc(c2{sr[SW2(j+128)], si[SW2(j+128)]}, w64b);
        v[3] = cmulc(c2{sr[SW2(j+192)], si[SW2(j+192)]}, w64c);
        dft4<-1>(v[0],v[1],v[2],v[3]);
        #pragma unroll
        for (int r=0;r<4;r++){
          int kb = j + 64*r;
          c2 tw = cis(-TWO_PI * (float)(n1*kb) * (1.0f/160000.0f));
          c2 z = cmul(v[r], tw);
          tr[n1i*GTF + kb] = z.x;
          ti[n1i*GTF + kb] = z.y;
        }
      }
    }
    wsync();
  }
  if (WRITEB){
    __syncthreads();
    c2* op = outB + (size_t)arr*TLEN;
    if (rows == GCH){
      for (int e = threadIdx.x; e < 256*GCH; e += 256){
        int kb = e / GCH, i = e - kb*GCH;
        op[(size_t)kb*NA + n1_0 + i] = c2{tr[i*GTF + kb], ti[i*GTF + kb]};
      }
    } else {
      for (int e = threadIdx.x; e < 256*rows; e += 256){
        int kb = e / rows, i = e - kb*rows;
        op[(size_t)kb*NA + n1_0 + i] = c2{tr[i*GTF + kb], ti[i*GTF + kb]};
      }
    }
  }
}

// ---------------- 625-point row FFT (radix-5 Stockham) ----------------
// FILT: 0 none, 1 psi1 (input Xf), 2 psi2 (input U1h). TW: output twiddle.
// kamax: when TW==0, only outputs n1 <= kamax are written (partial-spectrum store).
template<int S, int FILT, int TW>
__global__ __launch_bounds__(128) void k_fft625(const c2* __restrict__ inp, c2* __restrict__ outp,
                                                int cblk, int BLK, int nj2, int j2base, int scBase,
                                                int kamax){
  __shared__ c2 lds[2][672];
  int g = blockIdx.x;
  int i = g / NB, kb = g - i*NB;
  int j = threadIdx.x;
  const c2* ip;
  int j1 = 0, j2 = 0;
  if (FILT == 0){
    ip = inp + (size_t)i*TLEN;
  } else if (FILT == 1){
    int bt = i / BLK; j1 = cblk*BLK + (i - bt*BLK);
    ip = inp + (size_t)bt*TLEN;
  } else {
    int g2 = scBase + i;
    int npb = BLK*nj2;
    int bt = g2 / npb, rr = g2 - bt*npb;
    int jloc = rr / nj2; j2 = j2base + (rr - jloc*nj2);
    ip = inp + (size_t)(bt*BLK + jloc)*TLEN;
  }
  ip += (size_t)kb*NA;
  float xi = 0.0f, sig = 0.0f, inv2s = 0.0f;
  int klo = 0, khi = 0;
  if (FILT != 0){
    if (FILT == 1){ xi = 0.4f * exp2f(-(float)j1 * 0.0625f); sig = xi * 0.04427378243f; }
    else          { xi = 0.4f * exp2f(-(float)j2);           sig = 0.35f * xi; }
    inv2s = 0.5f / (sig*sig);
    klo = (int)((xi - 6.0f*sig) * (float)TLEN); if (klo < 0) klo = 0;
    khi = (int)((xi + 6.0f*sig) * (float)TLEN) + 1; if (khi > TLEN/2 - 1) khi = TLEN/2 - 1;
  }
  c2 a[5], b[5];
  if (j < 125){
    if (FILT == 0){
      #pragma unroll
      for (int q=0;q<5;q++) a[q] = ip[j + 125*q];
      dft5<S>(a, b);
    } else {
      bool any = false;
      #pragma unroll
      for (int q=0;q<5;q++){
        int ka = j + 125*q;
        int k = kb + 256*ka;
        c2 val = c2{0.0f, 0.0f};
        if (k >= klo && k <= khi){
          val = ip[ka];
          float d = (float)k * (1.0f/(float)TLEN) - xi;
          float f = __expf(-d*d*inv2s);
          val.x *= f; val.y *= f;
          any = true;
        }
        a[q] = val;
      }
      if (any){
        dft5<S>(a, b);
      } else {
        #pragma unroll
        for (int r=0;r<5;r++) b[r] = c2{0.0f,0.0f};
      }
    }
    #pragma unroll
    for (int r=0;r<5;r++) lds[0][SW(5*j + r)] = b[r];
  }
  __syncthreads();
  if (j < 125){ // L = 5
    int k = j % 5;
    c2 w = cis((float)S * TWO_PI * (float)k * (1.0f/25.0f));
    c2 w2 = cmul(w,w), w3 = cmul(w2,w), w4 = cmul(w3,w);
    a[0] = lds[0][SW(j)];
    a[1] = cmul(lds[0][SW(j+125)], w);
    a[2] = cmul(lds[0][SW(j+250)], w2);
    a[3] = cmul(lds[0][SW(j+375)], w3);
    a[4] = cmul(lds[0][SW(j+500)], w4);
    dft5<S>(a, b);
    int base = 5*(j-k)+k;
    #pragma unroll
    for (int r=0;r<5;r++) lds[1][SW(base + 5*r)] = b[r];
  }
  __syncthreads();
  if (j < 125){ // L = 25
    int k = j % 25;
    c2 w = cis((float)S * TWO_PI * (float)k * (1.0f/125.0f));
    c2 w2 = cmul(w,w), w3 = cmul(w2,w), w4 = cmul(w3,w);
    a[0] = lds[1][SW(j)];
    a[1] = cmul(lds[1][SW(j+125)], w);
    a[2] = cmul(lds[1][SW(j+250)], w2);
    a[3] = cmul(lds[1][SW(j+375)], w3);
    a[4] = cmul(lds[1][SW(j+500)], w4);
    dft5<S>(a, b);
    int base = 5*(j-k)+k;
    #pragma unroll
    for (int r=0;r<5;r++) lds[0][SW(base + 25*r)] = b[r];
  }
  __syncthreads();
  if (j < 125){ // L = 125
    c2 w = cis((float)S * TWO_PI * (float)j * (1.0f/625.0f));
    c2 w2 = cmul(w,w), w3 = cmul(w2,w), w4 = cmul(w3,w);
    a[0] = lds[0][SW(j)];
    a[1] = cmul(lds[0][SW(j+125)], w);
    a[2] = cmul(lds[0][SW(j+250)], w2);
    a[3] = cmul(lds[0][SW(j+375)], w3);
    a[4] = cmul(lds[0][SW(j+500)], w4);
    dft5<S>(a, b);
    c2* op = outp + (size_t)i*TLEN + (size_t)kb*NA;
    #pragma unroll
    for (int r=0;r<5;r++){
      int n1 = j + 125*r;
      c2 z = b[r];
      if (TW){
        c2 tw = cis((float)S * TWO_PI * (float)(n1*kb) * (1.0f/160000.0f));
        z = cmul(z, tw);
        op[n1] = z;
      } else {
        if (n1 <= kamax) op[n1] = z;
      }
    }
  }
}

// ---------------- complex transpose (x-chain only) ----------------
__global__ __launch_bounds__(256) void k_transpose(const c2* __restrict__ in, c2* __restrict__ out,
                                                   int R, int C, int tilesR, int tilesC){
  __shared__ c2 tile[32][33];
  int bi = blockIdx.x;
  int arr = bi / (tilesR*tilesC);
  int tt = bi - arr*(tilesR*tilesC);
  int tr = tt / tilesC, tc = tt - tr*tilesC;
  const c2* ip = in + (size_t)arr*TLEN;
  c2* op = out + (size_t)arr*TLEN;
  int tx = threadIdx.x & 31, ty = threadIdx.x >> 5;
  #pragma unroll
  for (int i=0;i<4;i++){
    int r = tr*32 + ty + i*8, cc = tc*32 + tx;
    if (r < R && cc < C) tile[ty+i*8][tx] = ip[(size_t)r*C + cc];
  }
  __syncthreads();
  #pragma unroll
  for (int i=0;i<4;i++){
    int r = tc*32 + ty + i*8, cc = tr*32 + tx;
    if (r < C && cc < R) op[(size_t)r*R + cc] = tile[tx][ty+i*8];
  }
}

// ---------------- Gaussian lowpass + decimate-by-64, natural layout (S0 only) ----------------
__global__ __launch_bounds__(256) void k_conv(const float* __restrict__ inp, float* __restrict__ S){
  __shared__ float w[NTAP];
  for (int i=threadIdx.x; i<NTAP; i+=256){
    float d = (float)(i - KC);
    w[i] = 0.015666427f * __expf(-7.7106284e-4f * d * d);
  }
  __syncthreads();
  int g = blockIdx.x;
  int arr = g / 10;
  int t = (g - arr*10)*256 + threadIdx.x;
  if (t >= TD) return;
  int srow = arr * SROWS;
  const float* ip = inp + (size_t)arr*TLEN;
  float acc = 0.0f;
  int n = 64*t - KC; if (n < 0) n += TLEN;
  for (int m=0;m<NTAP;m++){
    acc += ip[n] * w[m];
    n++; if (n == TLEN) n = 0;
  }
  S[(size_t)srow*TD + t] = acc;
}

// ---------------- fused LDS stage + conv for scrambled-layout U (S1/S2 rows) ----------------
#define CONV_NCOL 27
#define CONV_NU   16875
#define CONV_USZ  17138
#define CONV_LDSB ((CONV_USZ + NTAP + 1)*4)
template<int MODE>
__global__ __launch_bounds__(256) void k_conv2(const float* __restrict__ inp, float* __restrict__ S,
                                               int cblk, int BLK, int nj2, int j2base, int scBase){
  extern __shared__ float smem[];
  float* u = smem;
  float* w = smem + CONV_USZ;
  for (int i=threadIdx.x; i<NTAP; i+=256){
    float d = (float)(i - KC);
    w[i] = 0.015666427f * __expf(-7.7106284e-4f * d * d);
  }
  int g = blockIdx.x;
  int arr = g / 10;
  int b = g - arr*10;
  int nlo = 16000*b - KC;
  int n2_0 = (nlo >= 0) ? (nlo/625) : -1;
  const float* ip = inp + (size_t)arr*TLEN;
  for (int e = threadIdx.x; e < CONV_NU; e += 256){
    int n1 = e / CONV_NCOL;
    int c  = e - n1*CONV_NCOL;
    int n2 = n2_0 + c;
    n2 &= 255;
    u[SW64(n1 + 625*c)] = ip[n1*NB + n2];
  }
  __syncthreads();
  int tl = threadIdx.x;
  if (tl >= 250) return;
  int t = 250*b + tl;
  int srow;
  if (MODE == 1){
    int a2 = arr / BLK; int j1 = cblk*BLK + (arr - a2*BLK);
    srow = a2*SROWS + 1 + j1;
  } else {
    int g2 = scBase + arr; int npb = BLK*nj2;
    int a2 = g2/npb, rr = g2 - a2*npb;
    int jloc = rr/nj2; int j2 = j2base + (rr - jloc*nj2);
    int j1 = cblk*BLK + jloc;
    int full = j1 >> 4;
    int cum = 16*(5*full - (full*(full-1))/2) + (j1 & 15)*(5 - full);
    int P = cum + j2 - full - 1;
    srow = a2*SROWS + 97 + P;
  }
  int base = 64*t - KC - 625*n2_0;
  float acc = 0.0f;
  #pragma unroll 4
  for (int m=0;m<NTAP;m++){
    acc += u[SW64(base + m)] * w[m];
  }
  S[(size_t)srow*TD + t] = acc;
}

// ---------------- global min/max + finalize ----------------
__global__ __launch_bounds__(256) void k_minmax1(const float* __restrict__ S, int n, float* pmn, float* pmx){
  __shared__ float smn[256], smx[256];
  float mn = 3.4028235e38f, mx = -3.4028235e38f;
  for (size_t i = (size_t)blockIdx.x*256 + threadIdx.x; i < (size_t)n; i += (size_t)gridDim.x*256){
    float v = S[i]; mn = fminf(mn,v); mx = fmaxf(mx,v);
  }
  smn[threadIdx.x]=mn; smx[threadIdx.x]=mx; __syncthreads();
  for (int s=128;s>0;s>>=1){
    if ((int)threadIdx.x < s){
      smn[threadIdx.x]=fminf(smn[threadIdx.x],smn[threadIdx.x+s]);
      smx[threadIdx.x]=fmaxf(smx[threadIdx.x],smx[threadIdx.x+s]);
    }
    __syncthreads();
  }
  if (threadIdx.x==0){ pmn[blockIdx.x]=smn[0]; pmx[blockIdx.x]=smx[0]; }
}
__global__ __launch_bounds__(256) void k_minmax2(const float* __restrict__ pmn, const float* __restrict__ pmx,
                                                 int nb, float* scal){
  __shared__ float smn[256], smx[256];
  float mn = 3.4028235e38f, mx = -3.4028235e38f;
  for (int i = threadIdx.x; i < nb; i += 256){ mn = fminf(mn,pmn[i]); mx = fmaxf(mx,pmx[i]); }
  smn[threadIdx.x]=mn; smx[threadIdx.x]=mx; __syncthreads();
  for (int s=128;s>0;s>>=1){
    if ((int)threadIdx.x < s){
      smn[threadIdx.x]=fminf(smn[threadIdx.x],smn[threadIdx.x+s]);
      smx[threadIdx.x]=fmaxf(smx[threadIdx.x],smx[threadIdx.x+s]);
    }
    __syncthreads();
  }
  if (threadIdx.x==0){ scal[0]=smn[0]; scal[1]=smx[0]; }
}
__global__ __launch_bounds__(256) void k_final(const float* __restrict__ S, const float* __restrict__ scal,
                                               float* __restrict__ out, int n){
  int i = blockIdx.x*256 + threadIdx.x;
  if (i >= n) return;
  float mn = scal[0];
  float r = scal[1] - mn;
  if (r == 0.0f) r = 1.0f;
  int half = SROWS*TD;
  int a = i / half; int rest = i - a*half;
  out[i] = (S[(size_t)(a & 1)*half + rest] - mn) / r;
}

extern "C" void kernel_launch(void* const* d_in, const int* in_sizes, int n_in,
                              void* d_out, int out_size, void* d_ws, size_t ws_size,
                              hipStream_t stream){
  (void)in_sizes; (void)n_in;
  const float* x = (const float*)d_in[0];

  int BLK = 16;
  while (BLK > 1){
    size_t CH = 2*(size_t)BLK;
    size_t needb = 2560000ULL + 2ULL*CH*TLEN*8ULL + CH*TLEN*8ULL + CH*TLEN*8ULL
                 + 2ULL*CH*TLEN*4ULL + 6740000ULL + 8192ULL + 4096ULL;
    if (needb <= ws_size) break;
    BLK >>= 1;
  }
  {
    size_t CH = 2;
    size_t needmin = 2560000ULL + 2ULL*CH*TLEN*8ULL + CH*TLEN*8ULL + CH*TLEN*8ULL
                   + 2ULL*CH*TLEN*4ULL + 6740000ULL + 8192ULL + 4096ULL;
    if (ws_size < needmin) return;
  }
  int CH = 2*BLK;

  char* p = (char*)d_ws;
  auto carve = [&](size_t bytes)->void*{ void* r = (void*)p; p += (bytes + 255) & ~(size_t)255; return r; };
  c2*    Xf  = (c2*)carve(2ULL*TLEN*sizeof(c2));
  c2*    A   = (c2*)carve(2ULL*CH*TLEN*sizeof(c2));      // 2x slots for sc-pair batching
  c2*    B   = (c2*)carve((size_t)CH*TLEN*sizeof(c2));
  c2*    U1h = (c2*)carve((size_t)CH*TLEN*sizeof(c2));
  float* Ur  = (float*)carve(2ULL*CH*TLEN*sizeof(float)); // 2x slots
  float* Sb  = (float*)carve(2ULL*SROWS*TD*sizeof(float));
  float* pmn = (float*)carve(512*4);
  float* pmx = (float*)carve(512*4);
  float* scal = (float*)carve(256);

  // ---- forward FFT of x -> Xf ----
  k_fft256<-1,2,0><<<2*NA, 64, 0, stream>>>((const void*)x, (void*)A);
  k_transpose<<<2*20*8, 256, 0, stream>>>(A, B, NA, NB, 20, 8);
  k_fft625<-1,0,0><<<2*NB, 128, 0, stream>>>(B, Xf, 0,0,0,0,0, 314);  // only ka<=314 read by psi1
  // ---- S0 ----
  k_conv<<<2*10, 256, 0, stream>>>(x, Sb);

  int NCB = 96 / BLK;
  for (int c = 0; c < NCB; c++){
    int cq = (c*BLK)/16;
    int nj2 = 5 - cq;
    int j2base = cq + 1;
    // F3 partial-spectrum bound from the widest psi2 in this block (j2 = j2base)
    float xi2 = 0.4f * exp2f(-(float)j2base);
    int khi2 = (int)(3.1f * xi2 * 160000.0f) + 1; if (khi2 > TLEN/2 - 1) khi2 = TLEN/2 - 1;
    int kamax = (khi2 >> 8) + 1; if (kamax > 624) kamax = 624;
    // ---- order 1 ----
    k_fft625<1,1,1><<<CH*NB, 128, 0, stream>>>(Xf, A, c, BLK, 0,0,0, 624);
    if (nj2 > 0){
      k_fft256g<1><<<CH*GNCH, 256, G_LDSB, stream>>>(A, Ur, B);       // |ifft| -> Ur, fft -> B
      k_conv2<1><<<CH*10, 256, CONV_LDSB, stream>>>(Ur, Sb, c, BLK, 0,0,0);
      k_fft625<-1,0,0><<<CH*NB, 128, 0, stream>>>(B, U1h, 0,0,0,0,0, kamax);
      // ---- order 2, sc batched in pairs ----
      for (int scStart = 0; scStart < nj2; scStart += 2){
        int nsc = nj2 - scStart; if (nsc > 2) nsc = 2;
        k_fft625<1,2,1><<<nsc*CH*NB, 128, 0, stream>>>(U1h, A, c, BLK, nj2, j2base, scStart*CH, 624);
        k_fft256g<0><<<nsc*CH*GNCH, 256, G_LDSB, stream>>>(A, Ur, (c2*)nullptr);
        k_conv2<2><<<nsc*CH*10, 256, CONV_LDSB, stream>>>(Ur, Sb, c, BLK, nj2, j2base, scStart*CH);
      }
    } else {
      k_fft256g<0><<<CH*GNCH, 256, G_LDSB, stream>>>(A, Ur, (c2*)nullptr);
      k_conv2<1><<<CH*10, 256, CONV_LDSB, stream>>>(Ur, Sb, c, BLK, 0,0,0);
    }
  }

  // ---- global min-max normalize (standardize cancels) + tile(3,1,1) ----
  k_minmax1<<<512, 256, 0, stream>>>(Sb, 2*SROWS*TD, pmn, pmx);
  k_minmax2<<<1, 256, 0, stream>>>(pmn, pmx, 512, scal);
  k_final<<<(out_size+255)/256, 256, 0, stream>>>(Sb, scal, (float*)d_out, out_size);
}

// Round 10
// 1479.006 us; speedup vs baseline: 1.3311x; 1.0453x over previous
//
#include <hip/hip_runtime.h>
#include <math.h>

#define TLEN 160000
#define NA 625      // n1 (time rows) / ka (freq elements)
#define NB 256      // n2 (time elements) / kb (freq rows)
#define TD 2500
#define KC 128      // conv half width (~5 sigma_t, sigma_t = 25.46)
#define NTAP 257
#define SROWS 337
#define TWO_PI 6.283185307179586f

struct c2 { float x, y; };

__device__ __forceinline__ c2 cmul(c2 a, c2 b){ return c2{a.x*b.x - a.y*b.y, a.x*b.y + a.y*b.x}; }
__device__ __forceinline__ c2 cmulc(c2 a, c2 b){ return c2{a.x*b.x + a.y*b.y, a.y*b.x - a.x*b.y}; } // a*conj(b)
__device__ __forceinline__ c2 cadd(c2 a, c2 b){ return c2{a.x+b.x, a.y+b.y}; }
__device__ __forceinline__ c2 csub(c2 a, c2 b){ return c2{a.x-b.x, a.y-b.y}; }
__device__ __forceinline__ c2 cmac(c2 acc, c2 v, float wr, float wi){
  acc.x += v.x*wr - v.y*wi; acc.y += v.x*wi + v.y*wr; return acc;
}
__device__ __forceinline__ c2 cis(float ang){ c2 r; __sincosf(ang, &r.y, &r.x); return r; }
__device__ __forceinline__ int SW(int i){ return i + (i >> 4); }
__device__ __forceinline__ int SW2(int i){ return i + (i >> 2); }   // float-plane swizzle, gcd(5,32)=1 patterns
__device__ __forceinline__ int SW64(int i){ return i + (i >> 6); }
// wave-local "syncthreads": scratch is wave-private, so a block barrier is overkill.
__device__ __forceinline__ void wsync(){
  __builtin_amdgcn_wave_barrier();
  __threadfence_block();
  __builtin_amdgcn_wave_barrier();
}

template<int S>
__device__ __forceinline__ void dft4(c2& a0, c2& a1, c2& a2, c2& a3){
  c2 t0 = cadd(a0,a2), t1 = csub(a0,a2), t2 = cadd(a1,a3), t3 = csub(a1,a3);
  float fs = (float)S;
  a0 = cadd(t0,t2); a2 = csub(t0,t2);
  a1 = c2{t1.x - fs*t3.y, t1.y + fs*t3.x};
  a3 = c2{t1.x + fs*t3.y, t1.y - fs*t3.x};
}

template<int S>
__device__ __forceinline__ void dft5(const c2 a[5], c2 b[5]){
  const float C1 = 0.30901699437494742f, C2 = -0.80901699437494745f;
  const float S1 = 0.95105651629515353f * (float)S, S2 = 0.58778525229247314f * (float)S;
  b[0] = cadd(cadd(a[0],a[1]), cadd(cadd(a[2],a[3]),a[4]));
  c2 r;
  r = a[0]; r = cmac(r,a[1],C1, S1); r = cmac(r,a[2],C2, S2); r = cmac(r,a[3],C2,-S2); r = cmac(r,a[4],C1,-S1); b[1]=r;
  r = a[0]; r = cmac(r,a[1],C2, S2); r = cmac(r,a[2],C1,-S1); r = cmac(r,a[3],C1, S1); r = cmac(r,a[4],C2,-S2); b[2]=r;
  r = a[0]; r = cmac(r,a[1],C2,-S2); r = cmac(r,a[2],C1, S1); r = cmac(r,a[3],C1,-S1); r = cmac(r,a[4],C2, S2); b[3]=r;
  r = a[0]; r = cmac(r,a[1],C1,-S1); r = cmac(r,a[2],C2,-S2); r = cmac(r,a[3],C2, S2); r = cmac(r,a[4],C1, S1); b[4]=r;
}

// ---------------- 256-point row FFT (x-chain only) ----------------
template<int S, int INMODE, int OUTMODE>
__global__ __launch_bounds__(64) void k_fft256(const void* __restrict__ inp, void* __restrict__ outp){
  __shared__ c2 lds[2][272];
  int g = blockIdx.x;
  int arr = g / NA, n1 = g - arr*NA;
  int j = threadIdx.x;
  c2 v[4];
  if (INMODE == 0){
    const c2* ip = (const c2*)inp + (size_t)arr*TLEN + (size_t)n1*NB;
    #pragma unroll
    for (int q=0;q<4;q++) v[q] = ip[j + 64*q];
  } else if (INMODE == 1){
    const float* ip = (const float*)inp + (size_t)arr*TLEN + (size_t)n1*NB;
    #pragma unroll
    for (int q=0;q<4;q++) v[q] = c2{ip[j + 64*q], 0.0f};
  } else {
    const float* ip = (const float*)inp + (size_t)arr*TLEN;
    #pragma unroll
    for (int q=0;q<4;q++) v[q] = c2{ip[n1 + NA*(j + 64*q)], 0.0f};
  }
  dft4<S>(v[0],v[1],v[2],v[3]);
  #pragma unroll
  for (int r=0;r<4;r++) lds[0][SW(4*j + r)] = v[r];
  __syncthreads();
  { // L = 4
    int k = j & 3;
    c2 w = cis((float)S * TWO_PI * (float)k * (1.0f/16.0f));
    c2 w2 = cmul(w,w), w3 = cmul(w2,w);
    v[0] = lds[0][SW(j)];
    v[1] = cmul(lds[0][SW(j+64)], w);
    v[2] = cmul(lds[0][SW(j+128)], w2);
    v[3] = cmul(lds[0][SW(j+192)], w3);
    dft4<S>(v[0],v[1],v[2],v[3]);
    int base = 4*(j-k)+k;
    #pragma unroll
    for (int r=0;r<4;r++) lds[1][SW(base + 4*r)] = v[r];
  }
  __syncthreads();
  { // L = 16
    int k = j & 15;
    c2 w = cis((float)S * TWO_PI * (float)k * (1.0f/64.0f));
    c2 w2 = cmul(w,w), w3 = cmul(w2,w);
    v[0] = lds[1][SW(j)];
    v[1] = cmul(lds[1][SW(j+64)], w);
    v[2] = cmul(lds[1][SW(j+128)], w2);
    v[3] = cmul(lds[1][SW(j+192)], w3);
    dft4<S>(v[0],v[1],v[2],v[3]);
    int base = 4*(j-k)+k;
    #pragma unroll
    for (int r=0;r<4;r++) lds[0][SW(base + 16*r)] = v[r];
  }
  __syncthreads();
  { // L = 64
    c2 w = cis((float)S * TWO_PI * (float)j * (1.0f/256.0f));
    c2 w2 = cmul(w,w), w3 = cmul(w2,w);
    v[0] = lds[0][SW(j)];
    v[1] = cmul(lds[0][SW(j+64)], w);
    v[2] = cmul(lds[0][SW(j+128)], w2);
    v[3] = cmul(lds[0][SW(j+192)], w3);
    dft4<S>(v[0],v[1],v[2],v[3]);
    if (OUTMODE == 0){
      c2* op = (c2*)outp + (size_t)arr*TLEN + (size_t)n1*NB;
      #pragma unroll
      for (int r=0;r<4;r++){
        int kb = j + 64*r;
        c2 tw = cis((float)S * TWO_PI * (float)(n1*kb) * (1.0f/160000.0f));
        op[kb] = cmul(v[r], tw);
      }
    } else {
      float* op = (float*)outp + (size_t)arr*TLEN + (size_t)n1*NB;
      #pragma unroll
      for (int r=0;r<4;r++){
        c2 z = v[r];
        op[j + 64*r] = sqrtf(z.x*z.x + z.y*z.y) * (1.0f/160000.0f);
      }
    }
  }
}

// ---------------- fused gather + inverse 256-FFT + abs (+ optional forward 256-FFT -> B) --------
#define GCH     12
#define GNCH    53                        // ceil(625/12)
#define GTF     273                       // tile float-plane stride; 273 % 32 = 17
#define SCR     320                       // per-plane scratch floats; SW2(255)+1 = 319
#define G_LDSB  ((2*GCH*GTF + 4*2*SCR)*4) // 36448 B dynamic
template<int WRITEB>
__global__ __launch_bounds__(256) void k_fft256g(const c2* __restrict__ inp, float* __restrict__ outp,
                                                 c2* __restrict__ outB){
  extern __shared__ float smemg[];
  float* tr = smemg;                           // [GCH][GTF]
  float* ti = smemg + GCH*GTF;                 // [GCH][GTF]
  int g = blockIdx.x;
  int arr = g / GNCH, chunk = g - arr*GNCH;
  int n1_0 = chunk*GCH;
  int rows = NA - n1_0; if (rows > GCH) rows = GCH;
  const c2* ip = inp + (size_t)arr*TLEN;
  if (rows == GCH){
    for (int e = threadIdx.x; e < 256*GCH; e += 256){
      int kb = e / GCH, i = e - kb*GCH;        // const divisor
      c2 z = ip[(size_t)kb*NA + n1_0 + i];
      tr[i*GTF + kb] = z.x; ti[i*GTF + kb] = z.y;
    }
  } else {
    for (int e = threadIdx.x; e < 256*rows; e += 256){
      int kb = e / rows, i = e - kb*rows;
      c2 z = ip[(size_t)kb*NA + n1_0 + i];
      tr[i*GTF + kb] = z.x; ti[i*GTF + kb] = z.y;
    }
  }
  __syncthreads();
  int gq = threadIdx.x >> 6, j = threadIdx.x & 63;
  float* sr = smemg + 2*GCH*GTF + gq*(2*SCR);
  float* si = sr + SCR;
  // hoisted stage twiddles (inverse; forward = conjugate via cmulc)
  c2 w4  = cis(TWO_PI * (float)(j & 3)  * (1.0f/16.0f));
  c2 w4b = cmul(w4,w4),  w4c = cmul(w4b,w4);
  c2 w16 = cis(TWO_PI * (float)(j & 15) * (1.0f/64.0f));
  c2 w16b= cmul(w16,w16), w16c= cmul(w16b,w16);
  c2 w64 = cis(TWO_PI * (float)j * (1.0f/256.0f));
  c2 w64b= cmul(w64,w64), w64c= cmul(w64b,w64);
  int b4 = 4*(j-(j&3))+(j&3);
  int b16= 4*(j-(j&15))+(j&15);
  float* op0 = outp + (size_t)arr*TLEN;
  for (int t = 0; t < 3; t++){
    int n1i = gq + 4*t;
    if (n1i >= rows) break;
    int n1 = n1_0 + n1i;
    c2 v[4];
    #pragma unroll
    for (int q=0;q<4;q++) v[q] = c2{tr[n1i*GTF + j + 64*q], ti[n1i*GTF + j + 64*q]};
    dft4<1>(v[0],v[1],v[2],v[3]);
    #pragma unroll
    for (int r=0;r<4;r++){ sr[SW2(4*j + r)] = v[r].x; si[SW2(4*j + r)] = v[r].y; }
    wsync();
    { // L=4
      v[0] = c2{sr[SW2(j)],     si[SW2(j)]};
      v[1] = cmul(c2{sr[SW2(j+64)],  si[SW2(j+64)]},  w4);
      v[2] = cmul(c2{sr[SW2(j+128)], si[SW2(j+128)]}, w4b);
      v[3] = cmul(c2{sr[SW2(j+192)], si[SW2(j+192)]}, w4c);
      dft4<1>(v[0],v[1],v[2],v[3]);
      wsync();
      #pragma unroll
      for (int r=0;r<4;r++){ sr[SW2(b4 + 4*r)] = v[r].x; si[SW2(b4 + 4*r)] = v[r].y; }
    }
    wsync();
    { // L=16
      v[0] = c2{sr[SW2(j)],     si[SW2(j)]};
      v[1] = cmul(c2{sr[SW2(j+64)],  si[SW2(j+64)]},  w16);
      v[2] = cmul(c2{sr[SW2(j+128)], si[SW2(j+128)]}, w16b);
      v[3] = cmul(c2{sr[SW2(j+192)], si[SW2(j+192)]}, w16c);
      dft4<1>(v[0],v[1],v[2],v[3]);
      wsync();
      #pragma unroll
      for (int r=0;r<4;r++){ sr[SW2(b16 + 16*r)] = v[r].x; si[SW2(b16 + 16*r)] = v[r].y; }
    }
    wsync();
    float av[4];
    { // L=64 + abs
      v[0] = c2{sr[SW2(j)],     si[SW2(j)]};
      v[1] = cmul(c2{sr[SW2(j+64)],  si[SW2(j+64)]},  w64);
      v[2] = cmul(c2{sr[SW2(j+128)], si[SW2(j+128)]}, w64b);
      v[3] = cmul(c2{sr[SW2(j+192)], si[SW2(j+192)]}, w64c);
      dft4<1>(v[0],v[1],v[2],v[3]);
      float* op = op0 + (size_t)n1*NB;
      #pragma unroll
      for (int r=0;r<4;r++){
        c2 z = v[r];
        av[r] = sqrtf(z.x*z.x + z.y*z.y) * (1.0f/160000.0f);
        op[j + 64*r] = av[r];
      }
    }
    if (WRITEB){
      wsync();
      #pragma unroll
      for (int q=0;q<4;q++) v[q] = c2{av[q], 0.0f};
      dft4<-1>(v[0],v[1],v[2],v[3]);
      #pragma unroll
      for (int r=0;r<4;r++){ sr[SW2(4*j + r)] = v[r].x; si[SW2(4*j + r)] = v[r].y; }
      wsync();
      { // L=4
        v[0] = c2{sr[SW2(j)],     si[SW2(j)]};
        v[1] = cmulc(c2{sr[SW2(j+64)],  si[SW2(j+64)]},  w4);
        v[2] = cmulc(c2{sr[SW2(j+128)], si[SW2(j+128)]}, w4b);
        v[3] = cmulc(c2{sr[SW2(j+192)], si[SW2(j+192)]}, w4c);
        dft4<-1>(v[0],v[1],v[2],v[3]);
        wsync();
        #pragma unroll
        for (int r=0;r<4;r++){ sr[SW2(b4 + 4*r)] = v[r].x; si[SW2(b4 + 4*r)] = v[r].y; }
      }
      wsync();
      { // L=16
        v[0] = c2{sr[SW2(j)],     si[SW2(j)]};
        v[1] = cmulc(c2{sr[SW2(j+64)],  si[SW2(j+64)]},  w16);
        v[2] = cmulc(c2{sr[SW2(j+128)], si[SW2(j+128)]}, w16b);
        v[3] = cmulc(c2{sr[SW2(j+192)], si[SW2(j+192)]}, w16c);
        dft4<-1>(v[0],v[1],v[2],v[3]);
        wsync();
        #pragma unroll
        for (int r=0;r<4;r++){ sr[SW2(b16 + 16*r)] = v[r].x; si[SW2(b16 + 16*r)] = v[r].y; }
      }
      wsync();
      { // L=64 + row twiddle -> overwrite dead tile row (transposed store)
        v[0] = c2{sr[SW2(j)],     si[SW2(j)]};
        v[1] = cmulc(c2{sr[SW2(j+64)],  si[SW2(j+64)]},  w64);
        v[2] = cmulc(c2{sr[SW2(j+128)], si[SW2(j+128)]}, w64b);
        v[3] = cmulc(c2{sr[SW2(j+192)], si[SW2(j+192)]}, w64c);
        dft4<-1>(v[0],v[1],v[2],v[3]);
        #pragma unroll
        for (int r=0;r<4;r++){
          int kb = j + 64*r;
          c2 tw = cis(-TWO_PI * (float)(n1*kb) * (1.0f/160000.0f));
          c2 z = cmul(v[r], tw);
          tr[n1i*GTF + kb] = z.x;
          ti[n1i*GTF + kb] = z.y;
        }
      }
    }
    wsync();
  }
  if (WRITEB){
    __syncthreads();
    c2* op = outB + (size_t)arr*TLEN;
    if (rows == GCH){
      for (int e = threadIdx.x; e < 256*GCH; e += 256){
        int kb = e / GCH, i = e - kb*GCH;
        op[(size_t)kb*NA + n1_0 + i] = c2{tr[i*GTF + kb], ti[i*GTF + kb]};
      }
    } else {
      for (int e = threadIdx.x; e < 256*rows; e += 256){
        int kb = e / rows, i = e - kb*rows;
        op[(size_t)kb*NA + n1_0 + i] = c2{tr[i*GTF + kb], ti[i*GTF + kb]};
      }
    }
  }
}

// ---------------- 625-point row FFT (radix-5 Stockham), float-plane LDS ----------------
// FILT: 0 none, 1 psi1 (input Xf), 2 psi2 (input U1h). TW: output twiddle (incremental).
// kamax: when TW==0, only outputs n1 <= kamax are written (partial-spectrum store).
#define SCR625 784   // SW2(624)+1 = 781 -> pad
template<int S, int FILT, int TW>
__global__ __launch_bounds__(128) void k_fft625(const c2* __restrict__ inp, c2* __restrict__ outp,
                                                int cblk, int BLK, int nj2, int j2base, int scBase,
                                                int kamax){
  __shared__ float l0r[SCR625], l0i[SCR625], l1r[SCR625], l1i[SCR625];
  int g = blockIdx.x;
  int i = g / NB, kb = g - i*NB;
  int j = threadIdx.x;
  const c2* ip;
  int j1 = 0, j2 = 0;
  if (FILT == 0){
    ip = inp + (size_t)i*TLEN;
  } else if (FILT == 1){
    int bt = i / BLK; j1 = cblk*BLK + (i - bt*BLK);
    ip = inp + (size_t)bt*TLEN;
  } else {
    int g2 = scBase + i;
    int npb = BLK*nj2;
    int bt = g2 / npb, rr = g2 - bt*npb;
    int jloc = rr / nj2; j2 = j2base + (rr - jloc*nj2);
    ip = inp + (size_t)(bt*BLK + jloc)*TLEN;
  }
  ip += (size_t)kb*NA;
  float xi = 0.0f, sig = 0.0f, inv2s = 0.0f;
  int klo = 0, khi = 0;
  if (FILT != 0){
    if (FILT == 1){ xi = 0.4f * exp2f(-(float)j1 * 0.0625f); sig = xi * 0.04427378243f; }
    else          { xi = 0.4f * exp2f(-(float)j2);           sig = 0.35f * xi; }
    inv2s = 0.5f / (sig*sig);
    klo = (int)((xi - 6.0f*sig) * (float)TLEN); if (klo < 0) klo = 0;
    khi = (int)((xi + 6.0f*sig) * (float)TLEN) + 1; if (khi > TLEN/2 - 1) khi = TLEN/2 - 1;
  }
  c2 a[5], b[5];
  if (j < 125){
    if (FILT == 0){
      #pragma unroll
      for (int q=0;q<5;q++) a[q] = ip[j + 125*q];
      dft5<S>(a, b);
    } else {
      bool any = false;
      #pragma unroll
      for (int q=0;q<5;q++){
        int ka = j + 125*q;
        int k = kb + 256*ka;
        c2 val = c2{0.0f, 0.0f};
        if (k >= klo && k <= khi){
          val = ip[ka];
          float d = (float)k * (1.0f/(float)TLEN) - xi;
          float f = __expf(-d*d*inv2s);
          val.x *= f; val.y *= f;
          any = true;
        }
        a[q] = val;
      }
      if (any){
        dft5<S>(a, b);
      } else {
        #pragma unroll
        for (int r=0;r<5;r++) b[r] = c2{0.0f,0.0f};
      }
    }
    #pragma unroll
    for (int r=0;r<5;r++){ int s = SW2(5*j + r); l0r[s] = b[r].x; l0i[s] = b[r].y; }
  }
  __syncthreads();
  if (j < 125){ // L = 5
    int k = j % 5;
    c2 w = cis((float)S * TWO_PI * (float)k * (1.0f/25.0f));
    c2 w2 = cmul(w,w), w3 = cmul(w2,w), w4 = cmul(w3,w);
    a[0] = c2{l0r[SW2(j)],     l0i[SW2(j)]};
    a[1] = cmul(c2{l0r[SW2(j+125)], l0i[SW2(j+125)]}, w);
    a[2] = cmul(c2{l0r[SW2(j+250)], l0i[SW2(j+250)]}, w2);
    a[3] = cmul(c2{l0r[SW2(j+375)], l0i[SW2(j+375)]}, w3);
    a[4] = cmul(c2{l0r[SW2(j+500)], l0i[SW2(j+500)]}, w4);
    dft5<S>(a, b);
    int base = 5*(j-k)+k;
    #pragma unroll
    for (int r=0;r<5;r++){ int s = SW2(base + 5*r); l1r[s] = b[r].x; l1i[s] = b[r].y; }
  }
  __syncthreads();
  if (j < 125){ // L = 25
    int k = j % 25;
    c2 w = cis((float)S * TWO_PI * (float)k * (1.0f/125.0f));
    c2 w2 = cmul(w,w), w3 = cmul(w2,w), w4 = cmul(w3,w);
    a[0] = c2{l1r[SW2(j)],     l1i[SW2(j)]};
    a[1] = cmul(c2{l1r[SW2(j+125)], l1i[SW2(j+125)]}, w);
    a[2] = cmul(c2{l1r[SW2(j+250)], l1i[SW2(j+250)]}, w2);
    a[3] = cmul(c2{l1r[SW2(j+375)], l1i[SW2(j+375)]}, w3);
    a[4] = cmul(c2{l1r[SW2(j+500)], l1i[SW2(j+500)]}, w4);
    dft5<S>(a, b);
    int base = 5*(j-k)+k;
    #pragma unroll
    for (int r=0;r<5;r++){ int s = SW2(base + 25*r); l0r[s] = b[r].x; l0i[s] = b[r].y; }
  }
  __syncthreads();
  if (j < 125){ // L = 125
    c2 w = cis((float)S * TWO_PI * (float)j * (1.0f/625.0f));
    c2 w2 = cmul(w,w), w3 = cmul(w2,w), w4 = cmul(w3,w);
    a[0] = c2{l0r[SW2(j)],     l0i[SW2(j)]};
    a[1] = cmul(c2{l0r[SW2(j+125)], l0i[SW2(j+125)]}, w);
    a[2] = cmul(c2{l0r[SW2(j+250)], l0i[SW2(j+250)]}, w2);
    a[3] = cmul(c2{l0r[SW2(j+375)], l0i[SW2(j+375)]}, w3);
    a[4] = cmul(c2{l0r[SW2(j+500)], l0i[SW2(j+500)]}, w4);
    dft5<S>(a, b);
    c2* op = outp + (size_t)i*TLEN + (size_t)kb*NA;
    if (TW){
      // incremental output twiddle: tw(n1=j) base, step = tw(125*kb)
      c2 twb = cis((float)S * TWO_PI * (float)(j*kb)   * (1.0f/160000.0f));
      c2 tws = cis((float)S * TWO_PI * (float)(125*kb) * (1.0f/160000.0f));
      #pragma unroll
      for (int r=0;r<5;r++){
        int n1 = j + 125*r;
        op[n1] = cmul(b[r], twb);
        twb = cmul(twb, tws);
      }
    } else {
      #pragma unroll
      for (int r=0;r<5;r++){
        int n1 = j + 125*r;
        if (n1 <= kamax) op[n1] = b[r];
      }
    }
  }
}

// ---------------- complex transpose (x-chain only) ----------------
__global__ __launch_bounds__(256) void k_transpose(const c2* __restrict__ in, c2* __restrict__ out,
                                                   int R, int C, int tilesR, int tilesC){
  __shared__ c2 tile[32][33];
  int bi = blockIdx.x;
  int arr = bi / (tilesR*tilesC);
  int tt = bi - arr*(tilesR*tilesC);
  int tr = tt / tilesC, tc = tt - tr*tilesC;
  const c2* ip = in + (size_t)arr*TLEN;
  c2* op = out + (size_t)arr*TLEN;
  int tx = threadIdx.x & 31, ty = threadIdx.x >> 5;
  #pragma unroll
  for (int i=0;i<4;i++){
    int r = tr*32 + ty + i*8, cc = tc*32 + tx;
    if (r < R && cc < C) tile[ty+i*8][tx] = ip[(size_t)r*C + cc];
  }
  __syncthreads();
  #pragma unroll
  for (int i=0;i<4;i++){
    int r = tc*32 + ty + i*8, cc = tr*32 + tx;
    if (r < C && cc < R) op[(size_t)r*R + cc] = tile[tx][ty+i*8];
  }
}

// ---------------- Gaussian lowpass + decimate-by-64, natural layout (S0 only) ----------------
__global__ __launch_bounds__(256) void k_conv(const float* __restrict__ inp, float* __restrict__ S){
  __shared__ float w[NTAP];
  for (int i=threadIdx.x; i<NTAP; i+=256){
    float d = (float)(i - KC);
    w[i] = 0.015666427f * __expf(-7.7106284e-4f * d * d);
  }
  __syncthreads();
  int g = blockIdx.x;
  int arr = g / 10;
  int t = (g - arr*10)*256 + threadIdx.x;
  if (t >= TD) return;
  int srow = arr * SROWS;
  const float* ip = inp + (size_t)arr*TLEN;
  float acc = 0.0f;
  int n = 64*t - KC; if (n < 0) n += TLEN;
  for (int m=0;m<NTAP;m++){
    acc += ip[n] * w[m];
    n++; if (n == TLEN) n = 0;
  }
  S[(size_t)srow*TD + t] = acc;
}

// ---------------- fused LDS stage + conv for scrambled-layout U (S1/S2 rows) ----------------
#define CONV_NCOL 27
#define CONV_NU   16875
#define CONV_USZ  17138
#define CONV_LDSB ((CONV_USZ + NTAP + 1)*4)
template<int MODE>
__global__ __launch_bounds__(256) void k_conv2(const float* __restrict__ inp, float* __restrict__ S,
                                               int cblk, int BLK, int nj2, int j2base, int scBase){
  extern __shared__ float smem[];
  float* u = smem;
  float* w = smem + CONV_USZ;
  for (int i=threadIdx.x; i<NTAP; i+=256){
    float d = (float)(i - KC);
    w[i] = 0.015666427f * __expf(-7.7106284e-4f * d * d);
  }
  int g = blockIdx.x;
  int arr = g / 10;
  int b = g - arr*10;
  int nlo = 16000*b - KC;
  int n2_0 = (nlo >= 0) ? (nlo/625) : -1;
  const float* ip = inp + (size_t)arr*TLEN;
  for (int e = threadIdx.x; e < CONV_NU; e += 256){
    int n1 = e / CONV_NCOL;
    int c  = e - n1*CONV_NCOL;
    int n2 = n2_0 + c;
    n2 &= 255;
    u[SW64(n1 + 625*c)] = ip[n1*NB + n2];
  }
  __syncthreads();
  int tl = threadIdx.x;
  if (tl >= 250) return;
  int t = 250*b + tl;
  int srow;
  if (MODE == 1){
    int a2 = arr / BLK; int j1 = cblk*BLK + (arr - a2*BLK);
    srow = a2*SROWS + 1 + j1;
  } else {
    int g2 = scBase + arr; int npb = BLK*nj2;
    int a2 = g2/npb, rr = g2 - a2*npb;
    int jloc = rr/nj2; int j2 = j2base + (rr - jloc*nj2);
    int j1 = cblk*BLK + jloc;
    int full = j1 >> 4;
    int cum = 16*(5*full - (full*(full-1))/2) + (j1 & 15)*(5 - full);
    int P = cum + j2 - full - 1;
    srow = a2*SROWS + 97 + P;
  }
  int base = 64*t - KC - 625*n2_0;
  float acc = 0.0f;
  #pragma unroll 4
  for (int m=0;m<NTAP;m++){
    acc += u[SW64(base + m)] * w[m];
  }
  S[(size_t)srow*TD + t] = acc;
}

// ---------------- global min/max + finalize ----------------
__global__ __launch_bounds__(256) void k_minmax1(const float* __restrict__ S, int n, float* pmn, float* pmx){
  __shared__ float smn[256], smx[256];
  float mn = 3.4028235e38f, mx = -3.4028235e38f;
  for (size_t i = (size_t)blockIdx.x*256 + threadIdx.x; i < (size_t)n; i += (size_t)gridDim.x*256){
    float v = S[i]; mn = fminf(mn,v); mx = fmaxf(mx,v);
  }
  smn[threadIdx.x]=mn; smx[threadIdx.x]=mx; __syncthreads();
  for (int s=128;s>0;s>>=1){
    if ((int)threadIdx.x < s){
      smn[threadIdx.x]=fminf(smn[threadIdx.x],smn[threadIdx.x+s]);
      smx[threadIdx.x]=fmaxf(smx[threadIdx.x],smx[threadIdx.x+s]);
    }
    __syncthreads();
  }
  if (threadIdx.x==0){ pmn[blockIdx.x]=smn[0]; pmx[blockIdx.x]=smx[0]; }
}
__global__ __launch_bounds__(256) void k_minmax2(const float* __restrict__ pmn, const float* __restrict__ pmx,
                                                 int nb, float* scal){
  __shared__ float smn[256], smx[256];
  float mn = 3.4028235e38f, mx = -3.4028235e38f;
  for (int i = threadIdx.x; i < nb; i += 256){ mn = fminf(mn,pmn[i]); mx = fmaxf(mx,pmx[i]); }
  smn[threadIdx.x]=mn; smx[threadIdx.x]=mx; __syncthreads();
  for (int s=128;s>0;s>>=1){
    if ((int)threadIdx.x < s){
      smn[threadIdx.x]=fminf(smn[threadIdx.x],smn[threadIdx.x+s]);
      smx[threadIdx.x]=fmaxf(smx[threadIdx.x],smx[threadIdx.x+s]);
    }
    __syncthreads();
  }
  if (threadIdx.x==0){ scal[0]=smn[0]; scal[1]=smx[0]; }
}
__global__ __launch_bounds__(256) void k_final(const float* __restrict__ S, const float* __restrict__ scal,
                                               float* __restrict__ out, int n){
  int i = blockIdx.x*256 + threadIdx.x;
  if (i >= n) return;
  float mn = scal[0];
  float r = scal[1] - mn;
  if (r == 0.0f) r = 1.0f;
  int half = SROWS*TD;
  int a = i / half; int rest = i - a*half;
  out[i] = (S[(size_t)(a & 1)*half + rest] - mn) / r;
}

extern "C" void kernel_launch(void* const* d_in, const int* in_sizes, int n_in,
                              void* d_out, int out_size, void* d_ws, size_t ws_size,
                              hipStream_t stream){
  (void)in_sizes; (void)n_in;
  const float* x = (const float*)d_in[0];

  int BLK = 16;
  while (BLK > 1){
    size_t CH = 2*(size_t)BLK;
    size_t needb = 2560000ULL + 2ULL*CH*TLEN*8ULL + CH*TLEN*8ULL + CH*TLEN*8ULL
                 + 2ULL*CH*TLEN*4ULL + 6740000ULL + 8192ULL + 4096ULL;
    if (needb <= ws_size) break;
    BLK >>= 1;
  }
  {
    size_t CH = 2;
    size_t needmin = 2560000ULL + 2ULL*CH*TLEN*8ULL + CH*TLEN*8ULL + CH*TLEN*8ULL
                   + 2ULL*CH*TLEN*4ULL + 6740000ULL + 8192ULL + 4096ULL;
    if (ws_size < needmin) return;
  }
  int CH = 2*BLK;

  char* p = (char*)d_ws;
  auto carve = [&](size_t bytes)->void*{ void* r = (void*)p; p += (bytes + 255) & ~(size_t)255; return r; };
  c2*    Xf  = (c2*)carve(2ULL*TLEN*sizeof(c2));
  c2*    A   = (c2*)carve(2ULL*CH*TLEN*sizeof(c2));      // 2x slots for sc-pair batching
  c2*    B   = (c2*)carve((size_t)CH*TLEN*sizeof(c2));
  c2*    U1h = (c2*)carve((size_t)CH*TLEN*sizeof(c2));
  float* Ur  = (float*)carve(2ULL*CH*TLEN*sizeof(float)); // 2x slots
  float* Sb  = (float*)carve(2ULL*SROWS*TD*sizeof(float));
  float* pmn = (float*)carve(512*4);
  float* pmx = (float*)carve(512*4);
  float* scal = (float*)carve(256);

  // ---- forward FFT of x -> Xf ----
  k_fft256<-1,2,0><<<2*NA, 64, 0, stream>>>((const void*)x, (void*)A);
  k_transpose<<<2*20*8, 256, 0, stream>>>(A, B, NA, NB, 20, 8);
  k_fft625<-1,0,0><<<2*NB, 128, 0, stream>>>(B, Xf, 0,0,0,0,0, 314);  // only ka<=314 read by psi1
  // ---- S0 ----
  k_conv<<<2*10, 256, 0, stream>>>(x, Sb);

  int NCB = 96 / BLK;
  for (int c = 0; c < NCB; c++){
    int cq = (c*BLK)/16;
    int nj2 = 5 - cq;
    int j2base = cq + 1;
    // F3 partial-spectrum bound from the widest psi2 in this block (j2 = j2base)
    float xi2 = 0.4f * exp2f(-(float)j2base);
    int khi2 = (int)(3.1f * xi2 * 160000.0f) + 1; if (khi2 > TLEN/2 - 1) khi2 = TLEN/2 - 1;
    int kamax = (khi2 >> 8) + 1; if (kamax > 624) kamax = 624;
    // ---- order 1 ----
    k_fft625<1,1,1><<<CH*NB, 128, 0, stream>>>(Xf, A, c, BLK, 0,0,0, 624);
    if (nj2 > 0){
      k_fft256g<1><<<CH*GNCH, 256, G_LDSB, stream>>>(A, Ur, B);       // |ifft| -> Ur, fft -> B
      k_conv2<1><<<CH*10, 256, CONV_LDSB, stream>>>(Ur, Sb, c, BLK, 0,0,0);
      k_fft625<-1,0,0><<<CH*NB, 128, 0, stream>>>(B, U1h, 0,0,0,0,0, kamax);
      // ---- order 2, sc batched in pairs ----
      for (int scStart = 0; scStart < nj2; scStart += 2){
        int nsc = nj2 - scStart; if (nsc > 2) nsc = 2;
        k_fft625<1,2,1><<<nsc*CH*NB, 128, 0, stream>>>(U1h, A, c, BLK, nj2, j2base, scStart*CH, 624);
        k_fft256g<0><<<nsc*CH*GNCH, 256, G_LDSB, stream>>>(A, Ur, (c2*)nullptr);
        k_conv2<2><<<nsc*CH*10, 256, CONV_LDSB, stream>>>(Ur, Sb, c, BLK, nj2, j2base, scStart*CH);
      }
    } else {
      k_fft256g<0><<<CH*GNCH, 256, G_LDSB, stream>>>(A, Ur, (c2*)nullptr);
      k_conv2<1><<<CH*10, 256, CONV_LDSB, stream>>>(Ur, Sb, c, BLK, 0,0,0);
    }
  }

  // ---- global min-max normalize (standardize cancels) + tile(3,1,1) ----
  k_minmax1<<<512, 256, 0, stream>>>(Sb, 2*SROWS*TD, pmn, pmx);
  k_minmax2<<<1, 256, 0, stream>>>(pmn, pmx, 512, scal);
  k_final<<<(out_size+255)/256, 256, 0, stream>>>(Sb, scal, (float*)d_out, out_size);
}

// Round 11
// 1390.862 us; speedup vs baseline: 1.4155x; 1.0634x over previous
//
#include <hip/hip_runtime.h>
#include <math.h>

#define TLEN 160000
#define NA 625      // n1 (time rows) / ka (freq elements)
#define NB 256      // n2 (time elements) / kb (freq rows)
#define TD 2500
#define KC 128      // conv half width (~5 sigma_t, sigma_t = 25.46)
#define NTAP 257
#define SROWS 337
#define TWO_PI 6.283185307179586f

struct c2 { float x, y; };

__device__ __forceinline__ c2 cmul(c2 a, c2 b){ return c2{a.x*b.x - a.y*b.y, a.x*b.y + a.y*b.x}; }
__device__ __forceinline__ c2 cmulc(c2 a, c2 b){ return c2{a.x*b.x + a.y*b.y, a.y*b.x - a.x*b.y}; } // a*conj(b)
__device__ __forceinline__ c2 cadd(c2 a, c2 b){ return c2{a.x+b.x, a.y+b.y}; }
__device__ __forceinline__ c2 csub(c2 a, c2 b){ return c2{a.x-b.x, a.y-b.y}; }
__device__ __forceinline__ c2 cmac(c2 acc, c2 v, float wr, float wi){
  acc.x += v.x*wr - v.y*wi; acc.y += v.x*wi + v.y*wr; return acc;
}
__device__ __forceinline__ c2 cis(float ang){ c2 r; __sincosf(ang, &r.y, &r.x); return r; }
__device__ __forceinline__ int SW(int i){ return i + (i >> 4); }
__device__ __forceinline__ int SW2(int i){ return i + (i >> 2); }   // float-plane swizzle (pow2 strides)
__device__ __forceinline__ int SW64(int i){ return i + (i >> 6); }
// wave-local "syncthreads": scratch is wave-private, so a block barrier is overkill.
__device__ __forceinline__ void wsync(){
  __builtin_amdgcn_wave_barrier();
  __threadfence_block();
  __builtin_amdgcn_wave_barrier();
}

template<int S>
__device__ __forceinline__ void dft4(c2& a0, c2& a1, c2& a2, c2& a3){
  c2 t0 = cadd(a0,a2), t1 = csub(a0,a2), t2 = cadd(a1,a3), t3 = csub(a1,a3);
  float fs = (float)S;
  a0 = cadd(t0,t2); a2 = csub(t0,t2);
  a1 = c2{t1.x - fs*t3.y, t1.y + fs*t3.x};
  a3 = c2{t1.x + fs*t3.y, t1.y - fs*t3.x};
}

template<int S>
__device__ __forceinline__ void dft5(const c2 a[5], c2 b[5]){
  const float C1 = 0.30901699437494742f, C2 = -0.80901699437494745f;
  const float S1 = 0.95105651629515353f * (float)S, S2 = 0.58778525229247314f * (float)S;
  b[0] = cadd(cadd(a[0],a[1]), cadd(cadd(a[2],a[3]),a[4]));
  c2 r;
  r = a[0]; r = cmac(r,a[1],C1, S1); r = cmac(r,a[2],C2, S2); r = cmac(r,a[3],C2,-S2); r = cmac(r,a[4],C1,-S1); b[1]=r;
  r = a[0]; r = cmac(r,a[1],C2, S2); r = cmac(r,a[2],C1,-S1); r = cmac(r,a[3],C1, S1); r = cmac(r,a[4],C2,-S2); b[2]=r;
  r = a[0]; r = cmac(r,a[1],C2,-S2); r = cmac(r,a[2],C1, S1); r = cmac(r,a[3],C1,-S1); r = cmac(r,a[4],C2, S2); b[3]=r;
  r = a[0]; r = cmac(r,a[1],C1,-S1); r = cmac(r,a[2],C2,-S2); r = cmac(r,a[3],C2, S2); r = cmac(r,a[4],C1, S1); b[4]=r;
}

// ---------------- 256-point row FFT (x-chain only) ----------------
template<int S, int INMODE, int OUTMODE>
__global__ __launch_bounds__(64) void k_fft256(const void* __restrict__ inp, void* __restrict__ outp){
  __shared__ c2 lds[2][272];
  int g = blockIdx.x;
  int arr = g / NA, n1 = g - arr*NA;
  int j = threadIdx.x;
  c2 v[4];
  if (INMODE == 0){
    const c2* ip = (const c2*)inp + (size_t)arr*TLEN + (size_t)n1*NB;
    #pragma unroll
    for (int q=0;q<4;q++) v[q] = ip[j + 64*q];
  } else if (INMODE == 1){
    const float* ip = (const float*)inp + (size_t)arr*TLEN + (size_t)n1*NB;
    #pragma unroll
    for (int q=0;q<4;q++) v[q] = c2{ip[j + 64*q], 0.0f};
  } else {
    const float* ip = (const float*)inp + (size_t)arr*TLEN;
    #pragma unroll
    for (int q=0;q<4;q++) v[q] = c2{ip[n1 + NA*(j + 64*q)], 0.0f};
  }
  dft4<S>(v[0],v[1],v[2],v[3]);
  #pragma unroll
  for (int r=0;r<4;r++) lds[0][SW(4*j + r)] = v[r];
  __syncthreads();
  { // L = 4
    int k = j & 3;
    c2 w = cis((float)S * TWO_PI * (float)k * (1.0f/16.0f));
    c2 w2 = cmul(w,w), w3 = cmul(w2,w);
    v[0] = lds[0][SW(j)];
    v[1] = cmul(lds[0][SW(j+64)], w);
    v[2] = cmul(lds[0][SW(j+128)], w2);
    v[3] = cmul(lds[0][SW(j+192)], w3);
    dft4<S>(v[0],v[1],v[2],v[3]);
    int base = 4*(j-k)+k;
    #pragma unroll
    for (int r=0;r<4;r++) lds[1][SW(base + 4*r)] = v[r];
  }
  __syncthreads();
  { // L = 16
    int k = j & 15;
    c2 w = cis((float)S * TWO_PI * (float)k * (1.0f/64.0f));
    c2 w2 = cmul(w,w), w3 = cmul(w2,w);
    v[0] = lds[1][SW(j)];
    v[1] = cmul(lds[1][SW(j+64)], w);
    v[2] = cmul(lds[1][SW(j+128)], w2);
    v[3] = cmul(lds[1][SW(j+192)], w3);
    dft4<S>(v[0],v[1],v[2],v[3]);
    int base = 4*(j-k)+k;
    #pragma unroll
    for (int r=0;r<4;r++) lds[0][SW(base + 16*r)] = v[r];
  }
  __syncthreads();
  { // L = 64
    c2 w = cis((float)S * TWO_PI * (float)j * (1.0f/256.0f));
    c2 w2 = cmul(w,w), w3 = cmul(w2,w);
    v[0] = lds[0][SW(j)];
    v[1] = cmul(lds[0][SW(j+64)], w);
    v[2] = cmul(lds[0][SW(j+128)], w2);
    v[3] = cmul(lds[0][SW(j+192)], w3);
    dft4<S>(v[0],v[1],v[2],v[3]);
    if (OUTMODE == 0){
      c2* op = (c2*)outp + (size_t)arr*TLEN + (size_t)n1*NB;
      #pragma unroll
      for (int r=0;r<4;r++){
        int kb = j + 64*r;
        c2 tw = cis((float)S * TWO_PI * (float)(n1*kb) * (1.0f/160000.0f));
        op[kb] = cmul(v[r], tw);
      }
    } else {
      float* op = (float*)outp + (size_t)arr*TLEN + (size_t)n1*NB;
      #pragma unroll
      for (int r=0;r<4;r++){
        c2 z = v[r];
        op[j + 64*r] = sqrtf(z.x*z.x + z.y*z.y) * (1.0f/160000.0f);
      }
    }
  }
}

// ---------------- fused gather + inverse 256-FFT + abs (+ optional forward 256-FFT -> B) --------
#define GCH     12
#define GNCH    53                        // ceil(625/12)
#define GTF     273                       // tile float-plane stride; 273 % 32 = 17
#define SCR     320                       // per-plane scratch floats; SW2(255)+1 = 319
#define G_LDSB  ((2*GCH*GTF + 4*2*SCR)*4) // 36448 B dynamic
template<int WRITEB>
__global__ __launch_bounds__(256) void k_fft256g(const c2* __restrict__ inp, float* __restrict__ outp,
                                                 c2* __restrict__ outB){
  extern __shared__ float smemg[];
  float* tr = smemg;                           // [GCH][GTF]
  float* ti = smemg + GCH*GTF;                 // [GCH][GTF]
  int g = blockIdx.x;
  int arr = g / GNCH, chunk = g - arr*GNCH;
  int n1_0 = chunk*GCH;
  int rows = NA - n1_0; if (rows > GCH) rows = GCH;
  const c2* ip = inp + (size_t)arr*TLEN;
  if (rows == GCH){
    for (int e = threadIdx.x; e < 256*GCH; e += 256){
      int kb = e / GCH, i = e - kb*GCH;        // const divisor
      c2 z = ip[(size_t)kb*NA + n1_0 + i];
      tr[i*GTF + kb] = z.x; ti[i*GTF + kb] = z.y;
    }
  } else {
    for (int e = threadIdx.x; e < 256*rows; e += 256){
      int kb = e / rows, i = e - kb*rows;
      c2 z = ip[(size_t)kb*NA + n1_0 + i];
      tr[i*GTF + kb] = z.x; ti[i*GTF + kb] = z.y;
    }
  }
  __syncthreads();
  int gq = threadIdx.x >> 6, j = threadIdx.x & 63;
  float* sr = smemg + 2*GCH*GTF + gq*(2*SCR);
  float* si = sr + SCR;
  // hoisted stage twiddles (inverse; forward = conjugate via cmulc)
  c2 w4  = cis(TWO_PI * (float)(j & 3)  * (1.0f/16.0f));
  c2 w4b = cmul(w4,w4),  w4c = cmul(w4b,w4);
  c2 w16 = cis(TWO_PI * (float)(j & 15) * (1.0f/64.0f));
  c2 w16b= cmul(w16,w16), w16c= cmul(w16b,w16);
  c2 w64 = cis(TWO_PI * (float)j * (1.0f/256.0f));
  c2 w64b= cmul(w64,w64), w64c= cmul(w64b,w64);
  int b4 = 4*(j-(j&3))+(j&3);
  int b16= 4*(j-(j&15))+(j&15);
  float* op0 = outp + (size_t)arr*TLEN;
  for (int t = 0; t < 3; t++){
    int n1i = gq + 4*t;
    if (n1i >= rows) break;
    int n1 = n1_0 + n1i;
    c2 v[4];
    #pragma unroll
    for (int q=0;q<4;q++) v[q] = c2{tr[n1i*GTF + j + 64*q], ti[n1i*GTF + j + 64*q]};
    dft4<1>(v[0],v[1],v[2],v[3]);
    #pragma unroll
    for (int r=0;r<4;r++){ sr[SW2(4*j + r)] = v[r].x; si[SW2(4*j + r)] = v[r].y; }
    wsync();
    { // L=4
      v[0] = c2{sr[SW2(j)],     si[SW2(j)]};
      v[1] = cmul(c2{sr[SW2(j+64)],  si[SW2(j+64)]},  w4);
      v[2] = cmul(c2{sr[SW2(j+128)], si[SW2(j+128)]}, w4b);
      v[3] = cmul(c2{sr[SW2(j+192)], si[SW2(j+192)]}, w4c);
      dft4<1>(v[0],v[1],v[2],v[3]);
      wsync();
      #pragma unroll
      for (int r=0;r<4;r++){ sr[SW2(b4 + 4*r)] = v[r].x; si[SW2(b4 + 4*r)] = v[r].y; }
    }
    wsync();
    { // L=16
      v[0] = c2{sr[SW2(j)],     si[SW2(j)]};
      v[1] = cmul(c2{sr[SW2(j+64)],  si[SW2(j+64)]},  w16);
      v[2] = cmul(c2{sr[SW2(j+128)], si[SW2(j+128)]}, w16b);
      v[3] = cmul(c2{sr[SW2(j+192)], si[SW2(j+192)]}, w16c);
      dft4<1>(v[0],v[1],v[2],v[3]);
      wsync();
      #pragma unroll
      for (int r=0;r<4;r++){ sr[SW2(b16 + 16*r)] = v[r].x; si[SW2(b16 + 16*r)] = v[r].y; }
    }
    wsync();
    float av[4];
    { // L=64 + abs
      v[0] = c2{sr[SW2(j)],     si[SW2(j)]};
      v[1] = cmul(c2{sr[SW2(j+64)],  si[SW2(j+64)]},  w64);
      v[2] = cmul(c2{sr[SW2(j+128)], si[SW2(j+128)]}, w64b);
      v[3] = cmul(c2{sr[SW2(j+192)], si[SW2(j+192)]}, w64c);
      dft4<1>(v[0],v[1],v[2],v[3]);
      float* op = op0 + (size_t)n1*NB;
      #pragma unroll
      for (int r=0;r<4;r++){
        c2 z = v[r];
        av[r] = sqrtf(z.x*z.x + z.y*z.y) * (1.0f/160000.0f);
        op[j + 64*r] = av[r];
      }
    }
    if (WRITEB){
      wsync();
      #pragma unroll
      for (int q=0;q<4;q++) v[q] = c2{av[q], 0.0f};
      dft4<-1>(v[0],v[1],v[2],v[3]);
      #pragma unroll
      for (int r=0;r<4;r++){ sr[SW2(4*j + r)] = v[r].x; si[SW2(4*j + r)] = v[r].y; }
      wsync();
      { // L=4
        v[0] = c2{sr[SW2(j)],     si[SW2(j)]};
        v[1] = cmulc(c2{sr[SW2(j+64)],  si[SW2(j+64)]},  w4);
        v[2] = cmulc(c2{sr[SW2(j+128)], si[SW2(j+128)]}, w4b);
        v[3] = cmulc(c2{sr[SW2(j+192)], si[SW2(j+192)]}, w4c);
        dft4<-1>(v[0],v[1],v[2],v[3]);
        wsync();
        #pragma unroll
        for (int r=0;r<4;r++){ sr[SW2(b4 + 4*r)] = v[r].x; si[SW2(b4 + 4*r)] = v[r].y; }
      }
      wsync();
      { // L=16
        v[0] = c2{sr[SW2(j)],     si[SW2(j)]};
        v[1] = cmulc(c2{sr[SW2(j+64)],  si[SW2(j+64)]},  w16);
        v[2] = cmulc(c2{sr[SW2(j+128)], si[SW2(j+128)]}, w16b);
        v[3] = cmulc(c2{sr[SW2(j+192)], si[SW2(j+192)]}, w16c);
        dft4<-1>(v[0],v[1],v[2],v[3]);
        wsync();
        #pragma unroll
        for (int r=0;r<4;r++){ sr[SW2(b16 + 16*r)] = v[r].x; si[SW2(b16 + 16*r)] = v[r].y; }
      }
      wsync();
      { // L=64 + row twiddle -> overwrite dead tile row (transposed store)
        v[0] = c2{sr[SW2(j)],     si[SW2(j)]};
        v[1] = cmulc(c2{sr[SW2(j+64)],  si[SW2(j+64)]},  w64);
        v[2] = cmulc(c2{sr[SW2(j+128)], si[SW2(j+128)]}, w64b);
        v[3] = cmulc(c2{sr[SW2(j+192)], si[SW2(j+192)]}, w64c);
        dft4<-1>(v[0],v[1],v[2],v[3]);
        #pragma unroll
        for (int r=0;r<4;r++){
          int kb = j + 64*r;
          c2 tw = cis(-TWO_PI * (float)(n1*kb) * (1.0f/160000.0f));
          c2 z = cmul(v[r], tw);
          tr[n1i*GTF + kb] = z.x;
          ti[n1i*GTF + kb] = z.y;
        }
      }
    }
    wsync();
  }
  if (WRITEB){
    __syncthreads();
    c2* op = outB + (size_t)arr*TLEN;
    if (rows == GCH){
      for (int e = threadIdx.x; e < 256*GCH; e += 256){
        int kb = e / GCH, i = e - kb*GCH;
        op[(size_t)kb*NA + n1_0 + i] = c2{tr[i*GTF + kb], ti[i*GTF + kb]};
      }
    } else {
      for (int e = threadIdx.x; e < 256*rows; e += 256){
        int kb = e / rows, i = e - kb*rows;
        op[(size_t)kb*NA + n1_0 + i] = c2{tr[i*GTF + kb], ti[i*GTF + kb]};
      }
    }
  }
}

// ---------------- 625-point row FFT (radix-5 Stockham), float-plane LDS + W625 LUT ----------------
// FILT: 0 none, 1 psi1 (input Xf), 2 psi2 (input U1h). TW: output twiddle (incremental).
// kamax: when TW==0, only outputs n1 <= kamax are written (partial-spectrum store).
// Radix-5 strides have gcd(.,32)=1 -> float planes need no swizzle.
// All stage twiddles are powers of W625 -> one LUT (625 entries), S=-1 via conjugate.
template<int S, int FILT, int TW>
__global__ __launch_bounds__(128) void k_fft625(const c2* __restrict__ inp, c2* __restrict__ outp,
                                                int cblk, int BLK, int nj2, int j2base, int scBase,
                                                int kamax){
  __shared__ float l0r[625], l0i[625], l1r[625], l1i[625];
  __shared__ float lutr[625], luti[625];
  for (int m = threadIdx.x; m < 625; m += 128){
    c2 z = cis(TWO_PI * (float)m * (1.0f/625.0f));
    lutr[m] = z.x; luti[m] = z.y;
  }
  int g = blockIdx.x;
  int i = g / NB, kb = g - i*NB;
  int j = threadIdx.x;
  const c2* ip;
  int j1 = 0, j2 = 0;
  if (FILT == 0){
    ip = inp + (size_t)i*TLEN;
  } else if (FILT == 1){
    int bt = i / BLK; j1 = cblk*BLK + (i - bt*BLK);
    ip = inp + (size_t)bt*TLEN;
  } else {
    int g2 = scBase + i;
    int npb = BLK*nj2;
    int bt = g2 / npb, rr = g2 - bt*npb;
    int jloc = rr / nj2; j2 = j2base + (rr - jloc*nj2);
    ip = inp + (size_t)(bt*BLK + jloc)*TLEN;
  }
  ip += (size_t)kb*NA;
  float xi = 0.0f, sig = 0.0f, inv2s = 0.0f;
  int klo = 0, khi = 0;
  if (FILT != 0){
    if (FILT == 1){ xi = 0.4f * exp2f(-(float)j1 * 0.0625f); sig = xi * 0.04427378243f; }
    else          { xi = 0.4f * exp2f(-(float)j2);           sig = 0.35f * xi; }
    inv2s = 0.5f / (sig*sig);
    klo = (int)((xi - 6.0f*sig) * (float)TLEN); if (klo < 0) klo = 0;
    khi = (int)((xi + 6.0f*sig) * (float)TLEN) + 1; if (khi > TLEN/2 - 1) khi = TLEN/2 - 1;
  }
  c2 a[5], b[5];
  if (j < 125){
    if (FILT == 0){
      #pragma unroll
      for (int q=0;q<5;q++) a[q] = ip[j + 125*q];
      dft5<S>(a, b);
    } else {
      bool any = false;
      #pragma unroll
      for (int q=0;q<5;q++){
        int ka = j + 125*q;
        int k = kb + 256*ka;
        c2 val = c2{0.0f, 0.0f};
        if (k >= klo && k <= khi){
          val = ip[ka];
          float d = (float)k * (1.0f/(float)TLEN) - xi;
          float f = __expf(-d*d*inv2s);
          val.x *= f; val.y *= f;
          any = true;
        }
        a[q] = val;
      }
      if (any){
        dft5<S>(a, b);
      } else {
        #pragma unroll
        for (int r=0;r<5;r++) b[r] = c2{0.0f,0.0f};
      }
    }
    #pragma unroll
    for (int r=0;r<5;r++){ int s = 5*j + r; l0r[s] = b[r].x; l0i[s] = b[r].y; }
  }
  __syncthreads();   // also covers LUT fill
  if (j < 125){ // L = 5
    int k = j % 5;
    c2 w  = c2{lutr[25*k],  (S>0)? luti[25*k]  : -luti[25*k]};
    c2 w2 = c2{lutr[50*k],  (S>0)? luti[50*k]  : -luti[50*k]};
    c2 w3 = c2{lutr[75*k],  (S>0)? luti[75*k]  : -luti[75*k]};
    c2 w4 = c2{lutr[100*k], (S>0)? luti[100*k] : -luti[100*k]};
    a[0] = c2{l0r[j],     l0i[j]};
    a[1] = cmul(c2{l0r[j+125], l0i[j+125]}, w);
    a[2] = cmul(c2{l0r[j+250], l0i[j+250]}, w2);
    a[3] = cmul(c2{l0r[j+375], l0i[j+375]}, w3);
    a[4] = cmul(c2{l0r[j+500], l0i[j+500]}, w4);
    dft5<S>(a, b);
    int base = 5*(j-k)+k;
    #pragma unroll
    for (int r=0;r<5;r++){ int s = base + 5*r; l1r[s] = b[r].x; l1i[s] = b[r].y; }
  }
  __syncthreads();
  if (j < 125){ // L = 25
    int k = j % 25;
    c2 w  = c2{lutr[5*k],  (S>0)? luti[5*k]  : -luti[5*k]};
    c2 w2 = c2{lutr[10*k], (S>0)? luti[10*k] : -luti[10*k]};
    c2 w3 = c2{lutr[15*k], (S>0)? luti[15*k] : -luti[15*k]};
    c2 w4 = c2{lutr[20*k], (S>0)? luti[20*k] : -luti[20*k]};
    a[0] = c2{l1r[j],     l1i[j]};
    a[1] = cmul(c2{l1r[j+125], l1i[j+125]}, w);
    a[2] = cmul(c2{l1r[j+250], l1i[j+250]}, w2);
    a[3] = cmul(c2{l1r[j+375], l1i[j+375]}, w3);
    a[4] = cmul(c2{l1r[j+500], l1i[j+500]}, w4);
    dft5<S>(a, b);
    int base = 5*(j-k)+k;
    #pragma unroll
    for (int r=0;r<5;r++){ int s = base + 25*r; l0r[s] = b[r].x; l0i[s] = b[r].y; }
  }
  __syncthreads();
  if (j < 125){ // L = 125
    c2 w  = c2{lutr[j],   (S>0)? luti[j]   : -luti[j]};
    c2 w2 = c2{lutr[2*j], (S>0)? luti[2*j] : -luti[2*j]};
    c2 w3 = c2{lutr[3*j], (S>0)? luti[3*j] : -luti[3*j]};
    c2 w4 = c2{lutr[4*j], (S>0)? luti[4*j] : -luti[4*j]};
    a[0] = c2{l0r[j],     l0i[j]};
    a[1] = cmul(c2{l0r[j+125], l0i[j+125]}, w);
    a[2] = cmul(c2{l0r[j+250], l0i[j+250]}, w2);
    a[3] = cmul(c2{l0r[j+375], l0i[j+375]}, w3);
    a[4] = cmul(c2{l0r[j+500], l0i[j+500]}, w4);
    dft5<S>(a, b);
    c2* op = outp + (size_t)i*TLEN + (size_t)kb*NA;
    if (TW){
      // incremental output twiddle: tw(n1=j) base, step = tw(125*kb)
      c2 twb = cis((float)S * TWO_PI * (float)(j*kb)   * (1.0f/160000.0f));
      c2 tws = cis((float)S * TWO_PI * (float)(125*kb) * (1.0f/160000.0f));
      #pragma unroll
      for (int r=0;r<5;r++){
        int n1 = j + 125*r;
        op[n1] = cmul(b[r], twb);
        twb = cmul(twb, tws);
      }
    } else {
      #pragma unroll
      for (int r=0;r<5;r++){
        int n1 = j + 125*r;
        if (n1 <= kamax) op[n1] = b[r];
      }
    }
  }
}

// ---------------- complex transpose (x-chain only) ----------------
__global__ __launch_bounds__(256) void k_transpose(const c2* __restrict__ in, c2* __restrict__ out,
                                                   int R, int C, int tilesR, int tilesC){
  __shared__ c2 tile[32][33];
  int bi = blockIdx.x;
  int arr = bi / (tilesR*tilesC);
  int tt = bi - arr*(tilesR*tilesC);
  int tr = tt / tilesC, tc = tt - tr*tilesC;
  const c2* ip = in + (size_t)arr*TLEN;
  c2* op = out + (size_t)arr*TLEN;
  int tx = threadIdx.x & 31, ty = threadIdx.x >> 5;
  #pragma unroll
  for (int i=0;i<4;i++){
    int r = tr*32 + ty + i*8, cc = tc*32 + tx;
    if (r < R && cc < C) tile[ty+i*8][tx] = ip[(size_t)r*C + cc];
  }
  __syncthreads();
  #pragma unroll
  for (int i=0;i<4;i++){
    int r = tc*32 + ty + i*8, cc = tr*32 + tx;
    if (r < C && cc < R) op[(size_t)r*R + cc] = tile[tx][ty+i*8];
  }
}

// ---------------- Gaussian lowpass + decimate-by-64, natural layout (S0 only) ----------------
__global__ __launch_bounds__(256) void k_conv(const float* __restrict__ inp, float* __restrict__ S){
  __shared__ float w[NTAP];
  for (int i=threadIdx.x; i<NTAP; i+=256){
    float d = (float)(i - KC);
    w[i] = 0.015666427f * __expf(-7.7106284e-4f * d * d);
  }
  __syncthreads();
  int g = blockIdx.x;
  int arr = g / 10;
  int t = (g - arr*10)*256 + threadIdx.x;
  if (t >= TD) return;
  int srow = arr * SROWS;
  const float* ip = inp + (size_t)arr*TLEN;
  float acc = 0.0f;
  int n = 64*t - KC; if (n < 0) n += TLEN;
  for (int m=0;m<NTAP;m++){
    acc += ip[n] * w[m];
    n++; if (n == TLEN) n = 0;
  }
  S[(size_t)srow*TD + t] = acc;
}

// ---------------- fused LDS stage + conv for scrambled-layout U (S1/S2 rows) ----------------
#define CONV_NCOL 27
#define CONV_NU   16875
#define CONV_USZ  17138
#define CONV_LDSB ((CONV_USZ + NTAP + 1)*4)
template<int MODE>
__global__ __launch_bounds__(256) void k_conv2(const float* __restrict__ inp, float* __restrict__ S,
                                               int cblk, int BLK, int nj2, int j2base, int scBase){
  extern __shared__ float smem[];
  float* u = smem;
  float* w = smem + CONV_USZ;
  for (int i=threadIdx.x; i<NTAP; i+=256){
    float d = (float)(i - KC);
    w[i] = 0.015666427f * __expf(-7.7106284e-4f * d * d);
  }
  int g = blockIdx.x;
  int arr = g / 10;
  int b = g - arr*10;
  int nlo = 16000*b - KC;
  int n2_0 = (nlo >= 0) ? (nlo/625) : -1;
  const float* ip = inp + (size_t)arr*TLEN;
  for (int e = threadIdx.x; e < CONV_NU; e += 256){
    int n1 = e / CONV_NCOL;
    int c  = e - n1*CONV_NCOL;
    int n2 = n2_0 + c;
    n2 &= 255;
    u[SW64(n1 + 625*c)] = ip[n1*NB + n2];
  }
  __syncthreads();
  int tl = threadIdx.x;
  if (tl >= 250) return;
  int t = 250*b + tl;
  int srow;
  if (MODE == 1){
    int a2 = arr / BLK; int j1 = cblk*BLK + (arr - a2*BLK);
    srow = a2*SROWS + 1 + j1;
  } else {
    int g2 = scBase + arr; int npb = BLK*nj2;
    int a2 = g2/npb, rr = g2 - a2*npb;
    int jloc = rr/nj2; int j2 = j2base + (rr - jloc*nj2);
    int j1 = cblk*BLK + jloc;
    int full = j1 >> 4;
    int cum = 16*(5*full - (full*(full-1))/2) + (j1 & 15)*(5 - full);
    int P = cum + j2 - full - 1;
    srow = a2*SROWS + 97 + P;
  }
  int base = 64*t - KC - 625*n2_0;
  float acc = 0.0f;
  #pragma unroll 4
  for (int m=0;m<NTAP;m++){
    acc += u[SW64(base + m)] * w[m];
  }
  S[(size_t)srow*TD + t] = acc;
}

// ---------------- global min/max + finalize ----------------
__global__ __launch_bounds__(256) void k_minmax1(const float* __restrict__ S, int n, float* pmn, float* pmx){
  __shared__ float smn[256], smx[256];
  float mn = 3.4028235e38f, mx = -3.4028235e38f;
  for (size_t i = (size_t)blockIdx.x*256 + threadIdx.x; i < (size_t)n; i += (size_t)gridDim.x*256){
    float v = S[i]; mn = fminf(mn,v); mx = fmaxf(mx,v);
  }
  smn[threadIdx.x]=mn; smx[threadIdx.x]=mx; __syncthreads();
  for (int s=128;s>0;s>>=1){
    if ((int)threadIdx.x < s){
      smn[threadIdx.x]=fminf(smn[threadIdx.x],smn[threadIdx.x+s]);
      smx[threadIdx.x]=fmaxf(smx[threadIdx.x],smx[threadIdx.x+s]);
    }
    __syncthreads();
  }
  if (threadIdx.x==0){ pmn[blockIdx.x]=smn[0]; pmx[blockIdx.x]=smx[0]; }
}
__global__ __launch_bounds__(256) void k_minmax2(const float* __restrict__ pmn, const float* __restrict__ pmx,
                                                 int nb, float* scal){
  __shared__ float smn[256], smx[256];
  float mn = 3.4028235e38f, mx = -3.4028235e38f;
  for (int i = threadIdx.x; i < nb; i += 256){ mn = fminf(mn,pmn[i]); mx = fmaxf(mx,pmx[i]); }
  smn[threadIdx.x]=mn; smx[threadIdx.x]=mx; __syncthreads();
  for (int s=128;s>0;s>>=1){
    if ((int)threadIdx.x < s){
      smn[threadIdx.x]=fminf(smn[threadIdx.x],smn[threadIdx.x+s]);
      smx[threadIdx.x]=fmaxf(smx[threadIdx.x],smx[threadIdx.x+s]);
    }
    __syncthreads();
  }
  if (threadIdx.x==0){ scal[0]=smn[0]; scal[1]=smx[0]; }
}
__global__ __launch_bounds__(256) void k_final(const float* __restrict__ S, const float* __restrict__ scal,
                                               float* __restrict__ out, int n){
  int i = blockIdx.x*256 + threadIdx.x;
  if (i >= n) return;
  float mn = scal[0];
  float r = scal[1] - mn;
  if (r == 0.0f) r = 1.0f;
  int half = SROWS*TD;
  int a = i / half; int rest = i - a*half;
  out[i] = (S[(size_t)(a & 1)*half + rest] - mn) / r;
}

extern "C" void kernel_launch(void* const* d_in, const int* in_sizes, int n_in,
                              void* d_out, int out_size, void* d_ws, size_t ws_size,
                              hipStream_t stream){
  (void)in_sizes; (void)n_in;
  const float* x = (const float*)d_in[0];

  int BLK = 16;
  while (BLK > 1){
    size_t CH = 2*(size_t)BLK;
    // Xf + A(3 slots; slot1 doubles as B) + U1h + Ur(3 slots) + Sb + reductions
    size_t needb = 2560000ULL + 3ULL*CH*TLEN*8ULL + CH*TLEN*8ULL
                 + 3ULL*CH*TLEN*4ULL + 6740000ULL + 8192ULL + 4096ULL;
    if (needb <= ws_size) break;
    BLK >>= 1;
  }
  {
    size_t CH = 2;
    size_t needmin = 2560000ULL + 3ULL*CH*TLEN*8ULL + CH*TLEN*8ULL
                   + 3ULL*CH*TLEN*4ULL + 6740000ULL + 8192ULL + 4096ULL;
    if (ws_size < needmin) return;
  }
  int CH = 2*BLK;

  char* p = (char*)d_ws;
  auto carve = [&](size_t bytes)->void*{ void* r = (void*)p; p += (bytes + 255) & ~(size_t)255; return r; };
  c2*    Xf  = (c2*)carve(2ULL*TLEN*sizeof(c2));
  c2*    A   = (c2*)carve(3ULL*CH*TLEN*sizeof(c2));      // 3 slots for sc-triple batching
  c2*    B   = A + (size_t)CH*TLEN;                       // alias: slot 1 (dead A-slot during F3)
  c2*    U1h = (c2*)carve((size_t)CH*TLEN*sizeof(c2));
  float* Ur  = (float*)carve(3ULL*CH*TLEN*sizeof(float)); // 3 slots
  float* Sb  = (float*)carve(2ULL*SROWS*TD*sizeof(float));
  float* pmn = (float*)carve(512*4);
  float* pmx = (float*)carve(512*4);
  float* scal = (float*)carve(256);

  // ---- forward FFT of x -> Xf ----
  k_fft256<-1,2,0><<<2*NA, 64, 0, stream>>>((const void*)x, (void*)A);
  k_transpose<<<2*20*8, 256, 0, stream>>>(A, U1h, NA, NB, 20, 8);
  k_fft625<-1,0,0><<<2*NB, 128, 0, stream>>>(U1h, Xf, 0,0,0,0,0, 314);  // only ka<=314 read by psi1
  // ---- S0 ----
  k_conv<<<2*10, 256, 0, stream>>>(x, Sb);

  int NCB = 96 / BLK;
  for (int c = 0; c < NCB; c++){
    int cq = (c*BLK)/16;
    int nj2 = 5 - cq;
    int j2base = cq + 1;
    // F3 partial-spectrum bound from the widest psi2 in this block (j2 = j2base)
    float xi2 = 0.4f * exp2f(-(float)j2base);
    int khi2 = (int)(3.1f * xi2 * 160000.0f) + 1; if (khi2 > TLEN/2 - 1) khi2 = TLEN/2 - 1;
    int kamax = (khi2 >> 8) + 1; if (kamax > 624) kamax = 624;
    // ---- order 1 ----
    k_fft625<1,1,1><<<CH*NB, 128, 0, stream>>>(Xf, A, c, BLK, 0,0,0, 624);
    if (nj2 > 0){
      k_fft256g<1><<<CH*GNCH, 256, G_LDSB, stream>>>(A, Ur, B);       // |ifft| -> Ur, fft -> B (=A slot1)
      k_conv2<1><<<CH*10, 256, CONV_LDSB, stream>>>(Ur, Sb, c, BLK, 0,0,0);
      k_fft625<-1,0,0><<<CH*NB, 128, 0, stream>>>(B, U1h, 0,0,0,0,0, kamax);
      // ---- order 2, sc batched in triples ----
      for (int scStart = 0; scStart < nj2; scStart += 3){
        int nsc = nj2 - scStart; if (nsc > 3) nsc = 3;
        k_fft625<1,2,1><<<nsc*CH*NB, 128, 0, stream>>>(U1h, A, c, BLK, nj2, j2base, scStart*CH, 624);
        k_fft256g<0><<<nsc*CH*GNCH, 256, G_LDSB, stream>>>(A, Ur, (c2*)nullptr);
        k_conv2<2><<<nsc*CH*10, 256, CONV_LDSB, stream>>>(Ur, Sb, c, BLK, nj2, j2base, scStart*CH);
      }
    } else {
      k_fft256g<0><<<CH*GNCH, 256, G_LDSB, stream>>>(A, Ur, (c2*)nullptr);
      k_conv2<1><<<CH*10, 256, CONV_LDSB, stream>>>(Ur, Sb, c, BLK, 0,0,0);
    }
  }

  // ---- global min-max normalize (standardize cancels) + tile(3,1,1) ----
  k_minmax1<<<512, 256, 0, stream>>>(Sb, 2*SROWS*TD, pmn, pmx);
  k_minmax2<<<1, 256, 0, stream>>>(pmn, pmx, 512, scal);
  k_final<<<(out_size+255)/256, 256, 0, stream>>>(Sb, scal, (float*)d_out, out_size);
}